// Round 20
// 725.975 us; speedup vs baseline: 2.4756x; 1.0097x over previous
//
#include <hip/hip_runtime.h>
#include <hip/hip_bf16.h>

typedef unsigned short u16;
typedef _Float16 h16;

#define BB 16
#define NO 64
#define TT 21
#define NM 768
#define PP 20
#define CAx 29
#define CMx 9
#define DD 256
#define HH 8
#define LL 6
#define KK 16
#define NN (NO + NM)        // 832
#define HDX (DD / HH)       // 32
#define MTOT (BB * NN)      // 13312
#define MAPR (BB * NM * PP) // 245760 map point-rows

typedef __attribute__((ext_vector_type(8))) h16 h8v;
typedef __attribute__((ext_vector_type(4))) h16 h4v;
typedef __attribute__((ext_vector_type(4))) float f4v;

#define GLOAD_LDS16(gptr, lptr)                                                             \
    __builtin_amdgcn_global_load_lds(                                                       \
        (const __attribute__((address_space(1))) void*)(gptr),                              \
        (__attribute__((address_space(3))) void*)(lptr), 16, 0, 0)

// Bank-conflict swizzle for [rows][32]-fp16 linear tiles (gload_lds-compatible):
#define SWZ_LCOL(lane)   ((((lane) & 3) ^ (((lane) >> 3) & 3)) * 8)
#define SWZ_RD(kb, fr)   ((((kb) ^ (((fr) >> 1) & 3))) * 8)
#define SWZ_ELEM(row, kl) (((((kl) >> 3) ^ (((row) >> 1) & 3)) << 3) | ((kl) & 7))

// ---------------------------------------------------------------- KNN (top-16 smallest d2)
__global__ __launch_bounds__(256) void knn_kernel(
    const float* __restrict__ opos, const float* __restrict__ mpos, int* __restrict__ IDX)
{
    const int b = blockIdx.x / 208;
    const int blk = blockIdx.x % 208;
    __shared__ float px[NN], py[NN], pz[NN];
    for (int i = threadIdx.x; i < NN; i += 256) {
        const float* src = (i < NO) ? &opos[(size_t)(b * NO + i) * 3]
                                    : &mpos[(size_t)(b * NM + (i - NO)) * 3];
        px[i] = src[0]; py[i] = src[1]; pz[i] = src[2];
    }
    __syncthreads();
    const int wave = threadIdx.x >> 6, lane = threadIdx.x & 63;
    const int n = blk * 4 + wave;
    const float qx = px[n], qy = py[n], qz = pz[n];
    float d[13];
    #pragma unroll
    for (int s = 0; s < 13; s++) {
        int j = s * 64 + lane;
        float dx = qx - px[j], dy = qy - py[j], dz = qz - pz[j];
        d[s] = dx * dx + dy * dy + dz * dz;
    }
    int keep = 0;
    #pragma unroll
    for (int it = 0; it < 16; it++) {
        float bv = d[0]; int bs = 0;
        #pragma unroll
        for (int s = 1; s < 13; s++) { if (d[s] < bv) { bv = d[s]; bs = s; } }
        float v = bv; int jj = bs * 64 + lane;
        #pragma unroll
        for (int off = 32; off; off >>= 1) {
            float ov = __shfl_xor(v, off);
            int oj = __shfl_xor(jj, off);
            if (ov < v || (ov == v && oj < jj)) { v = ov; jj = oj; }
        }
        if (lane == (jj & 63)) {
            int sl = jj >> 6;
            #pragma unroll
            for (int s = 0; s < 13; s++) if (s == sl) d[s] = 3.4e38f;
        }
        if (lane == it) keep = jj;
    }
    if (lane < 16) IDX[((size_t)(b * NN + n)) * 16 + lane] = keep;
}

// ---------------------------------------------------------------- merged elementwise prep
#define PRB_MAP   30720
#define PRB_AG    (PRB_MAP + 2688)
#define PRB_PE    (PRB_AG + MTOT)
#define PRB_PN    (PRB_PE + 1480)
#define PRB_TOT   (PRB_PN + 18432)
#define W1P_O   0
#define W2S_O   2048
#define W3S_O   6144
#define MW1A_O  10240
#define MW1B_O  14336
#define MW2S_O  18432
#define OW1S_O  22528
#define OW2S_O  26624
#define APW_O   43008
#define AW1A_O  51200
#define AW1B_O  116736
#define AW2S_O  182272
#define AOW1_O  247808
#define AOW2_O  313344
#define WPN_TOT 378880
__global__ __launch_bounds__(256) void prep_all(
    const float* __restrict__ mp, const float* __restrict__ obj,
    const float* __restrict__ opos, const float* __restrict__ mpos,
    const float* __restrict__ wqkv, const float* __restrict__ wo,
    const float* __restrict__ f1w, const float* __restrict__ f2w,
    const float* __restrict__ m_pre_w1, const float* __restrict__ m_pre_w2,
    const float* __restrict__ m_pre_w3, const float* __restrict__ m_mlp_w1,
    const float* __restrict__ m_mlp_w2, const float* __restrict__ m_out_w1,
    const float* __restrict__ m_out_w2,
    const float* __restrict__ a_pre_w,  const float* __restrict__ a_mlp_w1,
    const float* __restrict__ a_mlp_w2, const float* __restrict__ a_out_w1,
    const float* __restrict__ a_out_w2,
    h16* __restrict__ pmap, h16* __restrict__ pagent,
    h16* __restrict__ PE16, h16* __restrict__ wpnf, h16* __restrict__ whf)
{
    const int bid = blockIdx.x;
    const int tid = threadIdx.x;
    if (bid < PRB_MAP) {
        int e = bid * 256 + tid;
        int r = e >> 5, c = e & 31;
        float v = (c < CMx) ? mp[(size_t)r * CMx + c] : 0.f;
        pmap[e] = (h16)v;
    } else if (bid < PRB_AG) {
        int e = (bid - PRB_MAP) * 256 + tid;
        int r = e >> 5, c = e & 31;
        float v = (c < CAx) ? obj[(size_t)r * CAx + c] : ((c == CAx) ? 1.0f : 0.f);
        pagent[e] = (h16)v;
    } else if (bid < PRB_PE) {
        int row = bid - PRB_AG;
        int b = row / NN, n = row % NN;
        const float* p = (n < NO) ? &opos[(size_t)(b * NO + n) * 3]
                                  : &mpos[(size_t)(b * NM + (n - NO)) * 3];
        float x = p[0], y = p[1];
        int j = tid & 127;
        float v = (tid < 128) ? y : x;
        float inv_dt = exp2f(-(float)(j & ~1) * 0.10381025296523f);
        float e = v * 6.283185307179586f * inv_dt;
        PE16[(size_t)row * DD + tid] = (h16)((j & 1) ? cosf(e) : sinf(e));
    } else if (bid < PRB_PN) {
        int e = (bid - PRB_PE) * 256 + tid;
        float v;
        if (e < W2S_O)       { int n = e >> 5, k = e & 31; v = (k < 9) ? m_pre_w1[n * 9 + k] : 0.f; }
        else if (e < W3S_O)  v = m_pre_w2[e - W2S_O];
        else if (e < MW1A_O) v = m_pre_w3[e - W3S_O];
        else if (e < MW1B_O) { int r = e - MW1A_O; v = m_mlp_w1[(r >> 6) * 128 + (r & 63)]; }
        else if (e < MW2S_O) { int r = e - MW1B_O; v = m_mlp_w1[(r >> 6) * 128 + 64 + (r & 63)]; }
        else if (e < OW1S_O) v = m_mlp_w2[e - MW2S_O];
        else if (e < OW2S_O) v = m_out_w1[e - OW1S_O];
        else if (e < APW_O)  v = m_out_w2[e - OW2S_O];
        else if (e < AW1A_O) { int r = e - APW_O; int n = r >> 5, k = r & 31; v = (k < 30) ? a_pre_w[n * 30 + k] : 0.f; }
        else if (e < AW1B_O) { int r = e - AW1A_O; v = a_mlp_w1[(r >> 8) * 512 + (r & 255)]; }
        else if (e < AW2S_O) { int r = e - AW1B_O; v = a_mlp_w1[(r >> 8) * 512 + 256 + (r & 255)]; }
        else if (e < AOW1_O) v = a_mlp_w2[e - AW2S_O];
        else if (e < AOW2_O) v = a_out_w1[e - AOW1_O];
        else                 v = a_out_w2[e - AOW2_O];
        wpnf[e] = (h16)v;
    } else {
        size_t e = (size_t)(bid - PRB_PN) * 256 + tid;
        int L = (int)(e / 786432);
        int r = (int)(e % 786432);
        float v;
        if (r < 196608)      v = wqkv[(size_t)L * 196608 + r];
        else if (r < 262144) v = wo[(size_t)L * 65536 + (r - 196608)];
        else if (r < 524288) v = f1w[(size_t)L * 262144 + (r - 262144)];
        else                 v = f2w[(size_t)L * 262144 + (r - 524288)];
        whf[e] = (h16)v;
    }
}

// ---------------------------------------------------------------- max-pool over P points, 8-wide
template<int P>
__global__ __launch_bounds__(256) void pool_max8(
    const h16* __restrict__ in, h16* __restrict__ out, int cshift)
{
    int e8 = blockIdx.x * 256 + threadIdx.x;
    int C = 1 << cshift;
    int base = e8 * 8;
    int g = base >> cshift, c = base & (C - 1);
    float m0 = -3.4e38f, m1 = m0, m2 = m0, m3 = m0, m4 = m0, m5 = m0, m6 = m0, m7 = m0;
    #pragma unroll
    for (int p = 0; p < P; p++) {
        h8v v = *(const h8v*)&in[((size_t)(g * P + p) << cshift) + c];
        m0 = fmaxf(m0, (float)v[0]); m1 = fmaxf(m1, (float)v[1]);
        m2 = fmaxf(m2, (float)v[2]); m3 = fmaxf(m3, (float)v[3]);
        m4 = fmaxf(m4, (float)v[4]); m5 = fmaxf(m5, (float)v[5]);
        m6 = fmaxf(m6, (float)v[6]); m7 = fmaxf(m7, (float)v[7]);
    }
    h8v o;
    o[0] = (h16)m0; o[1] = (h16)m1; o[2] = (h16)m2; o[3] = (h16)m3;
    o[4] = (h16)m4; o[5] = (h16)m5; o[6] = (h16)m6; o[7] = (h16)m7;
    *(h8v*)&out[((size_t)g << cshift) + c] = o;
}

// ---------------------------------------------------------------- pointnet GEMM (fp16 MFMA)
// ROWMAP: fp32 out at remapped row (safe staging; X16/XP16 made later by split_x0).
template<int BN, bool RELU, bool F16OUT, bool ROWMAP>
__global__ __launch_bounds__(256) void gemm_pn(
    const h16* __restrict__ A, const h16* __restrict__ W,
    const float* __restrict__ bias,
    const float* __restrict__ addrow, int ardiv, int arld,
    float* __restrict__ Cf, h16* __restrict__ C16,
    int K, int ldc, int rm_div, int rm_mul, int rm_add)
{
    constexpr int WAVES_M = (BN == 64) ? 4 : 2;
    constexpr int WM = 128 / (16 * WAVES_M);
    __shared__ __align__(16) h16 AS[128][32];
    __shared__ __align__(16) h16 WS[BN][32];
    const int m0 = blockIdx.x * 128;
    const int n0 = blockIdx.y * BN;
    const int tid = threadIdx.x;
    const int wave = tid >> 6, lane = tid & 63;
    const int wr = (BN == 64) ? wave : (wave >> 1);
    const int wc = (BN == 64) ? 0 : (wave & 1);
    const int fr = lane & 15, kb = lane >> 4;
    const int lrow = lane >> 2, lcol = SWZ_LCOL(lane);
    const int rdo = SWZ_RD(kb, fr);

    f4v acc[WM][4];
    #pragma unroll
    for (int i = 0; i < WM; i++)
        #pragma unroll
        for (int j = 0; j < 4; j++) { f4v z = {0.f, 0.f, 0.f, 0.f}; acc[i][j] = z; }

    for (int k0 = 0; k0 < K; k0 += 32) {
        __syncthreads();
        #pragma unroll
        for (int i = 0; i < 2; i++) {
            const int r = wave * 32 + i * 16;
            GLOAD_LDS16(&A[(size_t)(m0 + r + lrow) * K + k0 + lcol], &AS[r][0]);
        }
        if constexpr (BN == 64) {
            const int r = wave * 16;
            GLOAD_LDS16(&W[(size_t)(n0 + r + lrow) * K + k0 + lcol], &WS[r][0]);
        } else {
            #pragma unroll
            for (int i = 0; i < 2; i++) {
                const int r = wave * 32 + i * 16;
                GLOAD_LDS16(&W[(size_t)(n0 + r + lrow) * K + k0 + lcol], &WS[r][0]);
            }
        }
        __syncthreads();
        h8v af[WM];
        #pragma unroll
        for (int mi = 0; mi < WM; mi++)
            af[mi] = *(const h8v*)&AS[wr * (WM * 16) + mi * 16 + fr][rdo];
        #pragma unroll
        for (int nj = 0; nj < 4; nj++) {
            h8v bf = *(const h8v*)&WS[wc * 64 + nj * 16 + fr][rdo];
            #pragma unroll
            for (int mi = 0; mi < WM; mi++)
                acc[mi][nj] = __builtin_amdgcn_mfma_f32_16x16x32_f16(af[mi], bf, acc[mi][nj], 0, 0, 0);
        }
    }
    #pragma unroll
    for (int mi = 0; mi < WM; mi++) {
        #pragma unroll
        for (int nj = 0; nj < 4; nj++) {
            int col = n0 + wc * 64 + nj * 16 + fr;
            float bb = bias ? bias[col] : 0.f;
            #pragma unroll
            for (int r = 0; r < 4; r++) {
                int row = m0 + wr * (WM * 16) + mi * 16 + (lane >> 4) * 4 + r;
                float v = acc[mi][nj][r] + bb;
                if (addrow) v += addrow[(size_t)(row / ardiv) * arld + col];
                if (RELU) v = fmaxf(v, 0.f);
                if (F16OUT) {
                    C16[(size_t)row * ldc + col] = (h16)v;
                } else {
                    int drow = row;
                    if (ROWMAP) drow = row + rm_add + (row / rm_div) * rm_mul;
                    Cf[(size_t)drow * ldc + col] = v;
                }
            }
        }
    }
}

// ---------------------------------------------------------------- initial activation cvt
__global__ __launch_bounds__(256) void split_x0(
    const float* __restrict__ X, const h16* __restrict__ PE16,
    h16* __restrict__ X16, h16* __restrict__ XP16)
{
    size_t base = ((size_t)blockIdx.x * 256 + threadIdx.x) * 4;
    float4 x = *(const float4*)&X[base];
    h4v pe = *(const h4v*)&PE16[base];
    h4v a, b;
    a.x = (h16)x.x; a.y = (h16)x.y; a.z = (h16)x.z; a.w = (h16)x.w;
    b.x = (h16)(x.x + (float)pe.x); b.y = (h16)(x.y + (float)pe.y);
    b.z = (h16)(x.z + (float)pe.z); b.w = (h16)(x.w + (float)pe.w);
    *(h4v*)&X16[base] = a;
    *(h4v*)&XP16[base] = b;
}

// ---------------------------------------------------------------- fused map pre1->pre2->pre3
__global__ __launch_bounds__(256) void fused_map3(
    const h16* __restrict__ A,   // [MAPR][32]
    const h16* __restrict__ W1,  // [64][32]
    const h16* __restrict__ W2, const h16* __restrict__ W3,  // [64][64]
    const float* __restrict__ b1, const float* __restrict__ b2, const float* __restrict__ b3,
    h16* __restrict__ Out)       // [MAPR][64]
{
    __shared__ __align__(16) h16 AS[128][32];
    __shared__ __align__(16) h16 G0[2][128][32];
    __shared__ __align__(16) h16 G1[2][128][32];
    __shared__ __align__(16) h16 W1S[64][32];
    __shared__ __align__(16) h16 W2S[2][64][32];
    __shared__ __align__(16) h16 W3S[2][64][32];
    const int m0 = blockIdx.x * 128;
    const int tid = threadIdx.x;
    const int wave = tid >> 6, lane = tid & 63;
    const int fr = lane & 15, kb = lane >> 4;
    const int lrow = lane >> 2, lcol = SWZ_LCOL(lane);
    const int rdo = SWZ_RD(kb, fr);

    #pragma unroll
    for (int q = 0; q < 2; q++)
        GLOAD_LDS16(&A[(size_t)(m0 + wave * 32 + q * 16 + lrow) * 32 + lcol],
                    &AS[wave * 32 + q * 16][0]);
    GLOAD_LDS16(&W1[(size_t)(wave * 16 + lrow) * 32 + lcol], &W1S[wave * 16][0]);
    #pragma unroll
    for (int t = 0; t < 2; t++) {
        GLOAD_LDS16(&W2[(size_t)(wave * 16 + lrow) * 64 + t * 32 + lcol], &W2S[t][wave * 16][0]);
        GLOAD_LDS16(&W3[(size_t)(wave * 16 + lrow) * 64 + t * 32 + lcol], &W3S[t][wave * 16][0]);
    }
    __syncthreads();
    #pragma unroll
    for (int mi = 0; mi < 2; mi++) {
        h8v af = *(const h8v*)&AS[wave * 32 + mi * 16 + fr][rdo];
        #pragma unroll
        for (int nj = 0; nj < 4; nj++) {
            f4v a = {0.f, 0.f, 0.f, 0.f};
            h8v bf = *(const h8v*)&W1S[nj * 16 + fr][rdo];
            a = __builtin_amdgcn_mfma_f32_16x16x32_f16(af, bf, a, 0, 0, 0);
            int col = nj * 16 + fr, ch = col >> 5, kl = col & 31;
            float bb = b1[col];
            #pragma unroll
            for (int r = 0; r < 4; r++) {
                int row = wave * 32 + mi * 16 + kb * 4 + r;
                G0[ch][row][SWZ_ELEM(row, kl)] = (h16)fmaxf(a[r] + bb, 0.f);
            }
        }
    }
    __syncthreads();
    #pragma unroll
    for (int mi = 0; mi < 2; mi++) {
        #pragma unroll
        for (int nj = 0; nj < 4; nj++) {
            f4v a = {0.f, 0.f, 0.f, 0.f};
            #pragma unroll
            for (int t = 0; t < 2; t++) {
                h8v af = *(const h8v*)&G0[t][wave * 32 + mi * 16 + fr][rdo];
                h8v bf = *(const h8v*)&W2S[t][nj * 16 + fr][rdo];
                a = __builtin_amdgcn_mfma_f32_16x16x32_f16(af, bf, a, 0, 0, 0);
            }
            int col = nj * 16 + fr, ch = col >> 5, kl = col & 31;
            float bb = b2[col];
            #pragma unroll
            for (int r = 0; r < 4; r++) {
                int row = wave * 32 + mi * 16 + kb * 4 + r;
                G1[ch][row][SWZ_ELEM(row, kl)] = (h16)fmaxf(a[r] + bb, 0.f);
            }
        }
    }
    __syncthreads();
    #pragma unroll
    for (int mi = 0; mi < 2; mi++) {
        #pragma unroll
        for (int nj = 0; nj < 4; nj++) {
            f4v a = {0.f, 0.f, 0.f, 0.f};
            #pragma unroll
            for (int t = 0; t < 2; t++) {
                h8v af = *(const h8v*)&G1[t][wave * 32 + mi * 16 + fr][rdo];
                h8v bf = *(const h8v*)&W3S[t][nj * 16 + fr][rdo];
                a = __builtin_amdgcn_mfma_f32_16x16x32_f16(af, bf, a, 0, 0, 0);
            }
            int col = nj * 16 + fr;
            float bb = b3[col];
            #pragma unroll
            for (int r = 0; r < 4; r++) {
                int row = m0 + wave * 32 + mi * 16 + kb * 4 + r;
                Out[(size_t)row * 64 + col] = (h16)fmaxf(a[r] + bb, 0.f);
            }
        }
    }
}

// ---------------------------------------------------------------- fused map mid1->mid2
// mid1 bias b1 is carried entirely by `pooled` (PCf = pooled@W1B + b1).
__global__ __launch_bounds__(256) void fused_map2(
    const h16* __restrict__ A,   // [MAPR][64]
    const h16* __restrict__ W1,  // MW1A [64][64]
    const h16* __restrict__ W2,  // MW2S [64][64]
    const float* __restrict__ b2,
    const float* __restrict__ pooled,  // PCf [12288][64] f32 (includes b1)
    h16* __restrict__ Out)       // [MAPR][64]
{
    __shared__ __align__(16) h16 AS[2][128][32];
    __shared__ __align__(16) h16 G0[2][128][32];
    __shared__ __align__(16) h16 W1S[2][64][32];
    __shared__ __align__(16) h16 W2S[2][64][32];
    const int m0 = blockIdx.x * 128;
    const int tid = threadIdx.x;
    const int wave = tid >> 6, lane = tid & 63;
    const int fr = lane & 15, kb = lane >> 4;
    const int lrow = lane >> 2, lcol = SWZ_LCOL(lane);
    const int rdo = SWZ_RD(kb, fr);

    #pragma unroll
    for (int t = 0; t < 2; t++) {
        #pragma unroll
        for (int q = 0; q < 2; q++)
            GLOAD_LDS16(&A[(size_t)(m0 + wave * 32 + q * 16 + lrow) * 64 + t * 32 + lcol],
                        &AS[t][wave * 32 + q * 16][0]);
        GLOAD_LDS16(&W1[(size_t)(wave * 16 + lrow) * 64 + t * 32 + lcol], &W1S[t][wave * 16][0]);
        GLOAD_LDS16(&W2[(size_t)(wave * 16 + lrow) * 64 + t * 32 + lcol], &W2S[t][wave * 16][0]);
    }
    __syncthreads();
    #pragma unroll
    for (int mi = 0; mi < 2; mi++) {
        #pragma unroll
        for (int nj = 0; nj < 4; nj++) {
            f4v a = {0.f, 0.f, 0.f, 0.f};
            #pragma unroll
            for (int t = 0; t < 2; t++) {
                h8v af = *(const h8v*)&AS[t][wave * 32 + mi * 16 + fr][rdo];
                h8v bf = *(const h8v*)&W1S[t][nj * 16 + fr][rdo];
                a = __builtin_amdgcn_mfma_f32_16x16x32_f16(af, bf, a, 0, 0, 0);
            }
            int col = nj * 16 + fr, ch = col >> 5, kl = col & 31;
            #pragma unroll
            for (int r = 0; r < 4; r++) {
                int row = wave * 32 + mi * 16 + kb * 4 + r;
                int grow = m0 + row;
                float v = a[r] + pooled[(size_t)(grow / PP) * 64 + col];
                G0[ch][row][SWZ_ELEM(row, kl)] = (h16)fmaxf(v, 0.f);
            }
        }
    }
    __syncthreads();
    #pragma unroll
    for (int mi = 0; mi < 2; mi++) {
        #pragma unroll
        for (int nj = 0; nj < 4; nj++) {
            f4v a = {0.f, 0.f, 0.f, 0.f};
            #pragma unroll
            for (int t = 0; t < 2; t++) {
                h8v af = *(const h8v*)&G0[t][wave * 32 + mi * 16 + fr][rdo];
                h8v bf = *(const h8v*)&W2S[t][nj * 16 + fr][rdo];
                a = __builtin_amdgcn_mfma_f32_16x16x32_f16(af, bf, a, 0, 0, 0);
            }
            int col = nj * 16 + fr;
            float bb = b2[col];
            #pragma unroll
            for (int r = 0; r < 4; r++) {
                int row = m0 + wave * 32 + mi * 16 + kb * 4 + r;
                Out[(size_t)row * 64 + col] = (h16)fmaxf(a[r] + bb, 0.f);
            }
        }
    }
}

// ---------------------------------------------------------------- transformer fp16 MFMA GEMM
template<bool RELU, bool F16OUT>
__global__ __launch_bounds__(256) void gemm_mfma(
    const h16* __restrict__ A, const h16* __restrict__ A2, int a2min,
    const h16* __restrict__ W, const float* __restrict__ bias,
    float* __restrict__ Cf, h16* __restrict__ C16,
    int K, int ldc, int coff, float scale, int scale_until)
{
    __shared__ __align__(16) h16 AS[128][32];
    __shared__ __align__(16) h16 WS[128][32];
    const int m0 = blockIdx.x * 128;
    const int n0 = blockIdx.y * 128;
    const h16* pA = (n0 >= a2min) ? A2 : A;
    const int tid = threadIdx.x;
    const int wave = tid >> 6, lane = tid & 63;
    const int wr = wave >> 1, wc = wave & 1;
    const int fr = lane & 15, kb = lane >> 4;
    const int lrow = lane >> 2;
    const int lcol = SWZ_LCOL(lane);
    const int rdo = SWZ_RD(kb, fr);

    f4v acc[4][4];
    #pragma unroll
    for (int i = 0; i < 4; i++)
        #pragma unroll
        for (int j = 0; j < 4; j++) { f4v z = {0.f, 0.f, 0.f, 0.f}; acc[i][j] = z; }

    for (int k0 = 0; k0 < K; k0 += 32) {
        __syncthreads();
        #pragma unroll
        for (int i = 0; i < 2; i++) {
            const int r = wave * 32 + i * 16;
            const size_t grow = (size_t)(r + lrow);
            GLOAD_LDS16(&pA[(m0 + grow) * K + k0 + lcol], &AS[r][0]);
            GLOAD_LDS16(&W [(n0 + grow) * K + k0 + lcol], &WS[r][0]);
        }
        __syncthreads();
        h8v af[4];
        #pragma unroll
        for (int mi = 0; mi < 4; mi++)
            af[mi] = *(const h8v*)&AS[wr * 64 + mi * 16 + fr][rdo];
        #pragma unroll
        for (int nj = 0; nj < 4; nj++) {
            h8v bf = *(const h8v*)&WS[wc * 64 + nj * 16 + fr][rdo];
            #pragma unroll
            for (int mi = 0; mi < 4; mi++)
                acc[mi][nj] = __builtin_amdgcn_mfma_f32_16x16x32_f16(af[mi], bf, acc[mi][nj], 0, 0, 0);
        }
    }
    #pragma unroll
    for (int mi = 0; mi < 4; mi++) {
        #pragma unroll
        for (int nj = 0; nj < 4; nj++) {
            int col = n0 + wc * 64 + nj * 16 + fr;
            float bb = bias[col];
            #pragma unroll
            for (int r = 0; r < 4; r++) {
                int row = m0 + wr * 64 + mi * 16 + (lane >> 4) * 4 + r;
                float v = acc[mi][nj][r] + bb;
                if (RELU) v = fmaxf(v, 0.f);
                int gcol = coff + col;
                if (gcol < scale_until) v *= scale;
                if (F16OUT) {
                    C16[(size_t)row * ldc + gcol] = (h16)v;
                } else {
                    Cf[(size_t)row * ldc + gcol] = v;
                }
            }
        }
    }
}

// ---------------------------------------------------------------- GEMM + residual + LayerNorm (O-proj)
__global__ __launch_bounds__(512) void gemm_ln0(
    const h16* __restrict__ A, const h16* __restrict__ W,
    const float* __restrict__ bias, const h16* __restrict__ R16,
    const float* __restrict__ g, const float* __restrict__ bt,
    h16* __restrict__ O16, int K)
{
    __shared__ __align__(16) h16 AS[32][32];
    __shared__ __align__(16) h16 WS[256][32];
    __shared__ float red_s[2][8][32];
    const int m0 = blockIdx.x * 32;
    const int tid = threadIdx.x;
    const int wave = tid >> 6, lane = tid & 63;
    const int fr = lane & 15, kb = lane >> 4;
    const int lrow = lane >> 2, lcol = SWZ_LCOL(lane);
    const int rdo = SWZ_RD(kb, fr);

    f4v acc[2][2];
    #pragma unroll
    for (int i = 0; i < 2; i++)
        #pragma unroll
        for (int j = 0; j < 2; j++) { f4v z = {0.f, 0.f, 0.f, 0.f}; acc[i][j] = z; }

    for (int k0 = 0; k0 < K; k0 += 32) {
        __syncthreads();
        if (wave < 2) {
            GLOAD_LDS16(&A[(size_t)(m0 + wave * 16 + lrow) * K + k0 + lcol], &AS[wave * 16][0]);
        }
        #pragma unroll
        for (int i = 0; i < 2; i++) {
            const int r = wave * 32 + i * 16;
            GLOAD_LDS16(&W[(size_t)(r + lrow) * K + k0 + lcol], &WS[r][0]);
        }
        __syncthreads();
        h8v af[2];
        #pragma unroll
        for (int mi = 0; mi < 2; mi++)
            af[mi] = *(const h8v*)&AS[mi * 16 + fr][rdo];
        #pragma unroll
        for (int nj = 0; nj < 2; nj++) {
            h8v bf = *(const h8v*)&WS[wave * 32 + nj * 16 + fr][rdo];
            #pragma unroll
            for (int mi = 0; mi < 2; mi++)
                acc[mi][nj] = __builtin_amdgcn_mfma_f32_16x16x32_f16(af[mi], bf, acc[mi][nj], 0, 0, 0);
        }
    }
    float x[2][2][4];
    float rsum[2][4], rsq[2][4];
    #pragma unroll
    for (int mi = 0; mi < 2; mi++)
        #pragma unroll
        for (int r = 0; r < 4; r++) { rsum[mi][r] = 0.f; rsq[mi][r] = 0.f; }
    #pragma unroll
    for (int mi = 0; mi < 2; mi++) {
        #pragma unroll
        for (int nj = 0; nj < 2; nj++) {
            int col = wave * 32 + nj * 16 + fr;
            float bb = bias[col];
            #pragma unroll
            for (int r = 0; r < 4; r++) {
                int row = m0 + mi * 16 + kb * 4 + r;
                float v = acc[mi][nj][r] + bb + (float)R16[(size_t)row * 256 + col];
                x[mi][nj][r] = v;
                rsum[mi][r] += v;
                rsq[mi][r] += v * v;
            }
        }
    }
    #pragma unroll
    for (int off = 1; off < 16; off <<= 1) {
        #pragma unroll
        for (int mi = 0; mi < 2; mi++)
            #pragma unroll
            for (int r = 0; r < 4; r++) {
                rsum[mi][r] += __shfl_xor(rsum[mi][r], off);
                rsq[mi][r]  += __shfl_xor(rsq[mi][r], off);
            }
    }
    if (fr == 0) {
        #pragma unroll
        for (int mi = 0; mi < 2; mi++)
            #pragma unroll
            for (int r = 0; r < 4; r++) {
                int rid = mi * 16 + kb * 4 + r;
                red_s[0][wave][rid] = rsum[mi][r];
                red_s[1][wave][rid] = rsq[mi][r];
            }
    }
    __syncthreads();
    #pragma unroll
    for (int mi = 0; mi < 2; mi++) {
        #pragma unroll
        for (int r = 0; r < 4; r++) {
            int rid = mi * 16 + kb * 4 + r;
            float s = 0.f, sq = 0.f;
            #pragma unroll
            for (int w = 0; w < 8; w++) { s += red_s[0][w][rid]; sq += red_s[1][w][rid]; }
            float mean = s * (1.f / 256.f);
            float var = sq * (1.f / 256.f) - mean * mean;
            float inv = rsqrtf(var + 1e-5f);
            #pragma unroll
            for (int nj = 0; nj < 2; nj++) {
                int col = wave * 32 + nj * 16 + fr;
                float o = (x[mi][nj][r] - mean) * inv * g[col] + bt[col];
                O16[(size_t)(m0 + rid) * 256 + col] = (h16)o;
            }
        }
    }
}

// ---------------------------------------------------------------- fused FFN1+FFN2+residual+LN
template<int PEMODE>
__global__ __launch_bounds__(512) void fused_ffn(
    const h16* __restrict__ H16g, const h16* __restrict__ W1,
    const h16* __restrict__ W2,
    const float* __restrict__ b1, const float* __restrict__ b2,
    const float* __restrict__ g, const float* __restrict__ bt,
    float* __restrict__ OutF, h16* __restrict__ O16,
    const h16* __restrict__ PE16p, h16* __restrict__ P16)
{
    __shared__ __align__(16) h16 HS[8][32][32];
    __shared__ __align__(16) h16 GS[2][32][32];
    __shared__ __align__(16) h16 WSu[16384];
    __shared__ float red_s[2][8][32];
    const int m0 = blockIdx.x * 32;
    const int tid = threadIdx.x;
    const int wave = tid >> 6, lane = tid & 63;
    const int fr = lane & 15, kb = lane >> 4;
    const int lrow = lane >> 2, lcol = SWZ_LCOL(lane);
    const int rdo = SWZ_RD(kb, fr);
    const int mi1 = wave >> 2, nj1 = wave & 3;

    #pragma unroll
    for (int q = 0; q < 2; q++)
        GLOAD_LDS16(&H16g[(size_t)(m0 + q * 16 + lrow) * 256 + wave * 32 + lcol],
                    &HS[wave][q * 16][0]);

    f4v acc2[2][2];
    #pragma unroll
    for (int i = 0; i < 2; i++)
        #pragma unroll
        for (int j = 0; j < 2; j++) { f4v z = {0.f, 0.f, 0.f, 0.f}; acc2[i][j] = z; }

    for (int c = 0; c < 16; c++) {
        const int H0 = c * 64;
        __syncthreads();
        #pragma unroll
        for (int q = 0; q < 4; q++)
            GLOAD_LDS16(&W1[(size_t)(H0 + q * 16 + lrow) * 256 + wave * 32 + lcol],
                        &WSu[wave * 2048 + (q * 16) * 32]);
        __syncthreads();
        f4v a1 = {0.f, 0.f, 0.f, 0.f};
        #pragma unroll
        for (int t = 0; t < 8; t++) {
            h8v af = *(const h8v*)&HS[t][mi1 * 16 + fr][rdo];
            h8v bf = *(const h8v*)&WSu[t * 2048 + (nj1 * 16 + fr) * 32 + rdo];
            a1 = __builtin_amdgcn_mfma_f32_16x16x32_f16(af, bf, a1, 0, 0, 0);
        }
        {
            int col = nj1 * 16 + fr, ch = col >> 5, kl = col & 31;
            float bb = b1[H0 + col];
            #pragma unroll
            for (int r = 0; r < 4; r++) {
                int row = mi1 * 16 + kb * 4 + r;
                GS[ch][row][SWZ_ELEM(row, kl)] = (h16)fmaxf(a1[r] + bb, 0.f);
            }
        }
        __syncthreads();
        #pragma unroll
        for (int t2 = 0; t2 < 2; t2++)
            #pragma unroll
            for (int q = 0; q < 2; q++)
                GLOAD_LDS16(&W2[(size_t)(wave * 32 + q * 16 + lrow) * 1024 + H0 + t2 * 32 + lcol],
                            &WSu[t2 * 8192 + (wave * 32 + q * 16) * 32]);
        __syncthreads();
        #pragma unroll
        for (int t2 = 0; t2 < 2; t2++) {
            #pragma unroll
            for (int mi = 0; mi < 2; mi++) {
                h8v af = *(const h8v*)&GS[t2][mi * 16 + fr][rdo];
                #pragma unroll
                for (int nj = 0; nj < 2; nj++) {
                    h8v bf = *(const h8v*)&WSu[t2 * 8192 + (wave * 32 + nj * 16 + fr) * 32 + rdo];
                    acc2[mi][nj] = __builtin_amdgcn_mfma_f32_16x16x32_f16(af, bf, acc2[mi][nj], 0, 0, 0);
                }
            }
        }
    }
    float x[2][2][4];
    float rsum[2][4], rsq[2][4];
    #pragma unroll
    for (int mi = 0; mi < 2; mi++)
        #pragma unroll
        for (int r = 0; r < 4; r++) { rsum[mi][r] = 0.f; rsq[mi][r] = 0.f; }
    #pragma unroll
    for (int mi = 0; mi < 2; mi++) {
        #pragma unroll
        for (int nj = 0; nj < 2; nj++) {
            int col = wave * 32 + nj * 16 + fr;
            int ch = col >> 5, kl = col & 31;
            float bb = b2[col];
            #pragma unroll
            for (int r = 0; r < 4; r++) {
                int row = mi * 16 + kb * 4 + r;
                float res = (float)HS[ch][row][SWZ_ELEM(row, kl)];
                float v = acc2[mi][nj][r] + bb + res;
                x[mi][nj][r] = v;
                rsum[mi][r] += v;
                rsq[mi][r] += v * v;
            }
        }
    }
    #pragma unroll
    for (int off = 1; off < 16; off <<= 1) {
        #pragma unroll
        for (int mi = 0; mi < 2; mi++)
            #pragma unroll
            for (int r = 0; r < 4; r++) {
                rsum[mi][r] += __shfl_xor(rsum[mi][r], off);
                rsq[mi][r]  += __shfl_xor(rsq[mi][r], off);
            }
    }
    if (fr == 0) {
        #pragma unroll
        for (int mi = 0; mi < 2; mi++)
            #pragma unroll
            for (int r = 0; r < 4; r++) {
                int rid = mi * 16 + kb * 4 + r;
                red_s[0][wave][rid] = rsum[mi][r];
                red_s[1][wave][rid] = rsq[mi][r];
            }
    }
    __syncthreads();
    #pragma unroll
    for (int mi = 0; mi < 2; mi++) {
        #pragma unroll
        for (int r = 0; r < 4; r++) {
            int rid = mi * 16 + kb * 4 + r;
            float s = 0.f, sq = 0.f;
            #pragma unroll
            for (int w = 0; w < 8; w++) { s += red_s[0][w][rid]; sq += red_s[1][w][rid]; }
            float mean = s * (1.f / 256.f);
            float var = sq * (1.f / 256.f) - mean * mean;
            float inv = rsqrtf(var + 1e-5f);
            #pragma unroll
            for (int nj = 0; nj < 2; nj++) {
                int col = wave * 32 + nj * 16 + fr;
                float o = (x[mi][nj][r] - mean) * inv * g[col] + bt[col];
                size_t idx = (size_t)(m0 + rid) * 256 + col;
                if (PEMODE == 2) {
                    OutF[idx] = o;
                } else {
                    O16[idx] = (h16)o;
                    P16[idx] = (h16)(o + (float)PE16p[idx]);
                }
            }
        }
    }
}

// ---------------------------------------------------------------- local KNN attention (fp16 QKV)
__global__ __launch_bounds__(256) void attn_kernel(
    const h16* __restrict__ QKV16, const int* __restrict__ IDX,
    h16* __restrict__ AO16)
{
    __shared__ __align__(16) h16 Ks[32][256];
    __shared__ float p_s[2][HH][16];
    __shared__ int gid_s[2][16];
    const int sub = threadIdx.x >> 7;
    const int t = threadIdx.x & 127;
    const int wave = threadIdx.x >> 6, lane = threadIdx.x & 63;
    const int xcd = blockIdx.x & 7;
    const int j = blockIdx.x >> 3;            // 0..831
    const int b = (j / 416) * 8 + xcd;        // batch
    const int row = b * NN + (j % 416) * 2 + sub;
    const int h = t >> 4, k = t & 15;
    int nb = IDX[(size_t)row * 16 + k];
    int g = b * NN + nb;
    if (h == 0) gid_s[sub][k] = g;
    __syncthreads();
    #pragma unroll
    for (int i = 0; i < 4; i++) {
        int s0 = wave * 8 + i * 2;
        int s = s0 + (lane >> 5);
        int gs = gid_s[s >> 4][s & 15];
        int clog = (lane & 31) ^ (s & 7);
        GLOAD_LDS16(&QKV16[(size_t)gs * 768 + 256 + clog * 8], &Ks[s0][0]);
    }
    __syncthreads();
    const h16* q = &QKV16[(size_t)row * 768 + h * HDX];
    const int sidx = sub * 16 + k;
    float s = 0.f;
    #pragma unroll
    for (int c = 0; c < 4; c++) {
        h8v q8 = *(const h8v*)&q[c * 8];
        h8v k8 = *(const h8v*)&Ks[sidx][(((h * 4 + c) ^ (sidx & 7)) * 8)];
        #pragma unroll
        for (int e = 0; e < 8; e++) s += (float)q8[e] * (float)k8[e];
    }
    float m = s;
    #pragma unroll
    for (int off = 8; off; off >>= 1) m = fmaxf(m, __shfl_xor(m, off, 16));
    float e = expf(s - m);
    float sum = e;
    #pragma unroll
    for (int off = 8; off; off >>= 1) sum += __shfl_xor(sum, off, 16);
    p_s[sub][h][k] = e / sum;
    __syncthreads();
    const int d0 = t * 2;
    const int hh = d0 >> 5, dd = d0 & 31;
    float o0 = 0.f, o1 = 0.f;
    #pragma unroll
    for (int kk = 0; kk < 16; kk++) {
        int gg = gid_s[sub][kk];
        const h16* vr = &QKV16[(size_t)gg * 768 + 512 + hh * HDX + dd];
        float p = p_s[sub][hh][kk];
        o0 += p * (float)vr[0];
        o1 += p * (float)vr[1];
    }
    size_t base = (size_t)row * DD + d0;
    AO16[base] = (h16)o0;
    AO16[base + 1] = (h16)o1;
}

// ----------------------------------------------------------------
extern "C" void kernel_launch(void* const* d_in, const int* in_sizes, int n_in,
                              void* d_out, int out_size, void* d_ws, size_t ws_size,
                              hipStream_t stream)
{
    const float* obj      = (const float*)d_in[0];
    const float* mp       = (const float*)d_in[1];
    const float* opos     = (const float*)d_in[2];
    const float* mpos     = (const float*)d_in[3];
    const float* a_pre_w  = (const float*)d_in[4];
    const float* a_pre_b  = (const float*)d_in[5];
    const float* a_mlp_w1 = (const float*)d_in[6];
    const float* a_mlp_b1 = (const float*)d_in[7];
    const float* a_mlp_w2 = (const float*)d_in[8];
    const float* a_mlp_b2 = (const float*)d_in[9];
    const float* a_out_w1 = (const float*)d_in[10];
    const float* a_out_b1 = (const float*)d_in[11];
    const float* a_out_w2 = (const float*)d_in[12];
    const float* a_out_b2 = (const float*)d_in[13];
    const float* m_pre_w1 = (const float*)d_in[14];
    const float* m_pre_b1 = (const float*)d_in[15];
    const float* m_pre_w2 = (const float*)d_in[16];
    const float* m_pre_b2 = (const float*)d_in[17];
    const float* m_pre_w3 = (const float*)d_in[18];
    const float* m_pre_b3 = (const float*)d_in[19];
    const float* m_mlp_w1 = (const float*)d_in[20];
    const float* m_mlp_b1 = (const float*)d_in[21];
    const float* m_mlp_w2 = (const float*)d_in[22];
    const float* m_mlp_b2 = (const float*)d_in[23];
    const float* m_out_w1 = (const float*)d_in[24];
    const float* m_out_b1 = (const float*)d_in[25];
    const float* m_out_w2 = (const float*)d_in[26];
    const float* m_out_b2 = (const float*)d_in[27];
    const float* attn_wqkv = (const float*)d_in[28];
    const float* attn_bqkv = (const float*)d_in[29];
    const float* attn_wo   = (const float*)d_in[30];
    const float* attn_bo   = (const float*)d_in[31];
    const float* ffn_w1    = (const float*)d_in[32];
    const float* ffn_b1    = (const float*)d_in[33];
    const float* ffn_w2    = (const float*)d_in[34];
    const float* ffn_b2    = (const float*)d_in[35];
    const float* ln1_g     = (const float*)d_in[36];
    const float* ln1_b     = (const float*)d_in[37];
    const float* ln2_g     = (const float*)d_in[38];
    const float* ln2_b     = (const float*)d_in[39];

    const size_t M = MTOT;  // 13312
    float* ws   = (float*)d_ws;
    float* X    = ws;                 // M*256 f32 (pointnet out staging; pre-phase only)
    float* PEr  = X   + M * 256;      // PE16 region
    float* QKVr = PEr + M * 256;      // aliased region
    float* Hpad = QKVr + M * 768;     // padding region
    h16* AO16   = (h16*)(Hpad + M * 256);
    h16* X16    = AO16 + M * 256;
    h16* XP16   = X16  + M * 256;
    h16* H16    = XP16 + M * 256;
    h16* whf    = H16  + M * 256;     // 4,718,592 fp16
    h16* wpnf   = whf  + 4718592;
    int* IDX    = (int*)(wpnf + WPN_TOT);

    h16* PE16 = (h16*)PEr;
    h16* QKV16 = (h16*)QKVr;          // M*768 fp16 (live QKV-gemm..attn)

    // pointnet-phase aliases (QKVr..X16 dead window during pre-phase;
    // X16/XP16 written ONLY by split_x0 after all pointnet buffers are dead)
    h16* PN0f = (h16*)QKVr;           // pmap: MAPR*32 = 7,864,320 h16
    h16* PN1f = PN0f + 15728640;
    h16* SB   = PN0f + 31457280;
    h16* PLf  = SB;
    h16* GMf  = SB + 786432;
    h16* HVf  = SB + 1572864;
    h16* APLf = SB + 2359296;
    h16* AGMf = SB + 2621440;
    h16* AHVf = SB + 2883584;
    float* PCf = (float*)(SB + 3145728);
    float* APC = PCf + 786432;

    // ---------------- pre-phase ----------------
    knn_kernel<<<BB * 208, 256, 0, stream>>>(opos, mpos, IDX);
    prep_all<<<PRB_TOT, 256, 0, stream>>>(
        mp, obj, opos, mpos,
        attn_wqkv, attn_wo, ffn_w1, ffn_w2,
        m_pre_w1, m_pre_w2, m_pre_w3, m_mlp_w1, m_mlp_w2, m_out_w1, m_out_w2,
        a_pre_w, a_mlp_w1, a_mlp_w2, a_out_w1, a_out_w2,
        PN0f /*pmap*/, PN1f /*pagent*/, PE16, wpnf, whf);

    // ---- agent pointnet as GEMM chain (pagent staged in PN1f)
    {
        h16* PA32 = PN1f;
        h16* PB   = PN0f + 7864320;   // after pmap: [7.86M, 13.37M) h16
        h16* PA2  = PN1f;             // PA32 dead after first gemm
        gemm_pn<128, true, true, false><<<dim3(168, 2), 256, 0, stream>>>(
            PA32, wpnf + APW_O, a_pre_b, nullptr, 1, 0,
            nullptr, PB, 32, 256, 1, 0, 0);
        pool_max8<21><<<128, 256, 0, stream>>>(PB, APLf, 8);
        gemm_pn<128, false, false, false><<<dim3(8, 2), 256, 0, stream>>>(
            APLf, wpnf + AW1B_O, a_mlp_b1, nullptr, 1, 0,
            APC, nullptr, 256, 256, 1, 0, 0);
        gemm_pn<128, true, true, false><<<dim3(168, 2), 256, 0, stream>>>(
            PB, wpnf + AW1A_O, nullptr, APC, 21, 256,
            nullptr, PA2, 256, 256, 1, 0, 0);
        gemm_pn<128, true, true, false><<<dim3(168, 2), 256, 0, stream>>>(
            PA2, wpnf + AW2S_O, a_mlp_b2, nullptr, 1, 0,
            nullptr, PB, 256, 256, 1, 0, 0);
        pool_max8<21><<<128, 256, 0, stream>>>(PB, AGMf, 8);
        gemm_pn<128, true, true, false><<<dim3(8, 2), 256, 0, stream>>>(
            AGMf, wpnf + AOW1_O, a_out_b1, nullptr, 1, 0,
            nullptr, AHVf, 256, 256, 1, 0, 0);
        // agent out2 -> fp32 X: drow = row + (row/64)*768
        gemm_pn<128, false, false, true><<<dim3(8, 2), 256, 0, stream>>>(
            AHVf, wpnf + AOW2_O, a_out_b2, nullptr, 1, 0,
            X, nullptr, 256, 256, 64, 768, 0);
    }

    // ---- map pointnet: fused chains (pmap in PN0f)
    {
        fused_map3<<<MAPR / 128, 256, 0, stream>>>(
            PN0f, wpnf + W1P_O, wpnf + W2S_O, wpnf + W3S_O,
            m_pre_b1, m_pre_b2, m_pre_b3, PN1f);
        pool_max8<20><<<384, 256, 0, stream>>>(PN1f, PLf, 6);
        gemm_pn<64, false, false, false><<<dim3(96, 1), 256, 0, stream>>>(
            PLf, wpnf + MW1B_O, m_mlp_b1, nullptr, 1, 0,
            PCf, nullptr, 64, 64, 1, 0, 0);
        fused_map2<<<MAPR / 128, 256, 0, stream>>>(
            PN1f, wpnf + MW1A_O, wpnf + MW2S_O,
            m_mlp_b2, PCf, PN0f);
        pool_max8<20><<<384, 256, 0, stream>>>(PN0f, GMf, 6);
        gemm_pn<64, true, true, false><<<dim3(96, 1), 256, 0, stream>>>(
            GMf, wpnf + OW1S_O, m_out_b1, nullptr, 1, 0,
            nullptr, HVf, 64, 64, 1, 0, 0);
        // map out2 -> fp32 X: drow = row + 64 + (row/768)*64
        gemm_pn<128, false, false, true><<<dim3(96, 2), 256, 0, stream>>>(
            HVf, wpnf + OW2S_O, m_out_b2, nullptr, 1, 0,
            X, nullptr, 64, 256, 768, 64, 64);
    }

    // cvt X -> X16/XP16 (all pointnet scratch dead by stream order here)
    split_x0<<<(int)(M * 256 / 1024), 256, 0, stream>>>(X, PE16, X16, XP16);

    // ---------------- transformer layers ----------------
    const float scal = 0.17677669529663687f;  // 32^-0.5
    const int MB = MTOT / 128;  // 104
    for (int l = 0; l < LL; l++) {
        const size_t wb = (size_t)l * 786432;
        const h16* wqkv_f = whf + wb;
        const h16* wo_f   = whf + wb + 196608;
        const h16* f1_f   = whf + wb + 262144;
        const h16* f2_f   = whf + wb + 524288;
        const float* bqkv = attn_bqkv + (size_t)l * 768;
        gemm_mfma<false, true><<<dim3(MB, 6), 256, 0, stream>>>(
            XP16, X16, 512, wqkv_f, bqkv,
            nullptr, QKV16, 256, 768, 0, scal, 256);
        attn_kernel<<<MTOT / 2, 256, 0, stream>>>(QKV16, IDX, AO16);
        gemm_ln0<<<MTOT / 32, 512, 0, stream>>>(
            AO16, wo_f, attn_bo + (size_t)l * 256, X16,
            ln1_g + l * 256, ln1_b + l * 256, H16, 256);
        if (l == LL - 1) {
            fused_ffn<2><<<MTOT / 32, 512, 0, stream>>>(
                H16, f1_f, f2_f, ffn_b1 + (size_t)l * 1024, ffn_b2 + (size_t)l * 256,
                ln2_g + l * 256, ln2_b + l * 256,
                (float*)d_out, nullptr, nullptr, nullptr);
        } else {
            fused_ffn<1><<<MTOT / 32, 512, 0, stream>>>(
                H16, f1_f, f2_f, ffn_b1 + (size_t)l * 1024, ffn_b2 + (size_t)l * 256,
                ln2_g + l * 256, ln2_b + l * 256,
                nullptr, X16, PE16, XP16);
        }
    }
}

// Round 21
// 688.636 us; speedup vs baseline: 2.6098x; 1.0542x over previous
//
#include <hip/hip_runtime.h>
#include <hip/hip_bf16.h>

typedef unsigned short u16;
typedef _Float16 h16;

#define BB 16
#define NO 64
#define TT 21
#define NM 768
#define PP 20
#define CAx 29
#define CMx 9
#define DD 256
#define HH 8
#define LL 6
#define KK 16
#define NN (NO + NM)        // 832
#define HDX (DD / HH)       // 32
#define MTOT (BB * NN)      // 13312
#define MAPR (BB * NM * PP) // 245760 map point-rows

typedef __attribute__((ext_vector_type(8))) h16 h8v;
typedef __attribute__((ext_vector_type(4))) h16 h4v;
typedef __attribute__((ext_vector_type(4))) float f4v;

#define GLOAD_LDS16(gptr, lptr)                                                             \
    __builtin_amdgcn_global_load_lds(                                                       \
        (const __attribute__((address_space(1))) void*)(gptr),                              \
        (__attribute__((address_space(3))) void*)(lptr), 16, 0, 0)

// Bank-conflict swizzle for [rows][32]-fp16 linear tiles (gload_lds-compatible):
#define SWZ_LCOL(lane)   ((((lane) & 3) ^ (((lane) >> 3) & 3)) * 8)
#define SWZ_RD(kb, fr)   ((((kb) ^ (((fr) >> 1) & 3))) * 8)
#define SWZ_ELEM(row, kl) (((((kl) >> 3) ^ (((row) >> 1) & 3)) << 3) | ((kl) & 7))

// ---------------------------------------------------------------- KNN (top-16 smallest d2)
__global__ __launch_bounds__(256) void knn_kernel(
    const float* __restrict__ opos, const float* __restrict__ mpos, int* __restrict__ IDX)
{
    const int b = blockIdx.x / 208;
    const int blk = blockIdx.x % 208;
    __shared__ float px[NN], py[NN], pz[NN];
    for (int i = threadIdx.x; i < NN; i += 256) {
        const float* src = (i < NO) ? &opos[(size_t)(b * NO + i) * 3]
                                    : &mpos[(size_t)(b * NM + (i - NO)) * 3];
        px[i] = src[0]; py[i] = src[1]; pz[i] = src[2];
    }
    __syncthreads();
    const int wave = threadIdx.x >> 6, lane = threadIdx.x & 63;
    const int n = blk * 4 + wave;
    const float qx = px[n], qy = py[n], qz = pz[n];
    float d[13];
    #pragma unroll
    for (int s = 0; s < 13; s++) {
        int j = s * 64 + lane;
        float dx = qx - px[j], dy = qy - py[j], dz = qz - pz[j];
        d[s] = dx * dx + dy * dy + dz * dz;
    }
    int keep = 0;
    #pragma unroll
    for (int it = 0; it < 16; it++) {
        float bv = d[0]; int bs = 0;
        #pragma unroll
        for (int s = 1; s < 13; s++) { if (d[s] < bv) { bv = d[s]; bs = s; } }
        float v = bv; int jj = bs * 64 + lane;
        #pragma unroll
        for (int off = 32; off; off >>= 1) {
            float ov = __shfl_xor(v, off);
            int oj = __shfl_xor(jj, off);
            if (ov < v || (ov == v && oj < jj)) { v = ov; jj = oj; }
        }
        if (lane == (jj & 63)) {
            int sl = jj >> 6;
            #pragma unroll
            for (int s = 0; s < 13; s++) if (s == sl) d[s] = 3.4e38f;
        }
        if (lane == it) keep = jj;
    }
    if (lane < 16) IDX[((size_t)(b * NN + n)) * 16 + lane] = keep;
}

// ---------------------------------------------------------------- merged elementwise prep
#define PRB_MAP   30720
#define PRB_AG    (PRB_MAP + 2688)
#define PRB_PE    (PRB_AG + MTOT)
#define PRB_PN    (PRB_PE + 1480)
#define PRB_TOT   (PRB_PN + 18432)
#define W1P_O   0
#define W2S_O   2048
#define W3S_O   6144
#define MW1A_O  10240
#define MW1B_O  14336
#define MW2S_O  18432
#define OW1S_O  22528
#define OW2S_O  26624
#define APW_O   43008
#define AW1A_O  51200
#define AW1B_O  116736
#define AW2S_O  182272
#define AOW1_O  247808
#define AOW2_O  313344
#define WPN_TOT 378880
__global__ __launch_bounds__(256) void prep_all(
    const float* __restrict__ mp, const float* __restrict__ obj,
    const float* __restrict__ opos, const float* __restrict__ mpos,
    const float* __restrict__ wqkv, const float* __restrict__ wo,
    const float* __restrict__ f1w, const float* __restrict__ f2w,
    const float* __restrict__ m_pre_w1, const float* __restrict__ m_pre_w2,
    const float* __restrict__ m_pre_w3, const float* __restrict__ m_mlp_w1,
    const float* __restrict__ m_mlp_w2, const float* __restrict__ m_out_w1,
    const float* __restrict__ m_out_w2,
    const float* __restrict__ a_pre_w,  const float* __restrict__ a_mlp_w1,
    const float* __restrict__ a_mlp_w2, const float* __restrict__ a_out_w1,
    const float* __restrict__ a_out_w2,
    h16* __restrict__ pmap, h16* __restrict__ pagent,
    h16* __restrict__ PE16, h16* __restrict__ wpnf, h16* __restrict__ whf)
{
    const int bid = blockIdx.x;
    const int tid = threadIdx.x;
    if (bid < PRB_MAP) {
        int e = bid * 256 + tid;
        int r = e >> 5, c = e & 31;
        float v = (c < CMx) ? mp[(size_t)r * CMx + c] : 0.f;
        pmap[e] = (h16)v;
    } else if (bid < PRB_AG) {
        int e = (bid - PRB_MAP) * 256 + tid;
        int r = e >> 5, c = e & 31;
        float v = (c < CAx) ? obj[(size_t)r * CAx + c] : ((c == CAx) ? 1.0f : 0.f);
        pagent[e] = (h16)v;
    } else if (bid < PRB_PE) {
        int row = bid - PRB_AG;
        int b = row / NN, n = row % NN;
        const float* p = (n < NO) ? &opos[(size_t)(b * NO + n) * 3]
                                  : &mpos[(size_t)(b * NM + (n - NO)) * 3];
        float x = p[0], y = p[1];
        int j = tid & 127;
        float v = (tid < 128) ? y : x;
        float inv_dt = exp2f(-(float)(j & ~1) * 0.10381025296523f);
        float e = v * 6.283185307179586f * inv_dt;
        PE16[(size_t)row * DD + tid] = (h16)((j & 1) ? cosf(e) : sinf(e));
    } else if (bid < PRB_PN) {
        int e = (bid - PRB_PE) * 256 + tid;
        float v;
        if (e < W2S_O)       { int n = e >> 5, k = e & 31; v = (k < 9) ? m_pre_w1[n * 9 + k] : 0.f; }
        else if (e < W3S_O)  v = m_pre_w2[e - W2S_O];
        else if (e < MW1A_O) v = m_pre_w3[e - W3S_O];
        else if (e < MW1B_O) { int r = e - MW1A_O; v = m_mlp_w1[(r >> 6) * 128 + (r & 63)]; }
        else if (e < MW2S_O) { int r = e - MW1B_O; v = m_mlp_w1[(r >> 6) * 128 + 64 + (r & 63)]; }
        else if (e < OW1S_O) v = m_mlp_w2[e - MW2S_O];
        else if (e < OW2S_O) v = m_out_w1[e - OW1S_O];
        else if (e < APW_O)  v = m_out_w2[e - OW2S_O];
        else if (e < AW1A_O) { int r = e - APW_O; int n = r >> 5, k = r & 31; v = (k < 30) ? a_pre_w[n * 30 + k] : 0.f; }
        else if (e < AW1B_O) { int r = e - AW1A_O; v = a_mlp_w1[(r >> 8) * 512 + (r & 255)]; }
        else if (e < AW2S_O) { int r = e - AW1B_O; v = a_mlp_w1[(r >> 8) * 512 + 256 + (r & 255)]; }
        else if (e < AOW1_O) v = a_mlp_w2[e - AW2S_O];
        else if (e < AOW2_O) v = a_out_w1[e - AOW1_O];
        else                 v = a_out_w2[e - AOW2_O];
        wpnf[e] = (h16)v;
    } else {
        size_t e = (size_t)(bid - PRB_PN) * 256 + tid;
        int L = (int)(e / 786432);
        int r = (int)(e % 786432);
        float v;
        if (r < 196608)      v = wqkv[(size_t)L * 196608 + r];
        else if (r < 262144) v = wo[(size_t)L * 65536 + (r - 196608)];
        else if (r < 524288) v = f1w[(size_t)L * 262144 + (r - 262144)];
        else                 v = f2w[(size_t)L * 262144 + (r - 524288)];
        whf[e] = (h16)v;
    }
}

// ---------------------------------------------------------------- max-pool over P points, 8-wide
template<int P>
__global__ __launch_bounds__(256) void pool_max8(
    const h16* __restrict__ in, h16* __restrict__ out, int cshift)
{
    int e8 = blockIdx.x * 256 + threadIdx.x;
    int C = 1 << cshift;
    int base = e8 * 8;
    int g = base >> cshift, c = base & (C - 1);
    float m0 = -3.4e38f, m1 = m0, m2 = m0, m3 = m0, m4 = m0, m5 = m0, m6 = m0, m7 = m0;
    #pragma unroll
    for (int p = 0; p < P; p++) {
        h8v v = *(const h8v*)&in[((size_t)(g * P + p) << cshift) + c];
        m0 = fmaxf(m0, (float)v[0]); m1 = fmaxf(m1, (float)v[1]);
        m2 = fmaxf(m2, (float)v[2]); m3 = fmaxf(m3, (float)v[3]);
        m4 = fmaxf(m4, (float)v[4]); m5 = fmaxf(m5, (float)v[5]);
        m6 = fmaxf(m6, (float)v[6]); m7 = fmaxf(m7, (float)v[7]);
    }
    h8v o;
    o[0] = (h16)m0; o[1] = (h16)m1; o[2] = (h16)m2; o[3] = (h16)m3;
    o[4] = (h16)m4; o[5] = (h16)m5; o[6] = (h16)m6; o[7] = (h16)m7;
    *(h8v*)&out[((size_t)g << cshift) + c] = o;
}

// ---------------------------------------------------------------- pointnet GEMM (fp16 MFMA)
template<int BN, bool RELU, bool F16OUT, bool ROWMAP>
__global__ __launch_bounds__(256) void gemm_pn(
    const h16* __restrict__ A, const h16* __restrict__ W,
    const float* __restrict__ bias,
    const float* __restrict__ addrow, int ardiv, int arld,
    float* __restrict__ Cf, h16* __restrict__ C16,
    int K, int ldc, int rm_div, int rm_mul, int rm_add)
{
    constexpr int WAVES_M = (BN == 64) ? 4 : 2;
    constexpr int WM = 128 / (16 * WAVES_M);
    __shared__ __align__(16) h16 AS[128][32];
    __shared__ __align__(16) h16 WS[BN][32];
    const int m0 = blockIdx.x * 128;
    const int n0 = blockIdx.y * BN;
    const int tid = threadIdx.x;
    const int wave = tid >> 6, lane = tid & 63;
    const int wr = (BN == 64) ? wave : (wave >> 1);
    const int wc = (BN == 64) ? 0 : (wave & 1);
    const int fr = lane & 15, kb = lane >> 4;
    const int lrow = lane >> 2, lcol = SWZ_LCOL(lane);
    const int rdo = SWZ_RD(kb, fr);

    f4v acc[WM][4];
    #pragma unroll
    for (int i = 0; i < WM; i++)
        #pragma unroll
        for (int j = 0; j < 4; j++) { f4v z = {0.f, 0.f, 0.f, 0.f}; acc[i][j] = z; }

    for (int k0 = 0; k0 < K; k0 += 32) {
        __syncthreads();
        #pragma unroll
        for (int i = 0; i < 2; i++) {
            const int r = wave * 32 + i * 16;
            GLOAD_LDS16(&A[(size_t)(m0 + r + lrow) * K + k0 + lcol], &AS[r][0]);
        }
        if constexpr (BN == 64) {
            const int r = wave * 16;
            GLOAD_LDS16(&W[(size_t)(n0 + r + lrow) * K + k0 + lcol], &WS[r][0]);
        } else {
            #pragma unroll
            for (int i = 0; i < 2; i++) {
                const int r = wave * 32 + i * 16;
                GLOAD_LDS16(&W[(size_t)(n0 + r + lrow) * K + k0 + lcol], &WS[r][0]);
            }
        }
        __syncthreads();
        h8v af[WM];
        #pragma unroll
        for (int mi = 0; mi < WM; mi++)
            af[mi] = *(const h8v*)&AS[wr * (WM * 16) + mi * 16 + fr][rdo];
        #pragma unroll
        for (int nj = 0; nj < 4; nj++) {
            h8v bf = *(const h8v*)&WS[wc * 64 + nj * 16 + fr][rdo];
            #pragma unroll
            for (int mi = 0; mi < WM; mi++)
                acc[mi][nj] = __builtin_amdgcn_mfma_f32_16x16x32_f16(af[mi], bf, acc[mi][nj], 0, 0, 0);
        }
    }
    #pragma unroll
    for (int mi = 0; mi < WM; mi++) {
        #pragma unroll
        for (int nj = 0; nj < 4; nj++) {
            int col = n0 + wc * 64 + nj * 16 + fr;
            float bb = bias ? bias[col] : 0.f;
            #pragma unroll
            for (int r = 0; r < 4; r++) {
                int row = m0 + wr * (WM * 16) + mi * 16 + (lane >> 4) * 4 + r;
                float v = acc[mi][nj][r] + bb;
                if (addrow) v += addrow[(size_t)(row / ardiv) * arld + col];
                if (RELU) v = fmaxf(v, 0.f);
                if (F16OUT) {
                    C16[(size_t)row * ldc + col] = (h16)v;
                } else {
                    int drow = row;
                    if (ROWMAP) drow = row + rm_add + (row / rm_div) * rm_mul;
                    Cf[(size_t)drow * ldc + col] = v;
                }
            }
        }
    }
}

// ---------------------------------------------------------------- initial activation cvt
__global__ __launch_bounds__(256) void split_x0(
    const float* __restrict__ X, const h16* __restrict__ PE16,
    h16* __restrict__ X16, h16* __restrict__ XP16)
{
    size_t base = ((size_t)blockIdx.x * 256 + threadIdx.x) * 4;
    float4 x = *(const float4*)&X[base];
    h4v pe = *(const h4v*)&PE16[base];
    h4v a, b;
    a.x = (h16)x.x; a.y = (h16)x.y; a.z = (h16)x.z; a.w = (h16)x.w;
    b.x = (h16)(x.x + (float)pe.x); b.y = (h16)(x.y + (float)pe.y);
    b.z = (h16)(x.z + (float)pe.z); b.w = (h16)(x.w + (float)pe.w);
    *(h4v*)&X16[base] = a;
    *(h4v*)&XP16[base] = b;
}

// ---------------------------------------------------------------- fused map pre1->pre2->pre3
__global__ __launch_bounds__(256) void fused_map3(
    const h16* __restrict__ A,   // [MAPR][32]
    const h16* __restrict__ W1,  // [64][32]
    const h16* __restrict__ W2, const h16* __restrict__ W3,  // [64][64]
    const float* __restrict__ b1, const float* __restrict__ b2, const float* __restrict__ b3,
    h16* __restrict__ Out)       // [MAPR][64]
{
    __shared__ __align__(16) h16 AS[128][32];
    __shared__ __align__(16) h16 G0[2][128][32];
    __shared__ __align__(16) h16 G1[2][128][32];
    __shared__ __align__(16) h16 W1S[64][32];
    __shared__ __align__(16) h16 W2S[2][64][32];
    __shared__ __align__(16) h16 W3S[2][64][32];
    const int m0 = blockIdx.x * 128;
    const int tid = threadIdx.x;
    const int wave = tid >> 6, lane = tid & 63;
    const int fr = lane & 15, kb = lane >> 4;
    const int lrow = lane >> 2, lcol = SWZ_LCOL(lane);
    const int rdo = SWZ_RD(kb, fr);

    #pragma unroll
    for (int q = 0; q < 2; q++)
        GLOAD_LDS16(&A[(size_t)(m0 + wave * 32 + q * 16 + lrow) * 32 + lcol],
                    &AS[wave * 32 + q * 16][0]);
    GLOAD_LDS16(&W1[(size_t)(wave * 16 + lrow) * 32 + lcol], &W1S[wave * 16][0]);
    #pragma unroll
    for (int t = 0; t < 2; t++) {
        GLOAD_LDS16(&W2[(size_t)(wave * 16 + lrow) * 64 + t * 32 + lcol], &W2S[t][wave * 16][0]);
        GLOAD_LDS16(&W3[(size_t)(wave * 16 + lrow) * 64 + t * 32 + lcol], &W3S[t][wave * 16][0]);
    }
    __syncthreads();
    #pragma unroll
    for (int mi = 0; mi < 2; mi++) {
        h8v af = *(const h8v*)&AS[wave * 32 + mi * 16 + fr][rdo];
        #pragma unroll
        for (int nj = 0; nj < 4; nj++) {
            f4v a = {0.f, 0.f, 0.f, 0.f};
            h8v bf = *(const h8v*)&W1S[nj * 16 + fr][rdo];
            a = __builtin_amdgcn_mfma_f32_16x16x32_f16(af, bf, a, 0, 0, 0);
            int col = nj * 16 + fr, ch = col >> 5, kl = col & 31;
            float bb = b1[col];
            #pragma unroll
            for (int r = 0; r < 4; r++) {
                int row = wave * 32 + mi * 16 + kb * 4 + r;
                G0[ch][row][SWZ_ELEM(row, kl)] = (h16)fmaxf(a[r] + bb, 0.f);
            }
        }
    }
    __syncthreads();
    #pragma unroll
    for (int mi = 0; mi < 2; mi++) {
        #pragma unroll
        for (int nj = 0; nj < 4; nj++) {
            f4v a = {0.f, 0.f, 0.f, 0.f};
            #pragma unroll
            for (int t = 0; t < 2; t++) {
                h8v af = *(const h8v*)&G0[t][wave * 32 + mi * 16 + fr][rdo];
                h8v bf = *(const h8v*)&W2S[t][nj * 16 + fr][rdo];
                a = __builtin_amdgcn_mfma_f32_16x16x32_f16(af, bf, a, 0, 0, 0);
            }
            int col = nj * 16 + fr, ch = col >> 5, kl = col & 31;
            float bb = b2[col];
            #pragma unroll
            for (int r = 0; r < 4; r++) {
                int row = wave * 32 + mi * 16 + kb * 4 + r;
                G1[ch][row][SWZ_ELEM(row, kl)] = (h16)fmaxf(a[r] + bb, 0.f);
            }
        }
    }
    __syncthreads();
    #pragma unroll
    for (int mi = 0; mi < 2; mi++) {
        #pragma unroll
        for (int nj = 0; nj < 4; nj++) {
            f4v a = {0.f, 0.f, 0.f, 0.f};
            #pragma unroll
            for (int t = 0; t < 2; t++) {
                h8v af = *(const h8v*)&G1[t][wave * 32 + mi * 16 + fr][rdo];
                h8v bf = *(const h8v*)&W3S[t][nj * 16 + fr][rdo];
                a = __builtin_amdgcn_mfma_f32_16x16x32_f16(af, bf, a, 0, 0, 0);
            }
            int col = nj * 16 + fr;
            float bb = b3[col];
            #pragma unroll
            for (int r = 0; r < 4; r++) {
                int row = m0 + wave * 32 + mi * 16 + kb * 4 + r;
                Out[(size_t)row * 64 + col] = (h16)fmaxf(a[r] + bb, 0.f);
            }
        }
    }
}

// ---------------------------------------------------------------- fused map mid1->mid2
// mid1 bias b1 is carried entirely by `pooled` (PCf = pooled@W1B + b1).
__global__ __launch_bounds__(256) void fused_map2(
    const h16* __restrict__ A,   // [MAPR][64]
    const h16* __restrict__ W1,  // MW1A [64][64]
    const h16* __restrict__ W2,  // MW2S [64][64]
    const float* __restrict__ b2,
    const float* __restrict__ pooled,  // PCf [12288][64] f32 (includes b1)
    h16* __restrict__ Out)       // [MAPR][64]
{
    __shared__ __align__(16) h16 AS[2][128][32];
    __shared__ __align__(16) h16 G0[2][128][32];
    __shared__ __align__(16) h16 W1S[2][64][32];
    __shared__ __align__(16) h16 W2S[2][64][32];
    const int m0 = blockIdx.x * 128;
    const int tid = threadIdx.x;
    const int wave = tid >> 6, lane = tid & 63;
    const int fr = lane & 15, kb = lane >> 4;
    const int lrow = lane >> 2, lcol = SWZ_LCOL(lane);
    const int rdo = SWZ_RD(kb, fr);

    #pragma unroll
    for (int t = 0; t < 2; t++) {
        #pragma unroll
        for (int q = 0; q < 2; q++)
            GLOAD_LDS16(&A[(size_t)(m0 + wave * 32 + q * 16 + lrow) * 64 + t * 32 + lcol],
                        &AS[t][wave * 32 + q * 16][0]);
        GLOAD_LDS16(&W1[(size_t)(wave * 16 + lrow) * 64 + t * 32 + lcol], &W1S[t][wave * 16][0]);
        GLOAD_LDS16(&W2[(size_t)(wave * 16 + lrow) * 64 + t * 32 + lcol], &W2S[t][wave * 16][0]);
    }
    __syncthreads();
    #pragma unroll
    for (int mi = 0; mi < 2; mi++) {
        #pragma unroll
        for (int nj = 0; nj < 4; nj++) {
            f4v a = {0.f, 0.f, 0.f, 0.f};
            #pragma unroll
            for (int t = 0; t < 2; t++) {
                h8v af = *(const h8v*)&AS[t][wave * 32 + mi * 16 + fr][rdo];
                h8v bf = *(const h8v*)&W1S[t][nj * 16 + fr][rdo];
                a = __builtin_amdgcn_mfma_f32_16x16x32_f16(af, bf, a, 0, 0, 0);
            }
            int col = nj * 16 + fr, ch = col >> 5, kl = col & 31;
            #pragma unroll
            for (int r = 0; r < 4; r++) {
                int row = wave * 32 + mi * 16 + kb * 4 + r;
                int grow = m0 + row;
                float v = a[r] + pooled[(size_t)(grow / PP) * 64 + col];
                G0[ch][row][SWZ_ELEM(row, kl)] = (h16)fmaxf(v, 0.f);
            }
        }
    }
    __syncthreads();
    #pragma unroll
    for (int mi = 0; mi < 2; mi++) {
        #pragma unroll
        for (int nj = 0; nj < 4; nj++) {
            f4v a = {0.f, 0.f, 0.f, 0.f};
            #pragma unroll
            for (int t = 0; t < 2; t++) {
                h8v af = *(const h8v*)&G0[t][wave * 32 + mi * 16 + fr][rdo];
                h8v bf = *(const h8v*)&W2S[t][nj * 16 + fr][rdo];
                a = __builtin_amdgcn_mfma_f32_16x16x32_f16(af, bf, a, 0, 0, 0);
            }
            int col = nj * 16 + fr;
            float bb = b2[col];
            #pragma unroll
            for (int r = 0; r < 4; r++) {
                int row = m0 + wave * 32 + mi * 16 + kb * 4 + r;
                Out[(size_t)row * 64 + col] = (h16)fmaxf(a[r] + bb, 0.f);
            }
        }
    }
}

// ---------------------------------------------------------------- transformer fp16 MFMA GEMM
template<bool RELU, bool F16OUT>
__global__ __launch_bounds__(256) void gemm_mfma(
    const h16* __restrict__ A, const h16* __restrict__ A2, int a2min,
    const h16* __restrict__ W, const float* __restrict__ bias,
    float* __restrict__ Cf, h16* __restrict__ C16,
    int K, int ldc, int coff, float scale, int scale_until)
{
    __shared__ __align__(16) h16 AS[128][32];
    __shared__ __align__(16) h16 WS[128][32];
    const int m0 = blockIdx.x * 128;
    const int n0 = blockIdx.y * 128;
    const h16* pA = (n0 >= a2min) ? A2 : A;
    const int tid = threadIdx.x;
    const int wave = tid >> 6, lane = tid & 63;
    const int wr = wave >> 1, wc = wave & 1;
    const int fr = lane & 15, kb = lane >> 4;
    const int lrow = lane >> 2;
    const int lcol = SWZ_LCOL(lane);
    const int rdo = SWZ_RD(kb, fr);

    f4v acc[4][4];
    #pragma unroll
    for (int i = 0; i < 4; i++)
        #pragma unroll
        for (int j = 0; j < 4; j++) { f4v z = {0.f, 0.f, 0.f, 0.f}; acc[i][j] = z; }

    for (int k0 = 0; k0 < K; k0 += 32) {
        __syncthreads();
        #pragma unroll
        for (int i = 0; i < 2; i++) {
            const int r = wave * 32 + i * 16;
            const size_t grow = (size_t)(r + lrow);
            GLOAD_LDS16(&pA[(m0 + grow) * K + k0 + lcol], &AS[r][0]);
            GLOAD_LDS16(&W [(n0 + grow) * K + k0 + lcol], &WS[r][0]);
        }
        __syncthreads();
        h8v af[4];
        #pragma unroll
        for (int mi = 0; mi < 4; mi++)
            af[mi] = *(const h8v*)&AS[wr * 64 + mi * 16 + fr][rdo];
        #pragma unroll
        for (int nj = 0; nj < 4; nj++) {
            h8v bf = *(const h8v*)&WS[wc * 64 + nj * 16 + fr][rdo];
            #pragma unroll
            for (int mi = 0; mi < 4; mi++)
                acc[mi][nj] = __builtin_amdgcn_mfma_f32_16x16x32_f16(af[mi], bf, acc[mi][nj], 0, 0, 0);
        }
    }
    #pragma unroll
    for (int mi = 0; mi < 4; mi++) {
        #pragma unroll
        for (int nj = 0; nj < 4; nj++) {
            int col = n0 + wc * 64 + nj * 16 + fr;
            float bb = bias[col];
            #pragma unroll
            for (int r = 0; r < 4; r++) {
                int row = m0 + wr * 64 + mi * 16 + (lane >> 4) * 4 + r;
                float v = acc[mi][nj][r] + bb;
                if (RELU) v = fmaxf(v, 0.f);
                int gcol = coff + col;
                if (gcol < scale_until) v *= scale;
                if (F16OUT) {
                    C16[(size_t)row * ldc + gcol] = (h16)v;
                } else {
                    Cf[(size_t)row * ldc + gcol] = v;
                }
            }
        }
    }
}

// ---------------------------------------------------------------- fused O-proj+LN1+FFN1+FFN2+LN2
// 32 rows/block, 8 waves. AO tile + post-LN H tile resident in LDS; no H global round-trip.
// PEMODE 1: write X16 + XP16(=h16(o+PE)).  PEMODE 2: write fp32 d_out.
template<int PEMODE>
__global__ __launch_bounds__(512) void fused_layer(
    const h16* __restrict__ AO16, const h16* __restrict__ Wo,   // [256][256]
    const float* __restrict__ bo, const h16* __restrict__ X16r,
    const float* __restrict__ g1, const float* __restrict__ bt1,
    const h16* __restrict__ W1,   // [1024][256]
    const h16* __restrict__ W2,   // [256][1024]
    const float* __restrict__ b1, const float* __restrict__ b2,
    const float* __restrict__ g2, const float* __restrict__ bt2,
    float* __restrict__ OutF, h16* __restrict__ O16,
    const h16* __restrict__ PE16p, h16* __restrict__ P16)
{
    __shared__ __align__(16) h16 AOS[8][32][32];   // 16 KB: AO tile (k-tiles)
    __shared__ __align__(16) h16 HS[8][32][32];    // 16 KB: post-LN h (col-chunk tiles)
    __shared__ __align__(16) h16 GS[2][32][32];    // 4 KB
    __shared__ __align__(16) h16 WSu[16384];       // 32 KB: Wo/W1/W2 chunk union
    __shared__ float red_s[2][8][32];
    const int m0 = blockIdx.x * 32;
    const int tid = threadIdx.x;
    const int wave = tid >> 6, lane = tid & 63;
    const int fr = lane & 15, kb = lane >> 4;
    const int lrow = lane >> 2, lcol = SWZ_LCOL(lane);
    const int rdo = SWZ_RD(kb, fr);
    const int mi1 = wave >> 2, nj1 = wave & 3;

    // stage AO tile: wave w -> k-tile t=w
    #pragma unroll
    for (int q = 0; q < 2; q++)
        GLOAD_LDS16(&AO16[(size_t)(m0 + q * 16 + lrow) * 256 + wave * 32 + lcol],
                    &AOS[wave][q * 16][0]);

    // ---- stage 0: O-proj (4 col-chunks of 64) + residual(X16r) + LN1 stats
    float xo[4][4];
    float rsum1[4] = {0.f, 0.f, 0.f, 0.f}, rsq1[4] = {0.f, 0.f, 0.f, 0.f};
    #pragma unroll
    for (int oc = 0; oc < 4; oc++) {
        __syncthreads();   // WSu free
        #pragma unroll
        for (int q = 0; q < 4; q++)
            GLOAD_LDS16(&Wo[(size_t)(oc * 64 + q * 16 + lrow) * 256 + wave * 32 + lcol],
                        &WSu[wave * 2048 + (q * 16) * 32]);
        __syncthreads();   // Wo chunk (and first-iter AOS) visible
        f4v o1 = {0.f, 0.f, 0.f, 0.f};
        #pragma unroll
        for (int t = 0; t < 8; t++) {
            h8v af = *(const h8v*)&AOS[t][mi1 * 16 + fr][rdo];
            h8v bf = *(const h8v*)&WSu[t * 2048 + (nj1 * 16 + fr) * 32 + rdo];
            o1 = __builtin_amdgcn_mfma_f32_16x16x32_f16(af, bf, o1, 0, 0, 0);
        }
        int col = oc * 64 + nj1 * 16 + fr;
        float bb = bo[col];
        #pragma unroll
        for (int r = 0; r < 4; r++) {
            int row = mi1 * 16 + kb * 4 + r;
            float v = o1[r] + bb + (float)X16r[(size_t)(m0 + row) * 256 + col];
            xo[oc][r] = v;
            rsum1[r] += v;
            rsq1[r] += v * v;
        }
    }
    #pragma unroll
    for (int off = 1; off < 16; off <<= 1)
        #pragma unroll
        for (int r = 0; r < 4; r++) {
            rsum1[r] += __shfl_xor(rsum1[r], off);
            rsq1[r]  += __shfl_xor(rsq1[r], off);
        }
    if (fr == 0) {
        #pragma unroll
        for (int r = 0; r < 4; r++) {
            red_s[0][wave][mi1 * 16 + kb * 4 + r] = rsum1[r];
            red_s[1][wave][mi1 * 16 + kb * 4 + r] = rsq1[r];
        }
    } else if (fr == 1) {
        #pragma unroll
        for (int r = 0; r < 4; r++) {
            red_s[0][wave][(1 - mi1) * 16 + kb * 4 + r] = 0.f;
            red_s[1][wave][(1 - mi1) * 16 + kb * 4 + r] = 0.f;
        }
    }
    __syncthreads();
    float mean1[4], inv1[4];
    #pragma unroll
    for (int r = 0; r < 4; r++) {
        int rid = mi1 * 16 + kb * 4 + r;
        float s = 0.f, sq = 0.f;
        #pragma unroll
        for (int w = 0; w < 8; w++) { s += red_s[0][w][rid]; sq += red_s[1][w][rid]; }
        mean1[r] = s * (1.f / 256.f);
        float var = sq * (1.f / 256.f) - mean1[r] * mean1[r];
        inv1[r] = rsqrtf(var + 1e-5f);
    }
    // write h = LN1(xo) into HS (col-chunk tile layout)
    #pragma unroll
    for (int oc = 0; oc < 4; oc++) {
        int col = oc * 64 + nj1 * 16 + fr;
        int ch = col >> 5, kl = col & 31;
        float gg = g1[col], bb = bt1[col];
        #pragma unroll
        for (int r = 0; r < 4; r++) {
            int row = mi1 * 16 + kb * 4 + r;
            float h = (xo[oc][r] - mean1[r]) * inv1[r] * gg + bb;
            HS[ch][row][SWZ_ELEM(row, kl)] = (h16)h;
        }
    }
    __syncthreads();   // HS ready; Wo reads done

    // ---- stage 1+2: FFN (hidden chunked by 64) accumulating acc2
    f4v acc2[2][2];
    #pragma unroll
    for (int i = 0; i < 2; i++)
        #pragma unroll
        for (int j = 0; j < 2; j++) { f4v z = {0.f, 0.f, 0.f, 0.f}; acc2[i][j] = z; }

    for (int c = 0; c < 16; c++) {
        const int H0 = c * 64;
        __syncthreads();
        #pragma unroll
        for (int q = 0; q < 4; q++)
            GLOAD_LDS16(&W1[(size_t)(H0 + q * 16 + lrow) * 256 + wave * 32 + lcol],
                        &WSu[wave * 2048 + (q * 16) * 32]);
        __syncthreads();
        f4v a1 = {0.f, 0.f, 0.f, 0.f};
        #pragma unroll
        for (int t = 0; t < 8; t++) {
            h8v af = *(const h8v*)&HS[t][mi1 * 16 + fr][rdo];
            h8v bf = *(const h8v*)&WSu[t * 2048 + (nj1 * 16 + fr) * 32 + rdo];
            a1 = __builtin_amdgcn_mfma_f32_16x16x32_f16(af, bf, a1, 0, 0, 0);
        }
        {
            int col = nj1 * 16 + fr, ch = col >> 5, kl = col & 31;
            float bb = b1[H0 + col];
            #pragma unroll
            for (int r = 0; r < 4; r++) {
                int row = mi1 * 16 + kb * 4 + r;
                GS[ch][row][SWZ_ELEM(row, kl)] = (h16)fmaxf(a1[r] + bb, 0.f);
            }
        }
        __syncthreads();
        #pragma unroll
        for (int t2 = 0; t2 < 2; t2++)
            #pragma unroll
            for (int q = 0; q < 2; q++)
                GLOAD_LDS16(&W2[(size_t)(wave * 32 + q * 16 + lrow) * 1024 + H0 + t2 * 32 + lcol],
                            &WSu[t2 * 8192 + (wave * 32 + q * 16) * 32]);
        __syncthreads();
        #pragma unroll
        for (int t2 = 0; t2 < 2; t2++) {
            #pragma unroll
            for (int mi = 0; mi < 2; mi++) {
                h8v af = *(const h8v*)&GS[t2][mi * 16 + fr][rdo];
                #pragma unroll
                for (int nj = 0; nj < 2; nj++) {
                    h8v bf = *(const h8v*)&WSu[t2 * 8192 + (wave * 32 + nj * 16 + fr) * 32 + rdo];
                    acc2[mi][nj] = __builtin_amdgcn_mfma_f32_16x16x32_f16(af, bf, acc2[mi][nj], 0, 0, 0);
                }
            }
        }
    }
    // ---- epilogue: x = h-residual(HS) + acc2 + b2; LN2; write
    float x[2][2][4];
    float rsum[2][4], rsq[2][4];
    #pragma unroll
    for (int mi = 0; mi < 2; mi++)
        #pragma unroll
        for (int r = 0; r < 4; r++) { rsum[mi][r] = 0.f; rsq[mi][r] = 0.f; }
    #pragma unroll
    for (int mi = 0; mi < 2; mi++) {
        #pragma unroll
        for (int nj = 0; nj < 2; nj++) {
            int col = wave * 32 + nj * 16 + fr;
            int ch = col >> 5, kl = col & 31;
            float bb = b2[col];
            #pragma unroll
            for (int r = 0; r < 4; r++) {
                int row = mi * 16 + kb * 4 + r;
                float res = (float)HS[ch][row][SWZ_ELEM(row, kl)];
                float v = acc2[mi][nj][r] + bb + res;
                x[mi][nj][r] = v;
                rsum[mi][r] += v;
                rsq[mi][r] += v * v;
            }
        }
    }
    #pragma unroll
    for (int off = 1; off < 16; off <<= 1) {
        #pragma unroll
        for (int mi = 0; mi < 2; mi++)
            #pragma unroll
            for (int r = 0; r < 4; r++) {
                rsum[mi][r] += __shfl_xor(rsum[mi][r], off);
                rsq[mi][r]  += __shfl_xor(rsq[mi][r], off);
            }
    }
    __syncthreads();   // red_s free from LN1
    if (fr == 0) {
        #pragma unroll
        for (int mi = 0; mi < 2; mi++)
            #pragma unroll
            for (int r = 0; r < 4; r++) {
                int rid = mi * 16 + kb * 4 + r;
                red_s[0][wave][rid] = rsum[mi][r];
                red_s[1][wave][rid] = rsq[mi][r];
            }
    }
    __syncthreads();
    #pragma unroll
    for (int mi = 0; mi < 2; mi++) {
        #pragma unroll
        for (int r = 0; r < 4; r++) {
            int rid = mi * 16 + kb * 4 + r;
            float s = 0.f, sq = 0.f;
            #pragma unroll
            for (int w = 0; w < 8; w++) { s += red_s[0][w][rid]; sq += red_s[1][w][rid]; }
            float mean = s * (1.f / 256.f);
            float var = sq * (1.f / 256.f) - mean * mean;
            float inv = rsqrtf(var + 1e-5f);
            #pragma unroll
            for (int nj = 0; nj < 2; nj++) {
                int col = wave * 32 + nj * 16 + fr;
                float o = (x[mi][nj][r] - mean) * inv * g2[col] + bt2[col];
                size_t idx = (size_t)(m0 + rid) * 256 + col;
                if (PEMODE == 2) {
                    OutF[idx] = o;
                } else {
                    O16[idx] = (h16)o;
                    P16[idx] = (h16)(o + (float)PE16p[idx]);
                }
            }
        }
    }
}

// ---------------------------------------------------------------- local KNN attention (fp16 QKV)
__global__ __launch_bounds__(256) void attn_kernel(
    const h16* __restrict__ QKV16, const int* __restrict__ IDX,
    h16* __restrict__ AO16)
{
    __shared__ __align__(16) h16 Ks[32][256];
    __shared__ float p_s[2][HH][16];
    __shared__ int gid_s[2][16];
    const int sub = threadIdx.x >> 7;
    const int t = threadIdx.x & 127;
    const int wave = threadIdx.x >> 6, lane = threadIdx.x & 63;
    const int xcd = blockIdx.x & 7;
    const int j = blockIdx.x >> 3;            // 0..831
    const int b = (j / 416) * 8 + xcd;        // batch
    const int row = b * NN + (j % 416) * 2 + sub;
    const int h = t >> 4, k = t & 15;
    int nb = IDX[(size_t)row * 16 + k];
    int g = b * NN + nb;
    if (h == 0) gid_s[sub][k] = g;
    __syncthreads();
    #pragma unroll
    for (int i = 0; i < 4; i++) {
        int s0 = wave * 8 + i * 2;
        int s = s0 + (lane >> 5);
        int gs = gid_s[s >> 4][s & 15];
        int clog = (lane & 31) ^ (s & 7);
        GLOAD_LDS16(&QKV16[(size_t)gs * 768 + 256 + clog * 8], &Ks[s0][0]);
    }
    __syncthreads();
    const h16* q = &QKV16[(size_t)row * 768 + h * HDX];
    const int sidx = sub * 16 + k;
    float s = 0.f;
    #pragma unroll
    for (int c = 0; c < 4; c++) {
        h8v q8 = *(const h8v*)&q[c * 8];
        h8v k8 = *(const h8v*)&Ks[sidx][(((h * 4 + c) ^ (sidx & 7)) * 8)];
        #pragma unroll
        for (int e = 0; e < 8; e++) s += (float)q8[e] * (float)k8[e];
    }
    float m = s;
    #pragma unroll
    for (int off = 8; off; off >>= 1) m = fmaxf(m, __shfl_xor(m, off, 16));
    float e = expf(s - m);
    float sum = e;
    #pragma unroll
    for (int off = 8; off; off >>= 1) sum += __shfl_xor(sum, off, 16);
    p_s[sub][h][k] = e / sum;
    __syncthreads();
    const int d0 = t * 2;
    const int hh = d0 >> 5, dd = d0 & 31;
    float o0 = 0.f, o1 = 0.f;
    #pragma unroll
    for (int kk = 0; kk < 16; kk++) {
        int gg = gid_s[sub][kk];
        const h16* vr = &QKV16[(size_t)gg * 768 + 512 + hh * HDX + dd];
        float p = p_s[sub][hh][kk];
        o0 += p * (float)vr[0];
        o1 += p * (float)vr[1];
    }
    size_t base = (size_t)row * DD + d0;
    AO16[base] = (h16)o0;
    AO16[base + 1] = (h16)o1;
}

// ----------------------------------------------------------------
extern "C" void kernel_launch(void* const* d_in, const int* in_sizes, int n_in,
                              void* d_out, int out_size, void* d_ws, size_t ws_size,
                              hipStream_t stream)
{
    const float* obj      = (const float*)d_in[0];
    const float* mp       = (const float*)d_in[1];
    const float* opos     = (const float*)d_in[2];
    const float* mpos     = (const float*)d_in[3];
    const float* a_pre_w  = (const float*)d_in[4];
    const float* a_pre_b  = (const float*)d_in[5];
    const float* a_mlp_w1 = (const float*)d_in[6];
    const float* a_mlp_b1 = (const float*)d_in[7];
    const float* a_mlp_w2 = (const float*)d_in[8];
    const float* a_mlp_b2 = (const float*)d_in[9];
    const float* a_out_w1 = (const float*)d_in[10];
    const float* a_out_b1 = (const float*)d_in[11];
    const float* a_out_w2 = (const float*)d_in[12];
    const float* a_out_b2 = (const float*)d_in[13];
    const float* m_pre_w1 = (const float*)d_in[14];
    const float* m_pre_b1 = (const float*)d_in[15];
    const float* m_pre_w2 = (const float*)d_in[16];
    const float* m_pre_b2 = (const float*)d_in[17];
    const float* m_pre_w3 = (const float*)d_in[18];
    const float* m_pre_b3 = (const float*)d_in[19];
    const float* m_mlp_w1 = (const float*)d_in[20];
    const float* m_mlp_b1 = (const float*)d_in[21];
    const float* m_mlp_w2 = (const float*)d_in[22];
    const float* m_mlp_b2 = (const float*)d_in[23];
    const float* m_out_w1 = (const float*)d_in[24];
    const float* m_out_b1 = (const float*)d_in[25];
    const float* m_out_w2 = (const float*)d_in[26];
    const float* m_out_b2 = (const float*)d_in[27];
    const float* attn_wqkv = (const float*)d_in[28];
    const float* attn_bqkv = (const float*)d_in[29];
    const float* attn_wo   = (const float*)d_in[30];
    const float* attn_bo   = (const float*)d_in[31];
    const float* ffn_w1    = (const float*)d_in[32];
    const float* ffn_b1    = (const float*)d_in[33];
    const float* ffn_w2    = (const float*)d_in[34];
    const float* ffn_b2    = (const float*)d_in[35];
    const float* ln1_g     = (const float*)d_in[36];
    const float* ln1_b     = (const float*)d_in[37];
    const float* ln2_g     = (const float*)d_in[38];
    const float* ln2_b     = (const float*)d_in[39];

    const size_t M = MTOT;  // 13312
    float* ws   = (float*)d_ws;
    float* X    = ws;                 // M*256 f32 (pointnet out staging)
    float* PEr  = X   + M * 256;      // PE16 region
    float* QKVr = PEr + M * 256;      // aliased region
    float* Hpad = QKVr + M * 768;     // padding region
    h16* AO16   = (h16*)(Hpad + M * 256);
    h16* X16    = AO16 + M * 256;
    h16* XP16   = X16  + M * 256;
    h16* H16    = XP16 + M * 256;     // unused now (layout stability)
    h16* whf    = H16  + M * 256;     // 4,718,592 fp16
    h16* wpnf   = whf  + 4718592;
    int* IDX    = (int*)(wpnf + WPN_TOT);

    h16* PE16 = (h16*)PEr;
    h16* QKV16 = (h16*)QKVr;          // M*768 fp16 (live QKV-gemm..attn)

    // pointnet-phase aliases (QKVr..AO16 dead window during pre-phase;
    // X16/XP16 written ONLY by split_x0 after all pointnet buffers are dead)
    h16* PN0f = (h16*)QKVr;
    h16* PN1f = PN0f + 15728640;
    h16* SB   = PN0f + 31457280;
    h16* PLf  = SB;
    h16* GMf  = SB + 786432;
    h16* HVf  = SB + 1572864;
    h16* APLf = SB + 2359296;
    h16* AGMf = SB + 2621440;
    h16* AHVf = SB + 2883584;
    float* PCf = (float*)(SB + 3145728);
    float* APC = PCf + 786432;

    // ---------------- pre-phase ----------------
    knn_kernel<<<BB * 208, 256, 0, stream>>>(opos, mpos, IDX);
    prep_all<<<PRB_TOT, 256, 0, stream>>>(
        mp, obj, opos, mpos,
        attn_wqkv, attn_wo, ffn_w1, ffn_w2,
        m_pre_w1, m_pre_w2, m_pre_w3, m_mlp_w1, m_mlp_w2, m_out_w1, m_out_w2,
        a_pre_w, a_mlp_w1, a_mlp_w2, a_out_w1, a_out_w2,
        PN0f /*pmap*/, PN1f /*pagent*/, PE16, wpnf, whf);

    // ---- agent pointnet as GEMM chain (pagent staged in PN1f)
    {
        h16* PA32 = PN1f;
        h16* PB   = PN0f + 7864320;
        h16* PA2  = PN1f;
        gemm_pn<128, true, true, false><<<dim3(168, 2), 256, 0, stream>>>(
            PA32, wpnf + APW_O, a_pre_b, nullptr, 1, 0,
            nullptr, PB, 32, 256, 1, 0, 0);
        pool_max8<21><<<128, 256, 0, stream>>>(PB, APLf, 8);
        gemm_pn<128, false, false, false><<<dim3(8, 2), 256, 0, stream>>>(
            APLf, wpnf + AW1B_O, a_mlp_b1, nullptr, 1, 0,
            APC, nullptr, 256, 256, 1, 0, 0);
        gemm_pn<128, true, true, false><<<dim3(168, 2), 256, 0, stream>>>(
            PB, wpnf + AW1A_O, nullptr, APC, 21, 256,
            nullptr, PA2, 256, 256, 1, 0, 0);
        gemm_pn<128, true, true, false><<<dim3(168, 2), 256, 0, stream>>>(
            PA2, wpnf + AW2S_O, a_mlp_b2, nullptr, 1, 0,
            nullptr, PB, 256, 256, 1, 0, 0);
        pool_max8<21><<<128, 256, 0, stream>>>(PB, AGMf, 8);
        gemm_pn<128, true, true, false><<<dim3(8, 2), 256, 0, stream>>>(
            AGMf, wpnf + AOW1_O, a_out_b1, nullptr, 1, 0,
            nullptr, AHVf, 256, 256, 1, 0, 0);
        gemm_pn<128, false, false, true><<<dim3(8, 2), 256, 0, stream>>>(
            AHVf, wpnf + AOW2_O, a_out_b2, nullptr, 1, 0,
            X, nullptr, 256, 256, 64, 768, 0);
    }

    // ---- map pointnet: fused chains (pmap in PN0f)
    {
        fused_map3<<<MAPR / 128, 256, 0, stream>>>(
            PN0f, wpnf + W1P_O, wpnf + W2S_O, wpnf + W3S_O,
            m_pre_b1, m_pre_b2, m_pre_b3, PN1f);
        pool_max8<20><<<384, 256, 0, stream>>>(PN1f, PLf, 6);
        gemm_pn<64, false, false, false><<<dim3(96, 1), 256, 0, stream>>>(
            PLf, wpnf + MW1B_O, m_mlp_b1, nullptr, 1, 0,
            PCf, nullptr, 64, 64, 1, 0, 0);
        fused_map2<<<MAPR / 128, 256, 0, stream>>>(
            PN1f, wpnf + MW1A_O, wpnf + MW2S_O,
            m_mlp_b2, PCf, PN0f);
        pool_max8<20><<<384, 256, 0, stream>>>(PN0f, GMf, 6);
        gemm_pn<64, true, true, false><<<dim3(96, 1), 256, 0, stream>>>(
            GMf, wpnf + OW1S_O, m_out_b1, nullptr, 1, 0,
            nullptr, HVf, 64, 64, 1, 0, 0);
        gemm_pn<128, false, false, true><<<dim3(96, 2), 256, 0, stream>>>(
            HVf, wpnf + OW2S_O, m_out_b2, nullptr, 1, 0,
            X, nullptr, 64, 256, 768, 64, 64);
    }

    split_x0<<<(int)(M * 256 / 1024), 256, 0, stream>>>(X, PE16, X16, XP16);

    // ---------------- transformer layers (3 dispatches/layer) ----------------
    const float scal = 0.17677669529663687f;  // 32^-0.5
    const int MB = MTOT / 128;  // 104
    for (int l = 0; l < LL; l++) {
        const size_t wb = (size_t)l * 786432;
        const h16* wqkv_f = whf + wb;
        const h16* wo_f   = whf + wb + 196608;
        const h16* f1_f   = whf + wb + 262144;
        const h16* f2_f   = whf + wb + 524288;
        const float* bqkv = attn_bqkv + (size_t)l * 768;
        gemm_mfma<false, true><<<dim3(MB, 6), 256, 0, stream>>>(
            XP16, X16, 512, wqkv_f, bqkv,
            nullptr, QKV16, 256, 768, 0, scal, 256);
        attn_kernel<<<MTOT / 2, 256, 0, stream>>>(QKV16, IDX, AO16);
        if (l == LL - 1) {
            fused_layer<2><<<MTOT / 32, 512, 0, stream>>>(
                AO16, wo_f, attn_bo + (size_t)l * 256, X16,
                ln1_g + l * 256, ln1_b + l * 256,
                f1_f, f2_f, ffn_b1 + (size_t)l * 1024, ffn_b2 + (size_t)l * 256,
                ln2_g + l * 256, ln2_b + l * 256,
                (float*)d_out, nullptr, nullptr, nullptr);
        } else {
            fused_layer<1><<<MTOT / 32, 512, 0, stream>>>(
                AO16, wo_f, attn_bo + (size_t)l * 256, X16,
                ln1_g + l * 256, ln1_b + l * 256,
                f1_f, f2_f, ffn_b1 + (size_t)l * 1024, ffn_b2 + (size_t)l * 256,
                ln2_g + l * 256, ln2_b + l * 256,
                nullptr, X16, PE16, XP16);
        }
    }
}

// Round 22
// 681.963 us; speedup vs baseline: 2.6354x; 1.0098x over previous
//
#include <hip/hip_runtime.h>
#include <hip/hip_bf16.h>

typedef unsigned short u16;
typedef _Float16 h16;

#define BB 16
#define NO 64
#define TT 21
#define NM 768
#define PP 20
#define CAx 29
#define CMx 9
#define DD 256
#define HH 8
#define LL 6
#define KK 16
#define NN (NO + NM)        // 832
#define HDX (DD / HH)       // 32
#define MTOT (BB * NN)      // 13312
#define MAPR (BB * NM * PP) // 245760 map point-rows

typedef __attribute__((ext_vector_type(8))) h16 h8v;
typedef __attribute__((ext_vector_type(4))) h16 h4v;
typedef __attribute__((ext_vector_type(4))) float f4v;

#define GLOAD_LDS16(gptr, lptr)                                                             \
    __builtin_amdgcn_global_load_lds(                                                       \
        (const __attribute__((address_space(1))) void*)(gptr),                              \
        (__attribute__((address_space(3))) void*)(lptr), 16, 0, 0)

// Bank-conflict swizzle for [rows][32]-fp16 linear tiles (gload_lds-compatible):
#define SWZ_LCOL(lane)   ((((lane) & 3) ^ (((lane) >> 3) & 3)) * 8)
#define SWZ_RD(kb, fr)   ((((kb) ^ (((fr) >> 1) & 3))) * 8)
#define SWZ_ELEM(row, kl) (((((kl) >> 3) ^ (((row) >> 1) & 3)) << 3) | ((kl) & 7))

// ---------------------------------------------------------------- KNN (top-16 smallest d2)
__global__ __launch_bounds__(256) void knn_kernel(
    const float* __restrict__ opos, const float* __restrict__ mpos, int* __restrict__ IDX)
{
    const int b = blockIdx.x / 208;
    const int blk = blockIdx.x % 208;
    __shared__ float px[NN], py[NN], pz[NN];
    for (int i = threadIdx.x; i < NN; i += 256) {
        const float* src = (i < NO) ? &opos[(size_t)(b * NO + i) * 3]
                                    : &mpos[(size_t)(b * NM + (i - NO)) * 3];
        px[i] = src[0]; py[i] = src[1]; pz[i] = src[2];
    }
    __syncthreads();
    const int wave = threadIdx.x >> 6, lane = threadIdx.x & 63;
    const int n = blk * 4 + wave;
    const float qx = px[n], qy = py[n], qz = pz[n];
    float d[13];
    #pragma unroll
    for (int s = 0; s < 13; s++) {
        int j = s * 64 + lane;
        float dx = qx - px[j], dy = qy - py[j], dz = qz - pz[j];
        d[s] = dx * dx + dy * dy + dz * dz;
    }
    int keep = 0;
    #pragma unroll
    for (int it = 0; it < 16; it++) {
        float bv = d[0]; int bs = 0;
        #pragma unroll
        for (int s = 1; s < 13; s++) { if (d[s] < bv) { bv = d[s]; bs = s; } }
        float v = bv; int jj = bs * 64 + lane;
        #pragma unroll
        for (int off = 32; off; off >>= 1) {
            float ov = __shfl_xor(v, off);
            int oj = __shfl_xor(jj, off);
            if (ov < v || (ov == v && oj < jj)) { v = ov; jj = oj; }
        }
        if (lane == (jj & 63)) {
            int sl = jj >> 6;
            #pragma unroll
            for (int s = 0; s < 13; s++) if (s == sl) d[s] = 3.4e38f;
        }
        if (lane == it) keep = jj;
    }
    if (lane < 16) IDX[((size_t)(b * NN + n)) * 16 + lane] = keep;
}

// ---------------------------------------------------------------- merged elementwise prep
#define PRB_MAP   30720
#define PRB_AG    (PRB_MAP + 2688)
#define PRB_PE    (PRB_AG + MTOT)
#define PRB_PN    (PRB_PE + 1480)
#define PRB_TOT   (PRB_PN + 18432)
#define W1P_O   0
#define W2S_O   2048
#define W3S_O   6144
#define MW1A_O  10240
#define MW1B_O  14336
#define MW2S_O  18432
#define OW1S_O  22528
#define OW2S_O  26624
#define APW_O   43008
#define AW1A_O  51200
#define AW1B_O  116736
#define AW2S_O  182272
#define AOW1_O  247808
#define AOW2_O  313344
#define WPN_TOT 378880
__global__ __launch_bounds__(256) void prep_all(
    const float* __restrict__ mp, const float* __restrict__ obj,
    const float* __restrict__ opos, const float* __restrict__ mpos,
    const float* __restrict__ wqkv, const float* __restrict__ wo,
    const float* __restrict__ f1w, const float* __restrict__ f2w,
    const float* __restrict__ m_pre_w1, const float* __restrict__ m_pre_w2,
    const float* __restrict__ m_pre_w3, const float* __restrict__ m_mlp_w1,
    const float* __restrict__ m_mlp_w2, const float* __restrict__ m_out_w1,
    const float* __restrict__ m_out_w2,
    const float* __restrict__ a_pre_w,  const float* __restrict__ a_mlp_w1,
    const float* __restrict__ a_mlp_w2, const float* __restrict__ a_out_w1,
    const float* __restrict__ a_out_w2,
    h16* __restrict__ pmap, h16* __restrict__ pagent,
    h16* __restrict__ PE16, h16* __restrict__ wpnf, h16* __restrict__ whf)
{
    const int bid = blockIdx.x;
    const int tid = threadIdx.x;
    if (bid < PRB_MAP) {
        int e = bid * 256 + tid;
        int r = e >> 5, c = e & 31;
        float v = (c < CMx) ? mp[(size_t)r * CMx + c] : 0.f;
        pmap[e] = (h16)v;
    } else if (bid < PRB_AG) {
        int e = (bid - PRB_MAP) * 256 + tid;
        int r = e >> 5, c = e & 31;
        float v = (c < CAx) ? obj[(size_t)r * CAx + c] : ((c == CAx) ? 1.0f : 0.f);
        pagent[e] = (h16)v;
    } else if (bid < PRB_PE) {
        int row = bid - PRB_AG;
        int b = row / NN, n = row % NN;
        const float* p = (n < NO) ? &opos[(size_t)(b * NO + n) * 3]
                                  : &mpos[(size_t)(b * NM + (n - NO)) * 3];
        float x = p[0], y = p[1];
        int j = tid & 127;
        float v = (tid < 128) ? y : x;
        float inv_dt = exp2f(-(float)(j & ~1) * 0.10381025296523f);
        float e = v * 6.283185307179586f * inv_dt;
        PE16[(size_t)row * DD + tid] = (h16)((j & 1) ? cosf(e) : sinf(e));
    } else if (bid < PRB_PN) {
        int e = (bid - PRB_PE) * 256 + tid;
        float v;
        if (e < W2S_O)       { int n = e >> 5, k = e & 31; v = (k < 9) ? m_pre_w1[n * 9 + k] : 0.f; }
        else if (e < W3S_O)  v = m_pre_w2[e - W2S_O];
        else if (e < MW1A_O) v = m_pre_w3[e - W3S_O];
        else if (e < MW1B_O) { int r = e - MW1A_O; v = m_mlp_w1[(r >> 6) * 128 + (r & 63)]; }
        else if (e < MW2S_O) { int r = e - MW1B_O; v = m_mlp_w1[(r >> 6) * 128 + 64 + (r & 63)]; }
        else if (e < OW1S_O) v = m_mlp_w2[e - MW2S_O];
        else if (e < OW2S_O) v = m_out_w1[e - OW1S_O];
        else if (e < APW_O)  v = m_out_w2[e - OW2S_O];
        else if (e < AW1A_O) { int r = e - APW_O; int n = r >> 5, k = r & 31; v = (k < 30) ? a_pre_w[n * 30 + k] : 0.f; }
        else if (e < AW1B_O) { int r = e - AW1A_O; v = a_mlp_w1[(r >> 8) * 512 + (r & 255)]; }
        else if (e < AW2S_O) { int r = e - AW1B_O; v = a_mlp_w1[(r >> 8) * 512 + 256 + (r & 255)]; }
        else if (e < AOW1_O) v = a_mlp_w2[e - AW2S_O];
        else if (e < AOW2_O) v = a_out_w1[e - AOW1_O];
        else                 v = a_out_w2[e - AOW2_O];
        wpnf[e] = (h16)v;
    } else {
        size_t e = (size_t)(bid - PRB_PN) * 256 + tid;
        int L = (int)(e / 786432);
        int r = (int)(e % 786432);
        float v;
        if (r < 196608)      v = wqkv[(size_t)L * 196608 + r];
        else if (r < 262144) v = wo[(size_t)L * 65536 + (r - 196608)];
        else if (r < 524288) v = f1w[(size_t)L * 262144 + (r - 262144)];
        else                 v = f2w[(size_t)L * 262144 + (r - 524288)];
        whf[e] = (h16)v;
    }
}

// ---------------------------------------------------------------- max-pool over P points, 8-wide
template<int P>
__global__ __launch_bounds__(256) void pool_max8(
    const h16* __restrict__ in, h16* __restrict__ out, int cshift)
{
    int e8 = blockIdx.x * 256 + threadIdx.x;
    int C = 1 << cshift;
    int base = e8 * 8;
    int g = base >> cshift, c = base & (C - 1);
    float m0 = -3.4e38f, m1 = m0, m2 = m0, m3 = m0, m4 = m0, m5 = m0, m6 = m0, m7 = m0;
    #pragma unroll
    for (int p = 0; p < P; p++) {
        h8v v = *(const h8v*)&in[((size_t)(g * P + p) << cshift) + c];
        m0 = fmaxf(m0, (float)v[0]); m1 = fmaxf(m1, (float)v[1]);
        m2 = fmaxf(m2, (float)v[2]); m3 = fmaxf(m3, (float)v[3]);
        m4 = fmaxf(m4, (float)v[4]); m5 = fmaxf(m5, (float)v[5]);
        m6 = fmaxf(m6, (float)v[6]); m7 = fmaxf(m7, (float)v[7]);
    }
    h8v o;
    o[0] = (h16)m0; o[1] = (h16)m1; o[2] = (h16)m2; o[3] = (h16)m3;
    o[4] = (h16)m4; o[5] = (h16)m5; o[6] = (h16)m6; o[7] = (h16)m7;
    *(h8v*)&out[((size_t)g << cshift) + c] = o;
}

// ---------------------------------------------------------------- pointnet GEMM (fp16 MFMA)
template<int BN, bool RELU, bool F16OUT, bool ROWMAP>
__global__ __launch_bounds__(256) void gemm_pn(
    const h16* __restrict__ A, const h16* __restrict__ W,
    const float* __restrict__ bias,
    const float* __restrict__ addrow, int ardiv, int arld,
    float* __restrict__ Cf, h16* __restrict__ C16,
    int K, int ldc, int rm_div, int rm_mul, int rm_add)
{
    constexpr int WAVES_M = (BN == 64) ? 4 : 2;
    constexpr int WM = 128 / (16 * WAVES_M);
    __shared__ __align__(16) h16 AS[128][32];
    __shared__ __align__(16) h16 WS[BN][32];
    const int m0 = blockIdx.x * 128;
    const int n0 = blockIdx.y * BN;
    const int tid = threadIdx.x;
    const int wave = tid >> 6, lane = tid & 63;
    const int wr = (BN == 64) ? wave : (wave >> 1);
    const int wc = (BN == 64) ? 0 : (wave & 1);
    const int fr = lane & 15, kb = lane >> 4;
    const int lrow = lane >> 2, lcol = SWZ_LCOL(lane);
    const int rdo = SWZ_RD(kb, fr);

    f4v acc[WM][4];
    #pragma unroll
    for (int i = 0; i < WM; i++)
        #pragma unroll
        for (int j = 0; j < 4; j++) { f4v z = {0.f, 0.f, 0.f, 0.f}; acc[i][j] = z; }

    for (int k0 = 0; k0 < K; k0 += 32) {
        __syncthreads();
        #pragma unroll
        for (int i = 0; i < 2; i++) {
            const int r = wave * 32 + i * 16;
            GLOAD_LDS16(&A[(size_t)(m0 + r + lrow) * K + k0 + lcol], &AS[r][0]);
        }
        if constexpr (BN == 64) {
            const int r = wave * 16;
            GLOAD_LDS16(&W[(size_t)(n0 + r + lrow) * K + k0 + lcol], &WS[r][0]);
        } else {
            #pragma unroll
            for (int i = 0; i < 2; i++) {
                const int r = wave * 32 + i * 16;
                GLOAD_LDS16(&W[(size_t)(n0 + r + lrow) * K + k0 + lcol], &WS[r][0]);
            }
        }
        __syncthreads();
        h8v af[WM];
        #pragma unroll
        for (int mi = 0; mi < WM; mi++)
            af[mi] = *(const h8v*)&AS[wr * (WM * 16) + mi * 16 + fr][rdo];
        #pragma unroll
        for (int nj = 0; nj < 4; nj++) {
            h8v bf = *(const h8v*)&WS[wc * 64 + nj * 16 + fr][rdo];
            #pragma unroll
            for (int mi = 0; mi < WM; mi++)
                acc[mi][nj] = __builtin_amdgcn_mfma_f32_16x16x32_f16(af[mi], bf, acc[mi][nj], 0, 0, 0);
        }
    }
    #pragma unroll
    for (int mi = 0; mi < WM; mi++) {
        #pragma unroll
        for (int nj = 0; nj < 4; nj++) {
            int col = n0 + wc * 64 + nj * 16 + fr;
            float bb = bias ? bias[col] : 0.f;
            #pragma unroll
            for (int r = 0; r < 4; r++) {
                int row = m0 + wr * (WM * 16) + mi * 16 + (lane >> 4) * 4 + r;
                float v = acc[mi][nj][r] + bb;
                if (addrow) v += addrow[(size_t)(row / ardiv) * arld + col];
                if (RELU) v = fmaxf(v, 0.f);
                if (F16OUT) {
                    C16[(size_t)row * ldc + col] = (h16)v;
                } else {
                    int drow = row;
                    if (ROWMAP) drow = row + rm_add + (row / rm_div) * rm_mul;
                    Cf[(size_t)drow * ldc + col] = v;
                }
            }
        }
    }
}

// ---------------------------------------------------------------- initial activation cvt
__global__ __launch_bounds__(256) void split_x0(
    const float* __restrict__ X, const h16* __restrict__ PE16,
    h16* __restrict__ X16, h16* __restrict__ XP16)
{
    size_t base = ((size_t)blockIdx.x * 256 + threadIdx.x) * 4;
    float4 x = *(const float4*)&X[base];
    h4v pe = *(const h4v*)&PE16[base];
    h4v a, b;
    a.x = (h16)x.x; a.y = (h16)x.y; a.z = (h16)x.z; a.w = (h16)x.w;
    b.x = (h16)(x.x + (float)pe.x); b.y = (h16)(x.y + (float)pe.y);
    b.z = (h16)(x.z + (float)pe.z); b.w = (h16)(x.w + (float)pe.w);
    *(h4v*)&X16[base] = a;
    *(h4v*)&XP16[base] = b;
}

// ---------------------------------------------------------------- fused map pre1->pre2->pre3
__global__ __launch_bounds__(256) void fused_map3(
    const h16* __restrict__ A,   // [MAPR][32]
    const h16* __restrict__ W1,  // [64][32]
    const h16* __restrict__ W2, const h16* __restrict__ W3,  // [64][64]
    const float* __restrict__ b1, const float* __restrict__ b2, const float* __restrict__ b3,
    h16* __restrict__ Out)       // [MAPR][64]
{
    __shared__ __align__(16) h16 AS[128][32];
    __shared__ __align__(16) h16 G0[2][128][32];
    __shared__ __align__(16) h16 G1[2][128][32];
    __shared__ __align__(16) h16 W1S[64][32];
    __shared__ __align__(16) h16 W2S[2][64][32];
    __shared__ __align__(16) h16 W3S[2][64][32];
    const int m0 = blockIdx.x * 128;
    const int tid = threadIdx.x;
    const int wave = tid >> 6, lane = tid & 63;
    const int fr = lane & 15, kb = lane >> 4;
    const int lrow = lane >> 2, lcol = SWZ_LCOL(lane);
    const int rdo = SWZ_RD(kb, fr);

    #pragma unroll
    for (int q = 0; q < 2; q++)
        GLOAD_LDS16(&A[(size_t)(m0 + wave * 32 + q * 16 + lrow) * 32 + lcol],
                    &AS[wave * 32 + q * 16][0]);
    GLOAD_LDS16(&W1[(size_t)(wave * 16 + lrow) * 32 + lcol], &W1S[wave * 16][0]);
    #pragma unroll
    for (int t = 0; t < 2; t++) {
        GLOAD_LDS16(&W2[(size_t)(wave * 16 + lrow) * 64 + t * 32 + lcol], &W2S[t][wave * 16][0]);
        GLOAD_LDS16(&W3[(size_t)(wave * 16 + lrow) * 64 + t * 32 + lcol], &W3S[t][wave * 16][0]);
    }
    __syncthreads();
    #pragma unroll
    for (int mi = 0; mi < 2; mi++) {
        h8v af = *(const h8v*)&AS[wave * 32 + mi * 16 + fr][rdo];
        #pragma unroll
        for (int nj = 0; nj < 4; nj++) {
            f4v a = {0.f, 0.f, 0.f, 0.f};
            h8v bf = *(const h8v*)&W1S[nj * 16 + fr][rdo];
            a = __builtin_amdgcn_mfma_f32_16x16x32_f16(af, bf, a, 0, 0, 0);
            int col = nj * 16 + fr, ch = col >> 5, kl = col & 31;
            float bb = b1[col];
            #pragma unroll
            for (int r = 0; r < 4; r++) {
                int row = wave * 32 + mi * 16 + kb * 4 + r;
                G0[ch][row][SWZ_ELEM(row, kl)] = (h16)fmaxf(a[r] + bb, 0.f);
            }
        }
    }
    __syncthreads();
    #pragma unroll
    for (int mi = 0; mi < 2; mi++) {
        #pragma unroll
        for (int nj = 0; nj < 4; nj++) {
            f4v a = {0.f, 0.f, 0.f, 0.f};
            #pragma unroll
            for (int t = 0; t < 2; t++) {
                h8v af = *(const h8v*)&G0[t][wave * 32 + mi * 16 + fr][rdo];
                h8v bf = *(const h8v*)&W2S[t][nj * 16 + fr][rdo];
                a = __builtin_amdgcn_mfma_f32_16x16x32_f16(af, bf, a, 0, 0, 0);
            }
            int col = nj * 16 + fr, ch = col >> 5, kl = col & 31;
            float bb = b2[col];
            #pragma unroll
            for (int r = 0; r < 4; r++) {
                int row = wave * 32 + mi * 16 + kb * 4 + r;
                G1[ch][row][SWZ_ELEM(row, kl)] = (h16)fmaxf(a[r] + bb, 0.f);
            }
        }
    }
    __syncthreads();
    #pragma unroll
    for (int mi = 0; mi < 2; mi++) {
        #pragma unroll
        for (int nj = 0; nj < 4; nj++) {
            f4v a = {0.f, 0.f, 0.f, 0.f};
            #pragma unroll
            for (int t = 0; t < 2; t++) {
                h8v af = *(const h8v*)&G1[t][wave * 32 + mi * 16 + fr][rdo];
                h8v bf = *(const h8v*)&W3S[t][nj * 16 + fr][rdo];
                a = __builtin_amdgcn_mfma_f32_16x16x32_f16(af, bf, a, 0, 0, 0);
            }
            int col = nj * 16 + fr;
            float bb = b3[col];
            #pragma unroll
            for (int r = 0; r < 4; r++) {
                int row = m0 + wave * 32 + mi * 16 + kb * 4 + r;
                Out[(size_t)row * 64 + col] = (h16)fmaxf(a[r] + bb, 0.f);
            }
        }
    }
}

// ---------------------------------------------------------------- fused map mid1->mid2
// mid1 bias b1 is carried entirely by `pooled` (PCf = pooled@W1B + b1).
__global__ __launch_bounds__(256) void fused_map2(
    const h16* __restrict__ A,   // [MAPR][64]
    const h16* __restrict__ W1,  // MW1A [64][64]
    const h16* __restrict__ W2,  // MW2S [64][64]
    const float* __restrict__ b2,
    const float* __restrict__ pooled,  // PCf [12288][64] f32 (includes b1)
    h16* __restrict__ Out)       // [MAPR][64]
{
    __shared__ __align__(16) h16 AS[2][128][32];
    __shared__ __align__(16) h16 G0[2][128][32];
    __shared__ __align__(16) h16 W1S[2][64][32];
    __shared__ __align__(16) h16 W2S[2][64][32];
    const int m0 = blockIdx.x * 128;
    const int tid = threadIdx.x;
    const int wave = tid >> 6, lane = tid & 63;
    const int fr = lane & 15, kb = lane >> 4;
    const int lrow = lane >> 2, lcol = SWZ_LCOL(lane);
    const int rdo = SWZ_RD(kb, fr);

    #pragma unroll
    for (int t = 0; t < 2; t++) {
        #pragma unroll
        for (int q = 0; q < 2; q++)
            GLOAD_LDS16(&A[(size_t)(m0 + wave * 32 + q * 16 + lrow) * 64 + t * 32 + lcol],
                        &AS[t][wave * 32 + q * 16][0]);
        GLOAD_LDS16(&W1[(size_t)(wave * 16 + lrow) * 64 + t * 32 + lcol], &W1S[t][wave * 16][0]);
        GLOAD_LDS16(&W2[(size_t)(wave * 16 + lrow) * 64 + t * 32 + lcol], &W2S[t][wave * 16][0]);
    }
    __syncthreads();
    #pragma unroll
    for (int mi = 0; mi < 2; mi++) {
        #pragma unroll
        for (int nj = 0; nj < 4; nj++) {
            f4v a = {0.f, 0.f, 0.f, 0.f};
            #pragma unroll
            for (int t = 0; t < 2; t++) {
                h8v af = *(const h8v*)&AS[t][wave * 32 + mi * 16 + fr][rdo];
                h8v bf = *(const h8v*)&W1S[t][nj * 16 + fr][rdo];
                a = __builtin_amdgcn_mfma_f32_16x16x32_f16(af, bf, a, 0, 0, 0);
            }
            int col = nj * 16 + fr, ch = col >> 5, kl = col & 31;
            #pragma unroll
            for (int r = 0; r < 4; r++) {
                int row = wave * 32 + mi * 16 + kb * 4 + r;
                int grow = m0 + row;
                float v = a[r] + pooled[(size_t)(grow / PP) * 64 + col];
                G0[ch][row][SWZ_ELEM(row, kl)] = (h16)fmaxf(v, 0.f);
            }
        }
    }
    __syncthreads();
    #pragma unroll
    for (int mi = 0; mi < 2; mi++) {
        #pragma unroll
        for (int nj = 0; nj < 4; nj++) {
            f4v a = {0.f, 0.f, 0.f, 0.f};
            #pragma unroll
            for (int t = 0; t < 2; t++) {
                h8v af = *(const h8v*)&G0[t][wave * 32 + mi * 16 + fr][rdo];
                h8v bf = *(const h8v*)&W2S[t][nj * 16 + fr][rdo];
                a = __builtin_amdgcn_mfma_f32_16x16x32_f16(af, bf, a, 0, 0, 0);
            }
            int col = nj * 16 + fr;
            float bb = b2[col];
            #pragma unroll
            for (int r = 0; r < 4; r++) {
                int row = m0 + wave * 32 + mi * 16 + kb * 4 + r;
                Out[(size_t)row * 64 + col] = (h16)fmaxf(a[r] + bb, 0.f);
            }
        }
    }
}

// ---------------------------------------------------------------- transformer fp16 MFMA GEMM
template<bool RELU, bool F16OUT>
__global__ __launch_bounds__(256) void gemm_mfma(
    const h16* __restrict__ A, const h16* __restrict__ A2, int a2min,
    const h16* __restrict__ W, const float* __restrict__ bias,
    float* __restrict__ Cf, h16* __restrict__ C16,
    int K, int ldc, int coff, float scale, int scale_until)
{
    __shared__ __align__(16) h16 AS[128][32];
    __shared__ __align__(16) h16 WS[128][32];
    const int m0 = blockIdx.x * 128;
    const int n0 = blockIdx.y * 128;
    const h16* pA = (n0 >= a2min) ? A2 : A;
    const int tid = threadIdx.x;
    const int wave = tid >> 6, lane = tid & 63;
    const int wr = wave >> 1, wc = wave & 1;
    const int fr = lane & 15, kb = lane >> 4;
    const int lrow = lane >> 2;
    const int lcol = SWZ_LCOL(lane);
    const int rdo = SWZ_RD(kb, fr);

    f4v acc[4][4];
    #pragma unroll
    for (int i = 0; i < 4; i++)
        #pragma unroll
        for (int j = 0; j < 4; j++) { f4v z = {0.f, 0.f, 0.f, 0.f}; acc[i][j] = z; }

    for (int k0 = 0; k0 < K; k0 += 32) {
        __syncthreads();
        #pragma unroll
        for (int i = 0; i < 2; i++) {
            const int r = wave * 32 + i * 16;
            const size_t grow = (size_t)(r + lrow);
            GLOAD_LDS16(&pA[(m0 + grow) * K + k0 + lcol], &AS[r][0]);
            GLOAD_LDS16(&W [(n0 + grow) * K + k0 + lcol], &WS[r][0]);
        }
        __syncthreads();
        h8v af[4];
        #pragma unroll
        for (int mi = 0; mi < 4; mi++)
            af[mi] = *(const h8v*)&AS[wr * 64 + mi * 16 + fr][rdo];
        #pragma unroll
        for (int nj = 0; nj < 4; nj++) {
            h8v bf = *(const h8v*)&WS[wc * 64 + nj * 16 + fr][rdo];
            #pragma unroll
            for (int mi = 0; mi < 4; mi++)
                acc[mi][nj] = __builtin_amdgcn_mfma_f32_16x16x32_f16(af[mi], bf, acc[mi][nj], 0, 0, 0);
        }
    }
    #pragma unroll
    for (int mi = 0; mi < 4; mi++) {
        #pragma unroll
        for (int nj = 0; nj < 4; nj++) {
            int col = n0 + wc * 64 + nj * 16 + fr;
            float bb = bias[col];
            #pragma unroll
            for (int r = 0; r < 4; r++) {
                int row = m0 + wr * 64 + mi * 16 + (lane >> 4) * 4 + r;
                float v = acc[mi][nj][r] + bb;
                if (RELU) v = fmaxf(v, 0.f);
                int gcol = coff + col;
                if (gcol < scale_until) v *= scale;
                if (F16OUT) {
                    C16[(size_t)row * ldc + gcol] = (h16)v;
                } else {
                    Cf[(size_t)row * ldc + gcol] = v;
                }
            }
        }
    }
}

// ---------------------------------------------------------------- fused O-proj+LN1+FFN1+FFN2+LN2
// 64 rows/block, 8 waves (4 wr x 2 wc). Hidden chunked by 128; 64KB WSu union.
// 4x MFMA per barrier vs the 32-row version; 208 blocks, 1 block/CU (148KB LDS).
// PEMODE 1: write X16 + XP16(=h16(o+PE)).  PEMODE 2: write fp32 d_out.
template<int PEMODE>
__global__ __launch_bounds__(512) void fused_layer(
    const h16* __restrict__ AO16, const h16* __restrict__ Wo,   // [256][256]
    const float* __restrict__ bo, const h16* __restrict__ X16r,
    const float* __restrict__ g1, const float* __restrict__ bt1,
    const h16* __restrict__ W1,   // [1024][256]
    const h16* __restrict__ W2,   // [256][1024]
    const float* __restrict__ b1, const float* __restrict__ b2,
    const float* __restrict__ g2, const float* __restrict__ bt2,
    float* __restrict__ OutF, h16* __restrict__ O16,
    const h16* __restrict__ PE16p, h16* __restrict__ P16)
{
    __shared__ __align__(16) h16 AOS[8][64][32];   // 32 KB: AO tile (k-tiles)
    __shared__ __align__(16) h16 HS[8][64][32];    // 32 KB: post-LN h (col-chunk tiles)
    __shared__ __align__(16) h16 GS[4][64][32];    // 16 KB: relu'd hidden chunk (128)
    __shared__ __align__(16) h16 WSu[32768];       // 64 KB: Wo/W1/W2 chunk union
    __shared__ float red_s[2][8][64];              // 4 KB
    const int m0 = blockIdx.x * 64;
    const int tid = threadIdx.x;
    const int wave = tid >> 6, lane = tid & 63;
    const int wr = wave >> 1, wc = wave & 1;
    const int fr = lane & 15, kb = lane >> 4;
    const int lrow = lane >> 2, lcol = SWZ_LCOL(lane);
    const int rdo = SWZ_RD(kb, fr);

    // stage AO tile: wave w -> k-tile t=w, 64 rows
    #pragma unroll
    for (int q = 0; q < 4; q++)
        GLOAD_LDS16(&AO16[(size_t)(m0 + q * 16 + lrow) * 256 + wave * 32 + lcol],
                    &AOS[wave][q * 16][0]);

    // ---- stage 0: O-proj (2 col-chunks of 128) + residual(X16r) + LN1 stats
    float xo[2][4][4];
    float rsum1[4] = {0.f, 0.f, 0.f, 0.f}, rsq1[4] = {0.f, 0.f, 0.f, 0.f};
    #pragma unroll
    for (int oc = 0; oc < 2; oc++) {
        __syncthreads();   // WSu free
        #pragma unroll
        for (int q = 0; q < 8; q++)
            GLOAD_LDS16(&Wo[(size_t)(oc * 128 + q * 16 + lrow) * 256 + wave * 32 + lcol],
                        &WSu[wave * 4096 + (q * 16) * 32]);
        __syncthreads();   // Wo chunk (and first-iter AOS) visible
        h8v aof[8];
        #pragma unroll
        for (int t = 0; t < 8; t++)
            aof[t] = *(const h8v*)&AOS[t][wr * 16 + fr][rdo];
        #pragma unroll
        for (int nj = 0; nj < 4; nj++) {
            f4v o1 = {0.f, 0.f, 0.f, 0.f};
            #pragma unroll
            for (int t = 0; t < 8; t++) {
                h8v bf = *(const h8v*)&WSu[t * 4096 + (wc * 64 + nj * 16 + fr) * 32 + rdo];
                o1 = __builtin_amdgcn_mfma_f32_16x16x32_f16(aof[t], bf, o1, 0, 0, 0);
            }
            int col = oc * 128 + wc * 64 + nj * 16 + fr;
            float bb = bo[col];
            #pragma unroll
            for (int r = 0; r < 4; r++) {
                int row = wr * 16 + kb * 4 + r;
                float v = o1[r] + bb + (float)X16r[(size_t)(m0 + row) * 256 + col];
                xo[oc][nj][r] = v;
                rsum1[r] += v;
                rsq1[r] += v * v;
            }
        }
    }
    #pragma unroll
    for (int off = 1; off < 16; off <<= 1)
        #pragma unroll
        for (int r = 0; r < 4; r++) {
            rsum1[r] += __shfl_xor(rsum1[r], off);
            rsq1[r]  += __shfl_xor(rsq1[r], off);
        }
    // each wave owns row-group wr; zero-fill the other 3 groups (post-butterfly all fr
    // lanes hold the full sum, so lane fr<4 writes group (wr+fr)&3, real iff fr==0)
    if (fr < 4) {
        int grp = (wr + fr) & 3;
        #pragma unroll
        for (int r = 0; r < 4; r++) {
            red_s[0][wave][grp * 16 + kb * 4 + r] = (fr == 0) ? rsum1[r] : 0.f;
            red_s[1][wave][grp * 16 + kb * 4 + r] = (fr == 0) ? rsq1[r] : 0.f;
        }
    }
    __syncthreads();
    float mean1[4], inv1[4];
    #pragma unroll
    for (int r = 0; r < 4; r++) {
        int rid = wr * 16 + kb * 4 + r;
        float s = 0.f, sq = 0.f;
        #pragma unroll
        for (int w = 0; w < 8; w++) { s += red_s[0][w][rid]; sq += red_s[1][w][rid]; }
        mean1[r] = s * (1.f / 256.f);
        float var = sq * (1.f / 256.f) - mean1[r] * mean1[r];
        inv1[r] = rsqrtf(var + 1e-5f);
    }
    // write h = LN1(xo) into HS (col-chunk tile layout)
    #pragma unroll
    for (int oc = 0; oc < 2; oc++)
        #pragma unroll
        for (int nj = 0; nj < 4; nj++) {
            int col = oc * 128 + wc * 64 + nj * 16 + fr;
            int ch = col >> 5, kl = col & 31;
            float gg = g1[col], bb = bt1[col];
            #pragma unroll
            for (int r = 0; r < 4; r++) {
                int row = wr * 16 + kb * 4 + r;
                float h = (xo[oc][nj][r] - mean1[r]) * inv1[r] * gg + bb;
                HS[ch][row][SWZ_ELEM(row, kl)] = (h16)h;
            }
        }
    __syncthreads();   // HS ready; Wo reads done

    // hoist h A-fragments (HS is chunk-invariant)
    h8v haf[8];
    #pragma unroll
    for (int t = 0; t < 8; t++)
        haf[t] = *(const h8v*)&HS[t][wr * 16 + fr][rdo];

    // ---- stage 1+2: FFN (hidden chunked by 128) accumulating acc2
    f4v acc2[8];
    #pragma unroll
    for (int j = 0; j < 8; j++) { f4v z = {0.f, 0.f, 0.f, 0.f}; acc2[j] = z; }

    for (int c = 0; c < 8; c++) {
        const int H0 = c * 128;
        __syncthreads();   // WSu/GS free from previous chunk
        #pragma unroll
        for (int q = 0; q < 8; q++)
            GLOAD_LDS16(&W1[(size_t)(H0 + q * 16 + lrow) * 256 + wave * 32 + lcol],
                        &WSu[wave * 4096 + (q * 16) * 32]);
        __syncthreads();   // W1 chunk visible
        #pragma unroll
        for (int nj = 0; nj < 4; nj++) {
            f4v a1 = {0.f, 0.f, 0.f, 0.f};
            #pragma unroll
            for (int t = 0; t < 8; t++) {
                h8v bf = *(const h8v*)&WSu[t * 4096 + (wc * 64 + nj * 16 + fr) * 32 + rdo];
                a1 = __builtin_amdgcn_mfma_f32_16x16x32_f16(haf[t], bf, a1, 0, 0, 0);
            }
            int n = wc * 64 + nj * 16 + fr;    // hidden index within chunk (0..127)
            int ch = n >> 5, kl = n & 31;
            float bb = b1[H0 + n];
            #pragma unroll
            for (int r = 0; r < 4; r++) {
                int row = wr * 16 + kb * 4 + r;
                GS[ch][row][SWZ_ELEM(row, kl)] = (h16)fmaxf(a1[r] + bb, 0.f);
            }
        }
        __syncthreads();   // GS visible; W1 reads done
        #pragma unroll
        for (int t2 = 0; t2 < 4; t2++)
            #pragma unroll
            for (int q = 0; q < 2; q++)
                GLOAD_LDS16(&W2[(size_t)(wave * 32 + q * 16 + lrow) * 1024 + H0 + t2 * 32 + lcol],
                            &WSu[t2 * 8192 + (wave * 32 + q * 16) * 32]);
        __syncthreads();   // W2 chunk visible
        #pragma unroll
        for (int t2 = 0; t2 < 4; t2++) {
            h8v gaf = *(const h8v*)&GS[t2][wr * 16 + fr][rdo];
            #pragma unroll
            for (int nj = 0; nj < 8; nj++) {
                h8v bf = *(const h8v*)&WSu[t2 * 8192 + (wc * 128 + nj * 16 + fr) * 32 + rdo];
                acc2[nj] = __builtin_amdgcn_mfma_f32_16x16x32_f16(gaf, bf, acc2[nj], 0, 0, 0);
            }
        }
    }
    // ---- epilogue: x = h-residual(HS) + acc2 + b2; LN2; write
    float x[8][4];
    float rsum[4] = {0.f, 0.f, 0.f, 0.f}, rsq[4] = {0.f, 0.f, 0.f, 0.f};
    #pragma unroll
    for (int nj = 0; nj < 8; nj++) {
        int col = wc * 128 + nj * 16 + fr;
        int ch = col >> 5, kl = col & 31;
        float bb = b2[col];
        #pragma unroll
        for (int r = 0; r < 4; r++) {
            int row = wr * 16 + kb * 4 + r;
            float res = (float)HS[ch][row][SWZ_ELEM(row, kl)];
            float v = acc2[nj][r] + bb + res;
            x[nj][r] = v;
            rsum[r] += v;
            rsq[r] += v * v;
        }
    }
    #pragma unroll
    for (int off = 1; off < 16; off <<= 1)
        #pragma unroll
        for (int r = 0; r < 4; r++) {
            rsum[r] += __shfl_xor(rsum[r], off);
            rsq[r]  += __shfl_xor(rsq[r], off);
        }
    __syncthreads();   // red_s free from LN1
    if (fr < 4) {
        int grp = (wr + fr) & 3;
        #pragma unroll
        for (int r = 0; r < 4; r++) {
            red_s[0][wave][grp * 16 + kb * 4 + r] = (fr == 0) ? rsum[r] : 0.f;
            red_s[1][wave][grp * 16 + kb * 4 + r] = (fr == 0) ? rsq[r] : 0.f;
        }
    }
    __syncthreads();
    #pragma unroll
    for (int r = 0; r < 4; r++) {
        int rid = wr * 16 + kb * 4 + r;
        float s = 0.f, sq = 0.f;
        #pragma unroll
        for (int w = 0; w < 8; w++) { s += red_s[0][w][rid]; sq += red_s[1][w][rid]; }
        float mean = s * (1.f / 256.f);
        float var = sq * (1.f / 256.f) - mean * mean;
        float inv = rsqrtf(var + 1e-5f);
        #pragma unroll
        for (int nj = 0; nj < 8; nj++) {
            int col = wc * 128 + nj * 16 + fr;
            float o = (x[nj][r] - mean) * inv * g2[col] + bt2[col];
            size_t idx = (size_t)(m0 + rid) * 256 + col;
            if (PEMODE == 2) {
                OutF[idx] = o;
            } else {
                O16[idx] = (h16)o;
                P16[idx] = (h16)(o + (float)PE16p[idx]);
            }
        }
    }
}

// ---------------------------------------------------------------- local KNN attention (fp16 QKV)
__global__ __launch_bounds__(256) void attn_kernel(
    const h16* __restrict__ QKV16, const int* __restrict__ IDX,
    h16* __restrict__ AO16)
{
    __shared__ __align__(16) h16 Ks[32][256];
    __shared__ float p_s[2][HH][16];
    __shared__ int gid_s[2][16];
    const int sub = threadIdx.x >> 7;
    const int t = threadIdx.x & 127;
    const int wave = threadIdx.x >> 6, lane = threadIdx.x & 63;
    const int xcd = blockIdx.x & 7;
    const int j = blockIdx.x >> 3;            // 0..831
    const int b = (j / 416) * 8 + xcd;        // batch
    const int row = b * NN + (j % 416) * 2 + sub;
    const int h = t >> 4, k = t & 15;
    int nb = IDX[(size_t)row * 16 + k];
    int g = b * NN + nb;
    if (h == 0) gid_s[sub][k] = g;
    __syncthreads();
    #pragma unroll
    for (int i = 0; i < 4; i++) {
        int s0 = wave * 8 + i * 2;
        int s = s0 + (lane >> 5);
        int gs = gid_s[s >> 4][s & 15];
        int clog = (lane & 31) ^ (s & 7);
        GLOAD_LDS16(&QKV16[(size_t)gs * 768 + 256 + clog * 8], &Ks[s0][0]);
    }
    __syncthreads();
    const h16* q = &QKV16[(size_t)row * 768 + h * HDX];
    const int sidx = sub * 16 + k;
    float s = 0.f;
    #pragma unroll
    for (int c = 0; c < 4; c++) {
        h8v q8 = *(const h8v*)&q[c * 8];
        h8v k8 = *(const h8v*)&Ks[sidx][(((h * 4 + c) ^ (sidx & 7)) * 8)];
        #pragma unroll
        for (int e = 0; e < 8; e++) s += (float)q8[e] * (float)k8[e];
    }
    float m = s;
    #pragma unroll
    for (int off = 8; off; off >>= 1) m = fmaxf(m, __shfl_xor(m, off, 16));
    float e = expf(s - m);
    float sum = e;
    #pragma unroll
    for (int off = 8; off; off >>= 1) sum += __shfl_xor(sum, off, 16);
    p_s[sub][h][k] = e / sum;
    __syncthreads();
    const int d0 = t * 2;
    const int hh = d0 >> 5, dd = d0 & 31;
    float o0 = 0.f, o1 = 0.f;
    #pragma unroll
    for (int kk = 0; kk < 16; kk++) {
        int gg = gid_s[sub][kk];
        const h16* vr = &QKV16[(size_t)gg * 768 + 512 + hh * HDX + dd];
        float p = p_s[sub][hh][kk];
        o0 += p * (float)vr[0];
        o1 += p * (float)vr[1];
    }
    size_t base = (size_t)row * DD + d0;
    AO16[base] = (h16)o0;
    AO16[base + 1] = (h16)o1;
}

// ----------------------------------------------------------------
extern "C" void kernel_launch(void* const* d_in, const int* in_sizes, int n_in,
                              void* d_out, int out_size, void* d_ws, size_t ws_size,
                              hipStream_t stream)
{
    const float* obj      = (const float*)d_in[0];
    const float* mp       = (const float*)d_in[1];
    const float* opos     = (const float*)d_in[2];
    const float* mpos     = (const float*)d_in[3];
    const float* a_pre_w  = (const float*)d_in[4];
    const float* a_pre_b  = (const float*)d_in[5];
    const float* a_mlp_w1 = (const float*)d_in[6];
    const float* a_mlp_b1 = (const float*)d_in[7];
    const float* a_mlp_w2 = (const float*)d_in[8];
    const float* a_mlp_b2 = (const float*)d_in[9];
    const float* a_out_w1 = (const float*)d_in[10];
    const float* a_out_b1 = (const float*)d_in[11];
    const float* a_out_w2 = (const float*)d_in[12];
    const float* a_out_b2 = (const float*)d_in[13];
    const float* m_pre_w1 = (const float*)d_in[14];
    const float* m_pre_b1 = (const float*)d_in[15];
    const float* m_pre_w2 = (const float*)d_in[16];
    const float* m_pre_b2 = (const float*)d_in[17];
    const float* m_pre_w3 = (const float*)d_in[18];
    const float* m_pre_b3 = (const float*)d_in[19];
    const float* m_mlp_w1 = (const float*)d_in[20];
    const float* m_mlp_b1 = (const float*)d_in[21];
    const float* m_mlp_w2 = (const float*)d_in[22];
    const float* m_mlp_b2 = (const float*)d_in[23];
    const float* m_out_w1 = (const float*)d_in[24];
    const float* m_out_b1 = (const float*)d_in[25];
    const float* m_out_w2 = (const float*)d_in[26];
    const float* m_out_b2 = (const float*)d_in[27];
    const float* attn_wqkv = (const float*)d_in[28];
    const float* attn_bqkv = (const float*)d_in[29];
    const float* attn_wo   = (const float*)d_in[30];
    const float* attn_bo   = (const float*)d_in[31];
    const float* ffn_w1    = (const float*)d_in[32];
    const float* ffn_b1    = (const float*)d_in[33];
    const float* ffn_w2    = (const float*)d_in[34];
    const float* ffn_b2    = (const float*)d_in[35];
    const float* ln1_g     = (const float*)d_in[36];
    const float* ln1_b     = (const float*)d_in[37];
    const float* ln2_g     = (const float*)d_in[38];
    const float* ln2_b     = (const float*)d_in[39];

    const size_t M = MTOT;  // 13312
    float* ws   = (float*)d_ws;
    float* X    = ws;                 // M*256 f32 (pointnet out staging)
    float* PEr  = X   + M * 256;      // PE16 region
    float* QKVr = PEr + M * 256;      // aliased region
    float* Hpad = QKVr + M * 768;     // padding region
    h16* AO16   = (h16*)(Hpad + M * 256);
    h16* X16    = AO16 + M * 256;
    h16* XP16   = X16  + M * 256;
    h16* H16    = XP16 + M * 256;     // unused now (layout stability)
    h16* whf    = H16  + M * 256;     // 4,718,592 fp16
    h16* wpnf   = whf  + 4718592;
    int* IDX    = (int*)(wpnf + WPN_TOT);

    h16* PE16 = (h16*)PEr;
    h16* QKV16 = (h16*)QKVr;          // M*768 fp16 (live QKV-gemm..attn)

    // pointnet-phase aliases (QKVr..AO16 dead window during pre-phase;
    // X16/XP16 written ONLY by split_x0 after all pointnet buffers are dead)
    h16* PN0f = (h16*)QKVr;
    h16* PN1f = PN0f + 15728640;
    h16* SB   = PN0f + 31457280;
    h16* PLf  = SB;
    h16* GMf  = SB + 786432;
    h16* HVf  = SB + 1572864;
    h16* APLf = SB + 2359296;
    h16* AGMf = SB + 2621440;
    h16* AHVf = SB + 2883584;
    float* PCf = (float*)(SB + 3145728);
    float* APC = PCf + 786432;

    // ---------------- pre-phase ----------------
    knn_kernel<<<BB * 208, 256, 0, stream>>>(opos, mpos, IDX);
    prep_all<<<PRB_TOT, 256, 0, stream>>>(
        mp, obj, opos, mpos,
        attn_wqkv, attn_wo, ffn_w1, ffn_w2,
        m_pre_w1, m_pre_w2, m_pre_w3, m_mlp_w1, m_mlp_w2, m_out_w1, m_out_w2,
        a_pre_w, a_mlp_w1, a_mlp_w2, a_out_w1, a_out_w2,
        PN0f /*pmap*/, PN1f /*pagent*/, PE16, wpnf, whf);

    // ---- agent pointnet as GEMM chain (pagent staged in PN1f)
    {
        h16* PA32 = PN1f;
        h16* PB   = PN0f + 7864320;
        h16* PA2  = PN1f;
        gemm_pn<128, true, true, false><<<dim3(168, 2), 256, 0, stream>>>(
            PA32, wpnf + APW_O, a_pre_b, nullptr, 1, 0,
            nullptr, PB, 32, 256, 1, 0, 0);
        pool_max8<21><<<128, 256, 0, stream>>>(PB, APLf, 8);
        gemm_pn<128, false, false, false><<<dim3(8, 2), 256, 0, stream>>>(
            APLf, wpnf + AW1B_O, a_mlp_b1, nullptr, 1, 0,
            APC, nullptr, 256, 256, 1, 0, 0);
        gemm_pn<128, true, true, false><<<dim3(168, 2), 256, 0, stream>>>(
            PB, wpnf + AW1A_O, nullptr, APC, 21, 256,
            nullptr, PA2, 256, 256, 1, 0, 0);
        gemm_pn<128, true, true, false><<<dim3(168, 2), 256, 0, stream>>>(
            PA2, wpnf + AW2S_O, a_mlp_b2, nullptr, 1, 0,
            nullptr, PB, 256, 256, 1, 0, 0);
        pool_max8<21><<<128, 256, 0, stream>>>(PB, AGMf, 8);
        gemm_pn<128, true, true, false><<<dim3(8, 2), 256, 0, stream>>>(
            AGMf, wpnf + AOW1_O, a_out_b1, nullptr, 1, 0,
            nullptr, AHVf, 256, 256, 1, 0, 0);
        gemm_pn<128, false, false, true><<<dim3(8, 2), 256, 0, stream>>>(
            AHVf, wpnf + AOW2_O, a_out_b2, nullptr, 1, 0,
            X, nullptr, 256, 256, 64, 768, 0);
    }

    // ---- map pointnet: fused chains (pmap in PN0f)
    {
        fused_map3<<<MAPR / 128, 256, 0, stream>>>(
            PN0f, wpnf + W1P_O, wpnf + W2S_O, wpnf + W3S_O,
            m_pre_b1, m_pre_b2, m_pre_b3, PN1f);
        pool_max8<20><<<384, 256, 0, stream>>>(PN1f, PLf, 6);
        gemm_pn<64, false, false, false><<<dim3(96, 1), 256, 0, stream>>>(
            PLf, wpnf + MW1B_O, m_mlp_b1, nullptr, 1, 0,
            PCf, nullptr, 64, 64, 1, 0, 0);
        fused_map2<<<MAPR / 128, 256, 0, stream>>>(
            PN1f, wpnf + MW1A_O, wpnf + MW2S_O,
            m_mlp_b2, PCf, PN0f);
        pool_max8<20><<<384, 256, 0, stream>>>(PN0f, GMf, 6);
        gemm_pn<64, true, true, false><<<dim3(96, 1), 256, 0, stream>>>(
            GMf, wpnf + OW1S_O, m_out_b1, nullptr, 1, 0,
            nullptr, HVf, 64, 64, 1, 0, 0);
        gemm_pn<128, false, false, true><<<dim3(96, 2), 256, 0, stream>>>(
            HVf, wpnf + OW2S_O, m_out_b2, nullptr, 1, 0,
            X, nullptr, 64, 256, 768, 64, 64);
    }

    split_x0<<<(int)(M * 256 / 1024), 256, 0, stream>>>(X, PE16, X16, XP16);

    // ---------------- transformer layers (3 dispatches/layer) ----------------
    const float scal = 0.17677669529663687f;  // 32^-0.5
    const int MB = MTOT / 128;  // 104
    for (int l = 0; l < LL; l++) {
        const size_t wb = (size_t)l * 786432;
        const h16* wqkv_f = whf + wb;
        const h16* wo_f   = whf + wb + 196608;
        const h16* f1_f   = whf + wb + 262144;
        const h16* f2_f   = whf + wb + 524288;
        const float* bqkv = attn_bqkv + (size_t)l * 768;
        gemm_mfma<false, true><<<dim3(MB, 6), 256, 0, stream>>>(
            XP16, X16, 512, wqkv_f, bqkv,
            nullptr, QKV16, 256, 768, 0, scal, 256);
        attn_kernel<<<MTOT / 2, 256, 0, stream>>>(QKV16, IDX, AO16);
        if (l == LL - 1) {
            fused_layer<2><<<MTOT / 64, 512, 0, stream>>>(
                AO16, wo_f, attn_bo + (size_t)l * 256, X16,
                ln1_g + l * 256, ln1_b + l * 256,
                f1_f, f2_f, ffn_b1 + (size_t)l * 1024, ffn_b2 + (size_t)l * 256,
                ln2_g + l * 256, ln2_b + l * 256,
                (float*)d_out, nullptr, nullptr, nullptr);
        } else {
            fused_layer<1><<<MTOT / 64, 512, 0, stream>>>(
                AO16, wo_f, attn_bo + (size_t)l * 256, X16,
                ln1_g + l * 256, ln1_b + l * 256,
                f1_f, f2_f, ffn_b1 + (size_t)l * 1024, ffn_b2 + (size_t)l * 256,
                ln2_g + l * 256, ln2_b + l * 256,
                nullptr, X16, PE16, XP16);
        }
    }
}

// Round 23
// 657.177 us; speedup vs baseline: 2.7348x; 1.0377x over previous
//
#include <hip/hip_runtime.h>
#include <hip/hip_bf16.h>

typedef unsigned short u16;
typedef _Float16 h16;

#define BB 16
#define NO 64
#define TT 21
#define NM 768
#define PP 20
#define CAx 29
#define CMx 9
#define DD 256
#define HH 8
#define LL 6
#define KK 16
#define NN (NO + NM)        // 832
#define HDX (DD / HH)       // 32
#define MTOT (BB * NN)      // 13312
#define MAPR (BB * NM * PP) // 245760 map point-rows

typedef __attribute__((ext_vector_type(8))) h16 h8v;
typedef __attribute__((ext_vector_type(4))) h16 h4v;
typedef __attribute__((ext_vector_type(4))) float f4v;

#define GLOAD_LDS16(gptr, lptr)                                                             \
    __builtin_amdgcn_global_load_lds(                                                       \
        (const __attribute__((address_space(1))) void*)(gptr),                              \
        (__attribute__((address_space(3))) void*)(lptr), 16, 0, 0)

// Bank-conflict swizzle for [rows][32]-fp16 linear tiles (gload_lds-compatible):
#define SWZ_LCOL(lane)   ((((lane) & 3) ^ (((lane) >> 3) & 3)) * 8)
#define SWZ_RD(kb, fr)   ((((kb) ^ (((fr) >> 1) & 3))) * 8)
#define SWZ_ELEM(row, kl) (((((kl) >> 3) ^ (((row) >> 1) & 3)) << 3) | ((kl) & 7))

// ---------------------------------------------------------------- KNN (top-16 smallest d2)
__global__ __launch_bounds__(256) void knn_kernel(
    const float* __restrict__ opos, const float* __restrict__ mpos, int* __restrict__ IDX)
{
    const int b = blockIdx.x / 208;
    const int blk = blockIdx.x % 208;
    __shared__ float px[NN], py[NN], pz[NN];
    for (int i = threadIdx.x; i < NN; i += 256) {
        const float* src = (i < NO) ? &opos[(size_t)(b * NO + i) * 3]
                                    : &mpos[(size_t)(b * NM + (i - NO)) * 3];
        px[i] = src[0]; py[i] = src[1]; pz[i] = src[2];
    }
    __syncthreads();
    const int wave = threadIdx.x >> 6, lane = threadIdx.x & 63;
    const int n = blk * 4 + wave;
    const float qx = px[n], qy = py[n], qz = pz[n];
    float d[13];
    #pragma unroll
    for (int s = 0; s < 13; s++) {
        int j = s * 64 + lane;
        float dx = qx - px[j], dy = qy - py[j], dz = qz - pz[j];
        d[s] = dx * dx + dy * dy + dz * dz;
    }
    int keep = 0;
    #pragma unroll
    for (int it = 0; it < 16; it++) {
        float bv = d[0]; int bs = 0;
        #pragma unroll
        for (int s = 1; s < 13; s++) { if (d[s] < bv) { bv = d[s]; bs = s; } }
        float v = bv; int jj = bs * 64 + lane;
        #pragma unroll
        for (int off = 32; off; off >>= 1) {
            float ov = __shfl_xor(v, off);
            int oj = __shfl_xor(jj, off);
            if (ov < v || (ov == v && oj < jj)) { v = ov; jj = oj; }
        }
        if (lane == (jj & 63)) {
            int sl = jj >> 6;
            #pragma unroll
            for (int s = 0; s < 13; s++) if (s == sl) d[s] = 3.4e38f;
        }
        if (lane == it) keep = jj;
    }
    if (lane < 16) IDX[((size_t)(b * NN + n)) * 16 + lane] = keep;
}

// ---------------------------------------------------------------- merged elementwise prep
#define PRB_MAP   30720
#define PRB_AG    (PRB_MAP + 2688)
#define PRB_PE    (PRB_AG + MTOT)
#define PRB_PN    (PRB_PE + 1480)
#define PRB_TOT   (PRB_PN + 18432)
#define W1P_O   0
#define W2S_O   2048
#define W3S_O   6144
#define MW1A_O  10240
#define MW1B_O  14336
#define MW2S_O  18432
#define OW1S_O  22528
#define OW2S_O  26624
#define APW_O   43008
#define AW1A_O  51200
#define AW1B_O  116736
#define AW2S_O  182272
#define AOW1_O  247808
#define AOW2_O  313344
#define WPN_TOT 378880
__global__ __launch_bounds__(256) void prep_all(
    const float* __restrict__ mp, const float* __restrict__ obj,
    const float* __restrict__ opos, const float* __restrict__ mpos,
    const float* __restrict__ wqkv, const float* __restrict__ wo,
    const float* __restrict__ f1w, const float* __restrict__ f2w,
    const float* __restrict__ m_pre_w1, const float* __restrict__ m_pre_w2,
    const float* __restrict__ m_pre_w3, const float* __restrict__ m_mlp_w1,
    const float* __restrict__ m_mlp_w2, const float* __restrict__ m_out_w1,
    const float* __restrict__ m_out_w2,
    const float* __restrict__ a_pre_w,  const float* __restrict__ a_mlp_w1,
    const float* __restrict__ a_mlp_w2, const float* __restrict__ a_out_w1,
    const float* __restrict__ a_out_w2,
    h16* __restrict__ pmap, h16* __restrict__ pagent,
    h16* __restrict__ PE16, h16* __restrict__ wpnf, h16* __restrict__ whf)
{
    const int bid = blockIdx.x;
    const int tid = threadIdx.x;
    if (bid < PRB_MAP) {
        int e = bid * 256 + tid;
        int r = e >> 5, c = e & 31;
        float v = (c < CMx) ? mp[(size_t)r * CMx + c] : 0.f;
        pmap[e] = (h16)v;
    } else if (bid < PRB_AG) {
        int e = (bid - PRB_MAP) * 256 + tid;
        int r = e >> 5, c = e & 31;
        float v = (c < CAx) ? obj[(size_t)r * CAx + c] : ((c == CAx) ? 1.0f : 0.f);
        pagent[e] = (h16)v;
    } else if (bid < PRB_PE) {
        int row = bid - PRB_AG;
        int b = row / NN, n = row % NN;
        const float* p = (n < NO) ? &opos[(size_t)(b * NO + n) * 3]
                                  : &mpos[(size_t)(b * NM + (n - NO)) * 3];
        float x = p[0], y = p[1];
        int j = tid & 127;
        float v = (tid < 128) ? y : x;
        float inv_dt = exp2f(-(float)(j & ~1) * 0.10381025296523f);
        float e = v * 6.283185307179586f * inv_dt;
        PE16[(size_t)row * DD + tid] = (h16)((j & 1) ? cosf(e) : sinf(e));
    } else if (bid < PRB_PN) {
        int e = (bid - PRB_PE) * 256 + tid;
        float v;
        if (e < W2S_O)       { int n = e >> 5, k = e & 31; v = (k < 9) ? m_pre_w1[n * 9 + k] : 0.f; }
        else if (e < W3S_O)  v = m_pre_w2[e - W2S_O];
        else if (e < MW1A_O) v = m_pre_w3[e - W3S_O];
        else if (e < MW1B_O) { int r = e - MW1A_O; v = m_mlp_w1[(r >> 6) * 128 + (r & 63)]; }
        else if (e < MW2S_O) { int r = e - MW1B_O; v = m_mlp_w1[(r >> 6) * 128 + 64 + (r & 63)]; }
        else if (e < OW1S_O) v = m_mlp_w2[e - MW2S_O];
        else if (e < OW2S_O) v = m_out_w1[e - OW1S_O];
        else if (e < APW_O)  v = m_out_w2[e - OW2S_O];
        else if (e < AW1A_O) { int r = e - APW_O; int n = r >> 5, k = r & 31; v = (k < 30) ? a_pre_w[n * 30 + k] : 0.f; }
        else if (e < AW1B_O) { int r = e - AW1A_O; v = a_mlp_w1[(r >> 8) * 512 + (r & 255)]; }
        else if (e < AW2S_O) { int r = e - AW1B_O; v = a_mlp_w1[(r >> 8) * 512 + 256 + (r & 255)]; }
        else if (e < AOW1_O) v = a_mlp_w2[e - AW2S_O];
        else if (e < AOW2_O) v = a_out_w1[e - AOW1_O];
        else                 v = a_out_w2[e - AOW2_O];
        wpnf[e] = (h16)v;
    } else {
        size_t e = (size_t)(bid - PRB_PN) * 256 + tid;
        int L = (int)(e / 786432);
        int r = (int)(e % 786432);
        float v;
        if (r < 196608)      v = wqkv[(size_t)L * 196608 + r];
        else if (r < 262144) v = wo[(size_t)L * 65536 + (r - 196608)];
        else if (r < 524288) v = f1w[(size_t)L * 262144 + (r - 262144)];
        else                 v = f2w[(size_t)L * 262144 + (r - 524288)];
        whf[e] = (h16)v;
    }
}

// ---------------------------------------------------------------- max-pool over P points, 8-wide
template<int P>
__global__ __launch_bounds__(256) void pool_max8(
    const h16* __restrict__ in, h16* __restrict__ out, int cshift)
{
    int e8 = blockIdx.x * 256 + threadIdx.x;
    int C = 1 << cshift;
    int base = e8 * 8;
    int g = base >> cshift, c = base & (C - 1);
    float m0 = -3.4e38f, m1 = m0, m2 = m0, m3 = m0, m4 = m0, m5 = m0, m6 = m0, m7 = m0;
    #pragma unroll
    for (int p = 0; p < P; p++) {
        h8v v = *(const h8v*)&in[((size_t)(g * P + p) << cshift) + c];
        m0 = fmaxf(m0, (float)v[0]); m1 = fmaxf(m1, (float)v[1]);
        m2 = fmaxf(m2, (float)v[2]); m3 = fmaxf(m3, (float)v[3]);
        m4 = fmaxf(m4, (float)v[4]); m5 = fmaxf(m5, (float)v[5]);
        m6 = fmaxf(m6, (float)v[6]); m7 = fmaxf(m7, (float)v[7]);
    }
    h8v o;
    o[0] = (h16)m0; o[1] = (h16)m1; o[2] = (h16)m2; o[3] = (h16)m3;
    o[4] = (h16)m4; o[5] = (h16)m5; o[6] = (h16)m6; o[7] = (h16)m7;
    *(h8v*)&out[((size_t)g << cshift) + c] = o;
}

// ---------------------------------------------------------------- pointnet GEMM (fp16 MFMA)
template<int BN, bool RELU, bool F16OUT, bool ROWMAP>
__global__ __launch_bounds__(256) void gemm_pn(
    const h16* __restrict__ A, const h16* __restrict__ W,
    const float* __restrict__ bias,
    const float* __restrict__ addrow, int ardiv, int arld,
    float* __restrict__ Cf, h16* __restrict__ C16,
    int K, int ldc, int rm_div, int rm_mul, int rm_add)
{
    constexpr int WAVES_M = (BN == 64) ? 4 : 2;
    constexpr int WM = 128 / (16 * WAVES_M);
    __shared__ __align__(16) h16 AS[128][32];
    __shared__ __align__(16) h16 WS[BN][32];
    const int m0 = blockIdx.x * 128;
    const int n0 = blockIdx.y * BN;
    const int tid = threadIdx.x;
    const int wave = tid >> 6, lane = tid & 63;
    const int wr = (BN == 64) ? wave : (wave >> 1);
    const int wc = (BN == 64) ? 0 : (wave & 1);
    const int fr = lane & 15, kb = lane >> 4;
    const int lrow = lane >> 2, lcol = SWZ_LCOL(lane);
    const int rdo = SWZ_RD(kb, fr);

    f4v acc[WM][4];
    #pragma unroll
    for (int i = 0; i < WM; i++)
        #pragma unroll
        for (int j = 0; j < 4; j++) { f4v z = {0.f, 0.f, 0.f, 0.f}; acc[i][j] = z; }

    for (int k0 = 0; k0 < K; k0 += 32) {
        __syncthreads();
        #pragma unroll
        for (int i = 0; i < 2; i++) {
            const int r = wave * 32 + i * 16;
            GLOAD_LDS16(&A[(size_t)(m0 + r + lrow) * K + k0 + lcol], &AS[r][0]);
        }
        if constexpr (BN == 64) {
            const int r = wave * 16;
            GLOAD_LDS16(&W[(size_t)(n0 + r + lrow) * K + k0 + lcol], &WS[r][0]);
        } else {
            #pragma unroll
            for (int i = 0; i < 2; i++) {
                const int r = wave * 32 + i * 16;
                GLOAD_LDS16(&W[(size_t)(n0 + r + lrow) * K + k0 + lcol], &WS[r][0]);
            }
        }
        __syncthreads();
        h8v af[WM];
        #pragma unroll
        for (int mi = 0; mi < WM; mi++)
            af[mi] = *(const h8v*)&AS[wr * (WM * 16) + mi * 16 + fr][rdo];
        #pragma unroll
        for (int nj = 0; nj < 4; nj++) {
            h8v bf = *(const h8v*)&WS[wc * 64 + nj * 16 + fr][rdo];
            #pragma unroll
            for (int mi = 0; mi < WM; mi++)
                acc[mi][nj] = __builtin_amdgcn_mfma_f32_16x16x32_f16(af[mi], bf, acc[mi][nj], 0, 0, 0);
        }
    }
    #pragma unroll
    for (int mi = 0; mi < WM; mi++) {
        #pragma unroll
        for (int nj = 0; nj < 4; nj++) {
            int col = n0 + wc * 64 + nj * 16 + fr;
            float bb = bias ? bias[col] : 0.f;
            #pragma unroll
            for (int r = 0; r < 4; r++) {
                int row = m0 + wr * (WM * 16) + mi * 16 + (lane >> 4) * 4 + r;
                float v = acc[mi][nj][r] + bb;
                if (addrow) v += addrow[(size_t)(row / ardiv) * arld + col];
                if (RELU) v = fmaxf(v, 0.f);
                if (F16OUT) {
                    C16[(size_t)row * ldc + col] = (h16)v;
                } else {
                    int drow = row;
                    if (ROWMAP) drow = row + rm_add + (row / rm_div) * rm_mul;
                    Cf[(size_t)drow * ldc + col] = v;
                }
            }
        }
    }
}

// ---------------------------------------------------------------- initial activation cvt
__global__ __launch_bounds__(256) void split_x0(
    const float* __restrict__ X, const h16* __restrict__ PE16,
    h16* __restrict__ X16, h16* __restrict__ XP16)
{
    size_t base = ((size_t)blockIdx.x * 256 + threadIdx.x) * 4;
    float4 x = *(const float4*)&X[base];
    h4v pe = *(const h4v*)&PE16[base];
    h4v a, b;
    a.x = (h16)x.x; a.y = (h16)x.y; a.z = (h16)x.z; a.w = (h16)x.w;
    b.x = (h16)(x.x + (float)pe.x); b.y = (h16)(x.y + (float)pe.y);
    b.z = (h16)(x.z + (float)pe.z); b.w = (h16)(x.w + (float)pe.w);
    *(h4v*)&X16[base] = a;
    *(h4v*)&XP16[base] = b;
}

// ---------------------------------------------------------------- fused map pre1->pre2->pre3
__global__ __launch_bounds__(256) void fused_map3(
    const h16* __restrict__ A,   // [MAPR][32]
    const h16* __restrict__ W1,  // [64][32]
    const h16* __restrict__ W2, const h16* __restrict__ W3,  // [64][64]
    const float* __restrict__ b1, const float* __restrict__ b2, const float* __restrict__ b3,
    h16* __restrict__ Out)       // [MAPR][64]
{
    __shared__ __align__(16) h16 AS[128][32];
    __shared__ __align__(16) h16 G0[2][128][32];
    __shared__ __align__(16) h16 G1[2][128][32];
    __shared__ __align__(16) h16 W1S[64][32];
    __shared__ __align__(16) h16 W2S[2][64][32];
    __shared__ __align__(16) h16 W3S[2][64][32];
    const int m0 = blockIdx.x * 128;
    const int tid = threadIdx.x;
    const int wave = tid >> 6, lane = tid & 63;
    const int fr = lane & 15, kb = lane >> 4;
    const int lrow = lane >> 2, lcol = SWZ_LCOL(lane);
    const int rdo = SWZ_RD(kb, fr);

    #pragma unroll
    for (int q = 0; q < 2; q++)
        GLOAD_LDS16(&A[(size_t)(m0 + wave * 32 + q * 16 + lrow) * 32 + lcol],
                    &AS[wave * 32 + q * 16][0]);
    GLOAD_LDS16(&W1[(size_t)(wave * 16 + lrow) * 32 + lcol], &W1S[wave * 16][0]);
    #pragma unroll
    for (int t = 0; t < 2; t++) {
        GLOAD_LDS16(&W2[(size_t)(wave * 16 + lrow) * 64 + t * 32 + lcol], &W2S[t][wave * 16][0]);
        GLOAD_LDS16(&W3[(size_t)(wave * 16 + lrow) * 64 + t * 32 + lcol], &W3S[t][wave * 16][0]);
    }
    __syncthreads();
    #pragma unroll
    for (int mi = 0; mi < 2; mi++) {
        h8v af = *(const h8v*)&AS[wave * 32 + mi * 16 + fr][rdo];
        #pragma unroll
        for (int nj = 0; nj < 4; nj++) {
            f4v a = {0.f, 0.f, 0.f, 0.f};
            h8v bf = *(const h8v*)&W1S[nj * 16 + fr][rdo];
            a = __builtin_amdgcn_mfma_f32_16x16x32_f16(af, bf, a, 0, 0, 0);
            int col = nj * 16 + fr, ch = col >> 5, kl = col & 31;
            float bb = b1[col];
            #pragma unroll
            for (int r = 0; r < 4; r++) {
                int row = wave * 32 + mi * 16 + kb * 4 + r;
                G0[ch][row][SWZ_ELEM(row, kl)] = (h16)fmaxf(a[r] + bb, 0.f);
            }
        }
    }
    __syncthreads();
    #pragma unroll
    for (int mi = 0; mi < 2; mi++) {
        #pragma unroll
        for (int nj = 0; nj < 4; nj++) {
            f4v a = {0.f, 0.f, 0.f, 0.f};
            #pragma unroll
            for (int t = 0; t < 2; t++) {
                h8v af = *(const h8v*)&G0[t][wave * 32 + mi * 16 + fr][rdo];
                h8v bf = *(const h8v*)&W2S[t][nj * 16 + fr][rdo];
                a = __builtin_amdgcn_mfma_f32_16x16x32_f16(af, bf, a, 0, 0, 0);
            }
            int col = nj * 16 + fr, ch = col >> 5, kl = col & 31;
            float bb = b2[col];
            #pragma unroll
            for (int r = 0; r < 4; r++) {
                int row = wave * 32 + mi * 16 + kb * 4 + r;
                G1[ch][row][SWZ_ELEM(row, kl)] = (h16)fmaxf(a[r] + bb, 0.f);
            }
        }
    }
    __syncthreads();
    #pragma unroll
    for (int mi = 0; mi < 2; mi++) {
        #pragma unroll
        for (int nj = 0; nj < 4; nj++) {
            f4v a = {0.f, 0.f, 0.f, 0.f};
            #pragma unroll
            for (int t = 0; t < 2; t++) {
                h8v af = *(const h8v*)&G1[t][wave * 32 + mi * 16 + fr][rdo];
                h8v bf = *(const h8v*)&W3S[t][nj * 16 + fr][rdo];
                a = __builtin_amdgcn_mfma_f32_16x16x32_f16(af, bf, a, 0, 0, 0);
            }
            int col = nj * 16 + fr;
            float bb = b3[col];
            #pragma unroll
            for (int r = 0; r < 4; r++) {
                int row = m0 + wave * 32 + mi * 16 + kb * 4 + r;
                Out[(size_t)row * 64 + col] = (h16)fmaxf(a[r] + bb, 0.f);
            }
        }
    }
}

// ---------------------------------------------------------------- fused map mid1->mid2
// mid1 bias b1 is carried entirely by `pooled` (PCf = pooled@W1B + b1).
__global__ __launch_bounds__(256) void fused_map2(
    const h16* __restrict__ A,   // [MAPR][64]
    const h16* __restrict__ W1,  // MW1A [64][64]
    const h16* __restrict__ W2,  // MW2S [64][64]
    const float* __restrict__ b2,
    const float* __restrict__ pooled,  // PCf [12288][64] f32 (includes b1)
    h16* __restrict__ Out)       // [MAPR][64]
{
    __shared__ __align__(16) h16 AS[2][128][32];
    __shared__ __align__(16) h16 G0[2][128][32];
    __shared__ __align__(16) h16 W1S[2][64][32];
    __shared__ __align__(16) h16 W2S[2][64][32];
    const int m0 = blockIdx.x * 128;
    const int tid = threadIdx.x;
    const int wave = tid >> 6, lane = tid & 63;
    const int fr = lane & 15, kb = lane >> 4;
    const int lrow = lane >> 2, lcol = SWZ_LCOL(lane);
    const int rdo = SWZ_RD(kb, fr);

    #pragma unroll
    for (int t = 0; t < 2; t++) {
        #pragma unroll
        for (int q = 0; q < 2; q++)
            GLOAD_LDS16(&A[(size_t)(m0 + wave * 32 + q * 16 + lrow) * 64 + t * 32 + lcol],
                        &AS[t][wave * 32 + q * 16][0]);
        GLOAD_LDS16(&W1[(size_t)(wave * 16 + lrow) * 64 + t * 32 + lcol], &W1S[t][wave * 16][0]);
        GLOAD_LDS16(&W2[(size_t)(wave * 16 + lrow) * 64 + t * 32 + lcol], &W2S[t][wave * 16][0]);
    }
    __syncthreads();
    #pragma unroll
    for (int mi = 0; mi < 2; mi++) {
        #pragma unroll
        for (int nj = 0; nj < 4; nj++) {
            f4v a = {0.f, 0.f, 0.f, 0.f};
            #pragma unroll
            for (int t = 0; t < 2; t++) {
                h8v af = *(const h8v*)&AS[t][wave * 32 + mi * 16 + fr][rdo];
                h8v bf = *(const h8v*)&W1S[t][nj * 16 + fr][rdo];
                a = __builtin_amdgcn_mfma_f32_16x16x32_f16(af, bf, a, 0, 0, 0);
            }
            int col = nj * 16 + fr, ch = col >> 5, kl = col & 31;
            #pragma unroll
            for (int r = 0; r < 4; r++) {
                int row = wave * 32 + mi * 16 + kb * 4 + r;
                int grow = m0 + row;
                float v = a[r] + pooled[(size_t)(grow / PP) * 64 + col];
                G0[ch][row][SWZ_ELEM(row, kl)] = (h16)fmaxf(v, 0.f);
            }
        }
    }
    __syncthreads();
    #pragma unroll
    for (int mi = 0; mi < 2; mi++) {
        #pragma unroll
        for (int nj = 0; nj < 4; nj++) {
            f4v a = {0.f, 0.f, 0.f, 0.f};
            #pragma unroll
            for (int t = 0; t < 2; t++) {
                h8v af = *(const h8v*)&G0[t][wave * 32 + mi * 16 + fr][rdo];
                h8v bf = *(const h8v*)&W2S[t][nj * 16 + fr][rdo];
                a = __builtin_amdgcn_mfma_f32_16x16x32_f16(af, bf, a, 0, 0, 0);
            }
            int col = nj * 16 + fr;
            float bb = b2[col];
            #pragma unroll
            for (int r = 0; r < 4; r++) {
                int row = m0 + wave * 32 + mi * 16 + kb * 4 + r;
                Out[(size_t)row * 64 + col] = (h16)fmaxf(a[r] + bb, 0.f);
            }
        }
    }
}

// ---------------------------------------------------------------- transformer fp16 MFMA GEMM
template<bool RELU, bool F16OUT>
__global__ __launch_bounds__(256) void gemm_mfma(
    const h16* __restrict__ A, const h16* __restrict__ A2, int a2min,
    const h16* __restrict__ W, const float* __restrict__ bias,
    float* __restrict__ Cf, h16* __restrict__ C16,
    int K, int ldc, int coff, float scale, int scale_until)
{
    __shared__ __align__(16) h16 AS[128][32];
    __shared__ __align__(16) h16 WS[128][32];
    const int m0 = blockIdx.x * 128;
    const int n0 = blockIdx.y * 128;
    const h16* pA = (n0 >= a2min) ? A2 : A;
    const int tid = threadIdx.x;
    const int wave = tid >> 6, lane = tid & 63;
    const int wr = wave >> 1, wc = wave & 1;
    const int fr = lane & 15, kb = lane >> 4;
    const int lrow = lane >> 2;
    const int lcol = SWZ_LCOL(lane);
    const int rdo = SWZ_RD(kb, fr);

    f4v acc[4][4];
    #pragma unroll
    for (int i = 0; i < 4; i++)
        #pragma unroll
        for (int j = 0; j < 4; j++) { f4v z = {0.f, 0.f, 0.f, 0.f}; acc[i][j] = z; }

    for (int k0 = 0; k0 < K; k0 += 32) {
        __syncthreads();
        #pragma unroll
        for (int i = 0; i < 2; i++) {
            const int r = wave * 32 + i * 16;
            const size_t grow = (size_t)(r + lrow);
            GLOAD_LDS16(&pA[(m0 + grow) * K + k0 + lcol], &AS[r][0]);
            GLOAD_LDS16(&W [(n0 + grow) * K + k0 + lcol], &WS[r][0]);
        }
        __syncthreads();
        h8v af[4];
        #pragma unroll
        for (int mi = 0; mi < 4; mi++)
            af[mi] = *(const h8v*)&AS[wr * 64 + mi * 16 + fr][rdo];
        #pragma unroll
        for (int nj = 0; nj < 4; nj++) {
            h8v bf = *(const h8v*)&WS[wc * 64 + nj * 16 + fr][rdo];
            #pragma unroll
            for (int mi = 0; mi < 4; mi++)
                acc[mi][nj] = __builtin_amdgcn_mfma_f32_16x16x32_f16(af[mi], bf, acc[mi][nj], 0, 0, 0);
        }
    }
    #pragma unroll
    for (int mi = 0; mi < 4; mi++) {
        #pragma unroll
        for (int nj = 0; nj < 4; nj++) {
            int col = n0 + wc * 64 + nj * 16 + fr;
            float bb = bias[col];
            #pragma unroll
            for (int r = 0; r < 4; r++) {
                int row = m0 + wr * 64 + mi * 16 + (lane >> 4) * 4 + r;
                float v = acc[mi][nj][r] + bb;
                if (RELU) v = fmaxf(v, 0.f);
                int gcol = coff + col;
                if (gcol < scale_until) v *= scale;
                if (F16OUT) {
                    C16[(size_t)row * ldc + gcol] = (h16)v;
                } else {
                    Cf[(size_t)row * ldc + gcol] = v;
                }
            }
        }
    }
}

// ---------------------------------------------------------------- fused O-proj+LN1+FFN1+FFN2+LN2
// 64 rows/block, 8 waves (4 wr x 2 wc). Ping-pong double-buffered weight staging:
// the next phase's chunk is issued into the free buffer right after each barrier,
// so the global_load_lds transfer overlaps the current phase's MFMA (drain is short).
// Phases: O-proj oc0..3 (64-col chunks, U0/U1/U0/U1; oc3 prefetches W1[0]->U0);
// FFN c=0..15: W1-phase (U0 fixed) prefetches W2[c]->U1; W2-phase (U1) prefetches W1[c+1]->U0.
// PEMODE 1: write X16 + XP16(=h16(o+PE)).  PEMODE 2: write fp32 d_out.
template<int PEMODE>
__global__ __launch_bounds__(512) void fused_layer(
    const h16* __restrict__ AO16, const h16* __restrict__ Wo,   // [256][256]
    const float* __restrict__ bo, const h16* __restrict__ X16r,
    const float* __restrict__ g1, const float* __restrict__ bt1,
    const h16* __restrict__ W1,   // [1024][256]
    const h16* __restrict__ W2,   // [256][1024]
    const float* __restrict__ b1, const float* __restrict__ b2,
    const float* __restrict__ g2, const float* __restrict__ bt2,
    float* __restrict__ OutF, h16* __restrict__ O16,
    const h16* __restrict__ PE16p, h16* __restrict__ P16)
{
    __shared__ __align__(16) h16 AOS[8][64][32];   // 32 KB: AO tile (k-tiles)
    __shared__ __align__(16) h16 HS[8][64][32];    // 32 KB: post-LN h (col-chunk tiles)
    __shared__ __align__(16) h16 GS[2][64][32];    // 8 KB: relu'd hidden chunk (64)
    __shared__ __align__(16) h16 U0[16384];        // 32 KB ping
    __shared__ __align__(16) h16 U1[16384];        // 32 KB pong
    __shared__ float red_s[2][8][64];              // 4 KB
    const int m0 = blockIdx.x * 64;
    const int tid = threadIdx.x;
    const int wave = tid >> 6, lane = tid & 63;
    const int wr = wave >> 1, wc = wave & 1;
    const int fr = lane & 15, kb = lane >> 4;
    const int lrow = lane >> 2, lcol = SWZ_LCOL(lane);
    const int rdo = SWZ_RD(kb, fr);

    // stage a 64-row x 256-k panel (k-tile t = wave) into dst
    auto stage_p64 = [&](const h16* src, h16* dst) {
        #pragma unroll
        for (int q = 0; q < 4; q++)
            GLOAD_LDS16(&src[(size_t)(q * 16 + lrow) * 256 + wave * 32 + lcol],
                        &dst[wave * 2048 + (q * 16) * 32]);
    };
    // stage W2 chunk c (256 rows x 64 hidden as 2 k-tiles) into dst
    auto stage_w2 = [&](int c, h16* dst) {
        #pragma unroll
        for (int t2 = 0; t2 < 2; t2++)
            #pragma unroll
            for (int q = 0; q < 2; q++)
                GLOAD_LDS16(&W2[(size_t)(wave * 32 + q * 16 + lrow) * 1024 + c * 64 + t2 * 32 + lcol],
                            &dst[t2 * 8192 + (wave * 32 + q * 16) * 32]);
    };

    // prologue: AO tile + first Wo chunk
    #pragma unroll
    for (int q = 0; q < 4; q++)
        GLOAD_LDS16(&AO16[(size_t)(m0 + q * 16 + lrow) * 256 + wave * 32 + lcol],
                    &AOS[wave][q * 16][0]);
    stage_p64(Wo, U0);
    __syncthreads();   // AOS + U0 ready

    h8v aof[8];
    #pragma unroll
    for (int t = 0; t < 8; t++)
        aof[t] = *(const h8v*)&AOS[t][wr * 16 + fr][rdo];

    // ---- stage 0: O-proj (4 col-chunks of 64) + residual(X16r) + LN1 stats
    float xo[4][2][4];
    float rsum1[4] = {0.f, 0.f, 0.f, 0.f}, rsq1[4] = {0.f, 0.f, 0.f, 0.f};
    #pragma unroll
    for (int oc = 0; oc < 4; oc++) {
        const h16* Ucur = (oc & 1) ? U1 : U0;
        h16* Unxt = (oc & 1) ? U0 : U1;
        // prefetch next chunk into the free buffer (readers of Unxt finished at prev barrier)
        if (oc < 3) stage_p64(Wo + (size_t)(oc + 1) * 64 * 256, Unxt);
        else        stage_p64(W1, Unxt);   // oc=3: Unxt=U0 <- W1 chunk 0
        #pragma unroll
        for (int nj = 0; nj < 2; nj++) {
            f4v o1 = {0.f, 0.f, 0.f, 0.f};
            #pragma unroll
            for (int t = 0; t < 8; t++) {
                h8v bf = *(const h8v*)&Ucur[t * 2048 + (wc * 32 + nj * 16 + fr) * 32 + rdo];
                o1 = __builtin_amdgcn_mfma_f32_16x16x32_f16(aof[t], bf, o1, 0, 0, 0);
            }
            int col = oc * 64 + wc * 32 + nj * 16 + fr;
            float bb = bo[col];
            #pragma unroll
            for (int r = 0; r < 4; r++) {
                int row = wr * 16 + kb * 4 + r;
                float v = o1[r] + bb + (float)X16r[(size_t)(m0 + row) * 256 + col];
                xo[oc][nj][r] = v;
                rsum1[r] += v;
                rsq1[r] += v * v;
            }
        }
        __syncthreads();   // all waves done reading Ucur; Unxt drained
    }
    #pragma unroll
    for (int off = 1; off < 16; off <<= 1)
        #pragma unroll
        for (int r = 0; r < 4; r++) {
            rsum1[r] += __shfl_xor(rsum1[r], off);
            rsq1[r]  += __shfl_xor(rsq1[r], off);
        }
    // each wave owns row-group wr; zero-fill the other 3 groups
    if (fr < 4) {
        int grp = (wr + fr) & 3;
        #pragma unroll
        for (int r = 0; r < 4; r++) {
            red_s[0][wave][grp * 16 + kb * 4 + r] = (fr == 0) ? rsum1[r] : 0.f;
            red_s[1][wave][grp * 16 + kb * 4 + r] = (fr == 0) ? rsq1[r] : 0.f;
        }
    }
    __syncthreads();
    float mean1[4], inv1[4];
    #pragma unroll
    for (int r = 0; r < 4; r++) {
        int rid = wr * 16 + kb * 4 + r;
        float s = 0.f, sq = 0.f;
        #pragma unroll
        for (int w = 0; w < 8; w++) { s += red_s[0][w][rid]; sq += red_s[1][w][rid]; }
        mean1[r] = s * (1.f / 256.f);
        float var = sq * (1.f / 256.f) - mean1[r] * mean1[r];
        inv1[r] = rsqrtf(var + 1e-5f);
    }
    // write h = LN1(xo) into HS (col-chunk tile layout)
    #pragma unroll
    for (int oc = 0; oc < 4; oc++)
        #pragma unroll
        for (int nj = 0; nj < 2; nj++) {
            int col = oc * 64 + wc * 32 + nj * 16 + fr;
            int ch = col >> 5, kl = col & 31;
            float gg = g1[col], bb = bt1[col];
            #pragma unroll
            for (int r = 0; r < 4; r++) {
                int row = wr * 16 + kb * 4 + r;
                float h = (xo[oc][nj][r] - mean1[r]) * inv1[r] * gg + bb;
                HS[ch][row][SWZ_ELEM(row, kl)] = (h16)h;
            }
        }
    __syncthreads();   // HS ready

    // hoist h A-fragments (HS is chunk-invariant)
    h8v haf[8];
    #pragma unroll
    for (int t = 0; t < 8; t++)
        haf[t] = *(const h8v*)&HS[t][wr * 16 + fr][rdo];

    // ---- stage 1+2: FFN (hidden chunked by 64); W1[c] lives in U0, W2[c] in U1
    f4v acc2[8];
    #pragma unroll
    for (int j = 0; j < 8; j++) { f4v z = {0.f, 0.f, 0.f, 0.f}; acc2[j] = z; }

    for (int c = 0; c < 16; c++) {
        // W1 phase (U0): prefetch W2[c] -> U1 (U1 readers done at last barrier)
        stage_w2(c, U1);
        #pragma unroll
        for (int nj = 0; nj < 2; nj++) {
            f4v a1 = {0.f, 0.f, 0.f, 0.f};
            #pragma unroll
            for (int t = 0; t < 8; t++) {
                h8v bf = *(const h8v*)&U0[t * 2048 + (wc * 32 + nj * 16 + fr) * 32 + rdo];
                a1 = __builtin_amdgcn_mfma_f32_16x16x32_f16(haf[t], bf, a1, 0, 0, 0);
            }
            int n = wc * 32 + nj * 16 + fr;    // hidden index within chunk (0..63)
            int ch = n >> 5, kl = n & 31;
            float bb = b1[c * 64 + n];
            #pragma unroll
            for (int r = 0; r < 4; r++) {
                int row = wr * 16 + kb * 4 + r;
                GS[ch][row][SWZ_ELEM(row, kl)] = (h16)fmaxf(a1[r] + bb, 0.f);
            }
        }
        __syncthreads();   // GS visible; U0 reads done; U1 drained
        // W2 phase (U1): prefetch W1[c+1] -> U0 (U0 readers done at barrier above)
        if (c < 15) stage_p64(W1 + (size_t)(c + 1) * 64 * 256, U0);
        #pragma unroll
        for (int t2 = 0; t2 < 2; t2++) {
            h8v gaf = *(const h8v*)&GS[t2][wr * 16 + fr][rdo];
            #pragma unroll
            for (int nj = 0; nj < 8; nj++) {
                h8v bf = *(const h8v*)&U1[t2 * 8192 + (wc * 128 + nj * 16 + fr) * 32 + rdo];
                acc2[nj] = __builtin_amdgcn_mfma_f32_16x16x32_f16(gaf, bf, acc2[nj], 0, 0, 0);
            }
        }
        __syncthreads();   // U1 reads done; GS free; U0 drained
    }
    // ---- epilogue: x = h-residual(HS) + acc2 + b2; LN2; write
    float x[8][4];
    float rsum[4] = {0.f, 0.f, 0.f, 0.f}, rsq[4] = {0.f, 0.f, 0.f, 0.f};
    #pragma unroll
    for (int nj = 0; nj < 8; nj++) {
        int col = wc * 128 + nj * 16 + fr;
        int ch = col >> 5, kl = col & 31;
        float bb = b2[col];
        #pragma unroll
        for (int r = 0; r < 4; r++) {
            int row = wr * 16 + kb * 4 + r;
            float res = (float)HS[ch][row][SWZ_ELEM(row, kl)];
            float v = acc2[nj][r] + bb + res;
            x[nj][r] = v;
            rsum[r] += v;
            rsq[r] += v * v;
        }
    }
    #pragma unroll
    for (int off = 1; off < 16; off <<= 1)
        #pragma unroll
        for (int r = 0; r < 4; r++) {
            rsum[r] += __shfl_xor(rsum[r], off);
            rsq[r]  += __shfl_xor(rsq[r], off);
        }
    __syncthreads();   // red_s free from LN1
    if (fr < 4) {
        int grp = (wr + fr) & 3;
        #pragma unroll
        for (int r = 0; r < 4; r++) {
            red_s[0][wave][grp * 16 + kb * 4 + r] = (fr == 0) ? rsum[r] : 0.f;
            red_s[1][wave][grp * 16 + kb * 4 + r] = (fr == 0) ? rsq[r] : 0.f;
        }
    }
    __syncthreads();
    #pragma unroll
    for (int r = 0; r < 4; r++) {
        int rid = wr * 16 + kb * 4 + r;
        float s = 0.f, sq = 0.f;
        #pragma unroll
        for (int w = 0; w < 8; w++) { s += red_s[0][w][rid]; sq += red_s[1][w][rid]; }
        float mean = s * (1.f / 256.f);
        float var = sq * (1.f / 256.f) - mean * mean;
        float inv = rsqrtf(var + 1e-5f);
        #pragma unroll
        for (int nj = 0; nj < 8; nj++) {
            int col = wc * 128 + nj * 16 + fr;
            float o = (x[nj][r] - mean) * inv * g2[col] + bt2[col];
            size_t idx = (size_t)(m0 + rid) * 256 + col;
            if (PEMODE == 2) {
                OutF[idx] = o;
            } else {
                O16[idx] = (h16)o;
                P16[idx] = (h16)(o + (float)PE16p[idx]);
            }
        }
    }
}

// ---------------------------------------------------------------- local KNN attention (fp16 QKV)
__global__ __launch_bounds__(256) void attn_kernel(
    const h16* __restrict__ QKV16, const int* __restrict__ IDX,
    h16* __restrict__ AO16)
{
    __shared__ __align__(16) h16 Ks[32][256];
    __shared__ float p_s[2][HH][16];
    __shared__ int gid_s[2][16];
    const int sub = threadIdx.x >> 7;
    const int t = threadIdx.x & 127;
    const int wave = threadIdx.x >> 6, lane = threadIdx.x & 63;
    const int xcd = blockIdx.x & 7;
    const int j = blockIdx.x >> 3;            // 0..831
    const int b = (j / 416) * 8 + xcd;        // batch
    const int row = b * NN + (j % 416) * 2 + sub;
    const int h = t >> 4, k = t & 15;
    int nb = IDX[(size_t)row * 16 + k];
    int g = b * NN + nb;
    if (h == 0) gid_s[sub][k] = g;
    __syncthreads();
    #pragma unroll
    for (int i = 0; i < 4; i++) {
        int s0 = wave * 8 + i * 2;
        int s = s0 + (lane >> 5);
        int gs = gid_s[s >> 4][s & 15];
        int clog = (lane & 31) ^ (s & 7);
        GLOAD_LDS16(&QKV16[(size_t)gs * 768 + 256 + clog * 8], &Ks[s0][0]);
    }
    __syncthreads();
    const h16* q = &QKV16[(size_t)row * 768 + h * HDX];
    const int sidx = sub * 16 + k;
    float s = 0.f;
    #pragma unroll
    for (int c = 0; c < 4; c++) {
        h8v q8 = *(const h8v*)&q[c * 8];
        h8v k8 = *(const h8v*)&Ks[sidx][(((h * 4 + c) ^ (sidx & 7)) * 8)];
        #pragma unroll
        for (int e = 0; e < 8; e++) s += (float)q8[e] * (float)k8[e];
    }
    float m = s;
    #pragma unroll
    for (int off = 8; off; off >>= 1) m = fmaxf(m, __shfl_xor(m, off, 16));
    float e = expf(s - m);
    float sum = e;
    #pragma unroll
    for (int off = 8; off; off >>= 1) sum += __shfl_xor(sum, off, 16);
    p_s[sub][h][k] = e / sum;
    __syncthreads();
    const int d0 = t * 2;
    const int hh = d0 >> 5, dd = d0 & 31;
    float o0 = 0.f, o1 = 0.f;
    #pragma unroll
    for (int kk = 0; kk < 16; kk++) {
        int gg = gid_s[sub][kk];
        const h16* vr = &QKV16[(size_t)gg * 768 + 512 + hh * HDX + dd];
        float p = p_s[sub][hh][kk];
        o0 += p * (float)vr[0];
        o1 += p * (float)vr[1];
    }
    size_t base = (size_t)row * DD + d0;
    AO16[base] = (h16)o0;
    AO16[base + 1] = (h16)o1;
}

// ----------------------------------------------------------------
extern "C" void kernel_launch(void* const* d_in, const int* in_sizes, int n_in,
                              void* d_out, int out_size, void* d_ws, size_t ws_size,
                              hipStream_t stream)
{
    const float* obj      = (const float*)d_in[0];
    const float* mp       = (const float*)d_in[1];
    const float* opos     = (const float*)d_in[2];
    const float* mpos     = (const float*)d_in[3];
    const float* a_pre_w  = (const float*)d_in[4];
    const float* a_pre_b  = (const float*)d_in[5];
    const float* a_mlp_w1 = (const float*)d_in[6];
    const float* a_mlp_b1 = (const float*)d_in[7];
    const float* a_mlp_w2 = (const float*)d_in[8];
    const float* a_mlp_b2 = (const float*)d_in[9];
    const float* a_out_w1 = (const float*)d_in[10];
    const float* a_out_b1 = (const float*)d_in[11];
    const float* a_out_w2 = (const float*)d_in[12];
    const float* a_out_b2 = (const float*)d_in[13];
    const float* m_pre_w1 = (const float*)d_in[14];
    const float* m_pre_b1 = (const float*)d_in[15];
    const float* m_pre_w2 = (const float*)d_in[16];
    const float* m_pre_b2 = (const float*)d_in[17];
    const float* m_pre_w3 = (const float*)d_in[18];
    const float* m_pre_b3 = (const float*)d_in[19];
    const float* m_mlp_w1 = (const float*)d_in[20];
    const float* m_mlp_b1 = (const float*)d_in[21];
    const float* m_mlp_w2 = (const float*)d_in[22];
    const float* m_mlp_b2 = (const float*)d_in[23];
    const float* m_out_w1 = (const float*)d_in[24];
    const float* m_out_b1 = (const float*)d_in[25];
    const float* m_out_w2 = (const float*)d_in[26];
    const float* m_out_b2 = (const float*)d_in[27];
    const float* attn_wqkv = (const float*)d_in[28];
    const float* attn_bqkv = (const float*)d_in[29];
    const float* attn_wo   = (const float*)d_in[30];
    const float* attn_bo   = (const float*)d_in[31];
    const float* ffn_w1    = (const float*)d_in[32];
    const float* ffn_b1    = (const float*)d_in[33];
    const float* ffn_w2    = (const float*)d_in[34];
    const float* ffn_b2    = (const float*)d_in[35];
    const float* ln1_g     = (const float*)d_in[36];
    const float* ln1_b     = (const float*)d_in[37];
    const float* ln2_g     = (const float*)d_in[38];
    const float* ln2_b     = (const float*)d_in[39];

    const size_t M = MTOT;  // 13312
    float* ws   = (float*)d_ws;
    float* X    = ws;                 // M*256 f32 (pointnet out staging)
    float* PEr  = X   + M * 256;      // PE16 region
    float* QKVr = PEr + M * 256;      // aliased region
    float* Hpad = QKVr + M * 768;     // padding region
    h16* AO16   = (h16*)(Hpad + M * 256);
    h16* X16    = AO16 + M * 256;
    h16* XP16   = X16  + M * 256;
    h16* H16    = XP16 + M * 256;     // unused now (layout stability)
    h16* whf    = H16  + M * 256;     // 4,718,592 fp16
    h16* wpnf   = whf  + 4718592;
    int* IDX    = (int*)(wpnf + WPN_TOT);

    h16* PE16 = (h16*)PEr;
    h16* QKV16 = (h16*)QKVr;          // M*768 fp16 (live QKV-gemm..attn)

    // pointnet-phase aliases (QKVr..AO16 dead window during pre-phase;
    // X16/XP16 written ONLY by split_x0 after all pointnet buffers are dead)
    h16* PN0f = (h16*)QKVr;
    h16* PN1f = PN0f + 15728640;
    h16* SB   = PN0f + 31457280;
    h16* PLf  = SB;
    h16* GMf  = SB + 786432;
    h16* HVf  = SB + 1572864;
    h16* APLf = SB + 2359296;
    h16* AGMf = SB + 2621440;
    h16* AHVf = SB + 2883584;
    float* PCf = (float*)(SB + 3145728);
    float* APC = PCf + 786432;

    // ---------------- pre-phase ----------------
    knn_kernel<<<BB * 208, 256, 0, stream>>>(opos, mpos, IDX);
    prep_all<<<PRB_TOT, 256, 0, stream>>>(
        mp, obj, opos, mpos,
        attn_wqkv, attn_wo, ffn_w1, ffn_w2,
        m_pre_w1, m_pre_w2, m_pre_w3, m_mlp_w1, m_mlp_w2, m_out_w1, m_out_w2,
        a_pre_w, a_mlp_w1, a_mlp_w2, a_out_w1, a_out_w2,
        PN0f /*pmap*/, PN1f /*pagent*/, PE16, wpnf, whf);

    // ---- agent pointnet as GEMM chain (pagent staged in PN1f)
    {
        h16* PA32 = PN1f;
        h16* PB   = PN0f + 7864320;
        h16* PA2  = PN1f;
        gemm_pn<128, true, true, false><<<dim3(168, 2), 256, 0, stream>>>(
            PA32, wpnf + APW_O, a_pre_b, nullptr, 1, 0,
            nullptr, PB, 32, 256, 1, 0, 0);
        pool_max8<21><<<128, 256, 0, stream>>>(PB, APLf, 8);
        gemm_pn<128, false, false, false><<<dim3(8, 2), 256, 0, stream>>>(
            APLf, wpnf + AW1B_O, a_mlp_b1, nullptr, 1, 0,
            APC, nullptr, 256, 256, 1, 0, 0);
        gemm_pn<128, true, true, false><<<dim3(168, 2), 256, 0, stream>>>(
            PB, wpnf + AW1A_O, nullptr, APC, 21, 256,
            nullptr, PA2, 256, 256, 1, 0, 0);
        gemm_pn<128, true, true, false><<<dim3(168, 2), 256, 0, stream>>>(
            PA2, wpnf + AW2S_O, a_mlp_b2, nullptr, 1, 0,
            nullptr, PB, 256, 256, 1, 0, 0);
        pool_max8<21><<<128, 256, 0, stream>>>(PB, AGMf, 8);
        gemm_pn<128, true, true, false><<<dim3(8, 2), 256, 0, stream>>>(
            AGMf, wpnf + AOW1_O, a_out_b1, nullptr, 1, 0,
            nullptr, AHVf, 256, 256, 1, 0, 0);
        gemm_pn<128, false, false, true><<<dim3(8, 2), 256, 0, stream>>>(
            AHVf, wpnf + AOW2_O, a_out_b2, nullptr, 1, 0,
            X, nullptr, 256, 256, 64, 768, 0);
    }

    // ---- map pointnet: fused chains (pmap in PN0f)
    {
        fused_map3<<<MAPR / 128, 256, 0, stream>>>(
            PN0f, wpnf + W1P_O, wpnf + W2S_O, wpnf + W3S_O,
            m_pre_b1, m_pre_b2, m_pre_b3, PN1f);
        pool_max8<20><<<384, 256, 0, stream>>>(PN1f, PLf, 6);
        gemm_pn<64, false, false, false><<<dim3(96, 1), 256, 0, stream>>>(
            PLf, wpnf + MW1B_O, m_mlp_b1, nullptr, 1, 0,
            PCf, nullptr, 64, 64, 1, 0, 0);
        fused_map2<<<MAPR / 128, 256, 0, stream>>>(
            PN1f, wpnf + MW1A_O, wpnf + MW2S_O,
            m_mlp_b2, PCf, PN0f);
        pool_max8<20><<<384, 256, 0, stream>>>(PN0f, GMf, 6);
        gemm_pn<64, true, true, false><<<dim3(96, 1), 256, 0, stream>>>(
            GMf, wpnf + OW1S_O, m_out_b1, nullptr, 1, 0,
            nullptr, HVf, 64, 64, 1, 0, 0);
        gemm_pn<128, false, false, true><<<dim3(96, 2), 256, 0, stream>>>(
            HVf, wpnf + OW2S_O, m_out_b2, nullptr, 1, 0,
            X, nullptr, 64, 256, 768, 64, 64);
    }

    split_x0<<<(int)(M * 256 / 1024), 256, 0, stream>>>(X, PE16, X16, XP16);

    // ---------------- transformer layers (3 dispatches/layer) ----------------
    const float scal = 0.17677669529663687f;  // 32^-0.5
    const int MB = MTOT / 128;  // 104
    for (int l = 0; l < LL; l++) {
        const size_t wb = (size_t)l * 786432;
        const h16* wqkv_f = whf + wb;
        const h16* wo_f   = whf + wb + 196608;
        const h16* f1_f   = whf + wb + 262144;
        const h16* f2_f   = whf + wb + 524288;
        const float* bqkv = attn_bqkv + (size_t)l * 768;
        gemm_mfma<false, true><<<dim3(MB, 6), 256, 0, stream>>>(
            XP16, X16, 512, wqkv_f, bqkv,
            nullptr, QKV16, 256, 768, 0, scal, 256);
        attn_kernel<<<MTOT / 2, 256, 0, stream>>>(QKV16, IDX, AO16);
        if (l == LL - 1) {
            fused_layer<2><<<MTOT / 64, 512, 0, stream>>>(
                AO16, wo_f, attn_bo + (size_t)l * 256, X16,
                ln1_g + l * 256, ln1_b + l * 256,
                f1_f, f2_f, ffn_b1 + (size_t)l * 1024, ffn_b2 + (size_t)l * 256,
                ln2_g + l * 256, ln2_b + l * 256,
                (float*)d_out, nullptr, nullptr, nullptr);
        } else {
            fused_layer<1><<<MTOT / 64, 512, 0, stream>>>(
                AO16, wo_f, attn_bo + (size_t)l * 256, X16,
                ln1_g + l * 256, ln1_b + l * 256,
                f1_f, f2_f, ffn_b1 + (size_t)l * 1024, ffn_b2 + (size_t)l * 256,
                ln2_g + l * 256, ln2_b + l * 256,
                nullptr, X16, PE16, XP16);
        }
    }
}

// Round 24
// 646.660 us; speedup vs baseline: 2.7792x; 1.0163x over previous
//
#include <hip/hip_runtime.h>
#include <hip/hip_bf16.h>

typedef unsigned short u16;
typedef _Float16 h16;

#define BB 16
#define NO 64
#define TT 21
#define NM 768
#define PP 20
#define CAx 29
#define CMx 9
#define DD 256
#define HH 8
#define LL 6
#define KK 16
#define NN (NO + NM)        // 832
#define HDX (DD / HH)       // 32
#define MTOT (BB * NN)      // 13312
#define MAPR (BB * NM * PP) // 245760 map point-rows

typedef __attribute__((ext_vector_type(8))) h16 h8v;
typedef __attribute__((ext_vector_type(4))) h16 h4v;
typedef __attribute__((ext_vector_type(4))) float f4v;

#define GLOAD_LDS16(gptr, lptr)                                                             \
    __builtin_amdgcn_global_load_lds(                                                       \
        (const __attribute__((address_space(1))) void*)(gptr),                              \
        (__attribute__((address_space(3))) void*)(lptr), 16, 0, 0)

// Bank-conflict swizzle for [rows][32]-fp16 linear tiles (gload_lds-compatible):
#define SWZ_LCOL(lane)   ((((lane) & 3) ^ (((lane) >> 3) & 3)) * 8)
#define SWZ_RD(kb, fr)   ((((kb) ^ (((fr) >> 1) & 3))) * 8)
#define SWZ_ELEM(row, kl) (((((kl) >> 3) ^ (((row) >> 1) & 3)) << 3) | ((kl) & 7))

// ---------------------------------------------------------------- merged prep + KNN
// block ranges: [0,3328) knn | map | agent | pe | cvt_pn | cvt_weights
#define PRB_KNN   3328
#define PRB_MAP   (PRB_KNN + 30720)
#define PRB_AG    (PRB_MAP + 2688)
#define PRB_PE    (PRB_AG + MTOT)
#define PRB_PN    (PRB_PE + 1480)
#define PRB_TOT   (PRB_PN + 18432)
#define W1P_O   0
#define W2S_O   2048
#define W3S_O   6144
#define MW1A_O  10240
#define MW1B_O  14336
#define MW2S_O  18432
#define OW1S_O  22528
#define OW2S_O  26624
#define APW_O   43008
#define AW1A_O  51200
#define AW1B_O  116736
#define AW2S_O  182272
#define AOW1_O  247808
#define AOW2_O  313344
#define WPN_TOT 378880
__global__ __launch_bounds__(256) void prep_all(
    const float* __restrict__ mp, const float* __restrict__ obj,
    const float* __restrict__ opos, const float* __restrict__ mpos,
    const float* __restrict__ wqkv, const float* __restrict__ wo,
    const float* __restrict__ f1w, const float* __restrict__ f2w,
    const float* __restrict__ m_pre_w1, const float* __restrict__ m_pre_w2,
    const float* __restrict__ m_pre_w3, const float* __restrict__ m_mlp_w1,
    const float* __restrict__ m_mlp_w2, const float* __restrict__ m_out_w1,
    const float* __restrict__ m_out_w2,
    const float* __restrict__ a_pre_w,  const float* __restrict__ a_mlp_w1,
    const float* __restrict__ a_mlp_w2, const float* __restrict__ a_out_w1,
    const float* __restrict__ a_out_w2,
    h16* __restrict__ pmap, h16* __restrict__ pagent,
    h16* __restrict__ PE16, h16* __restrict__ wpnf, h16* __restrict__ whf,
    int* __restrict__ IDX)
{
    const int bid = blockIdx.x;
    const int tid = threadIdx.x;
    if (bid < PRB_KNN) {
        // ---- KNN (top-16 smallest d2); VALU-bound, overlaps the mem-bound ranges below
        const int b = bid / 208;
        const int blk = bid % 208;
        __shared__ float px[NN], py[NN], pz[NN];
        for (int i = tid; i < NN; i += 256) {
            const float* src = (i < NO) ? &opos[(size_t)(b * NO + i) * 3]
                                        : &mpos[(size_t)(b * NM + (i - NO)) * 3];
            px[i] = src[0]; py[i] = src[1]; pz[i] = src[2];
        }
        __syncthreads();
        const int wave = tid >> 6, lane = tid & 63;
        const int n = blk * 4 + wave;
        const float qx = px[n], qy = py[n], qz = pz[n];
        float d[13];
        #pragma unroll
        for (int s = 0; s < 13; s++) {
            int j = s * 64 + lane;
            float dx = qx - px[j], dy = qy - py[j], dz = qz - pz[j];
            d[s] = dx * dx + dy * dy + dz * dz;
        }
        int keep = 0;
        #pragma unroll
        for (int it = 0; it < 16; it++) {
            float bv = d[0]; int bs = 0;
            #pragma unroll
            for (int s = 1; s < 13; s++) { if (d[s] < bv) { bv = d[s]; bs = s; } }
            float v = bv; int jj = bs * 64 + lane;
            #pragma unroll
            for (int off = 32; off; off >>= 1) {
                float ov = __shfl_xor(v, off);
                int oj = __shfl_xor(jj, off);
                if (ov < v || (ov == v && oj < jj)) { v = ov; jj = oj; }
            }
            if (lane == (jj & 63)) {
                int sl = jj >> 6;
                #pragma unroll
                for (int s = 0; s < 13; s++) if (s == sl) d[s] = 3.4e38f;
            }
            if (lane == it) keep = jj;
        }
        if (lane < 16) IDX[((size_t)(b * NN + n)) * 16 + lane] = keep;
    } else if (bid < PRB_MAP) {
        int e = (bid - PRB_KNN) * 256 + tid;
        int r = e >> 5, c = e & 31;
        float v = (c < CMx) ? mp[(size_t)r * CMx + c] : 0.f;
        pmap[e] = (h16)v;
    } else if (bid < PRB_AG) {
        int e = (bid - PRB_MAP) * 256 + tid;
        int r = e >> 5, c = e & 31;
        float v = (c < CAx) ? obj[(size_t)r * CAx + c] : ((c == CAx) ? 1.0f : 0.f);
        pagent[e] = (h16)v;
    } else if (bid < PRB_PE) {
        int row = bid - PRB_AG;
        int b = row / NN, n = row % NN;
        const float* p = (n < NO) ? &opos[(size_t)(b * NO + n) * 3]
                                  : &mpos[(size_t)(b * NM + (n - NO)) * 3];
        float x = p[0], y = p[1];
        int j = tid & 127;
        float v = (tid < 128) ? y : x;
        float inv_dt = exp2f(-(float)(j & ~1) * 0.10381025296523f);
        float e = v * 6.283185307179586f * inv_dt;
        PE16[(size_t)row * DD + tid] = (h16)((j & 1) ? cosf(e) : sinf(e));
    } else if (bid < PRB_PN) {
        int e = (bid - PRB_PE) * 256 + tid;
        float v;
        if (e < W2S_O)       { int n = e >> 5, k = e & 31; v = (k < 9) ? m_pre_w1[n * 9 + k] : 0.f; }
        else if (e < W3S_O)  v = m_pre_w2[e - W2S_O];
        else if (e < MW1A_O) v = m_pre_w3[e - W3S_O];
        else if (e < MW1B_O) { int r = e - MW1A_O; v = m_mlp_w1[(r >> 6) * 128 + (r & 63)]; }
        else if (e < MW2S_O) { int r = e - MW1B_O; v = m_mlp_w1[(r >> 6) * 128 + 64 + (r & 63)]; }
        else if (e < OW1S_O) v = m_mlp_w2[e - MW2S_O];
        else if (e < OW2S_O) v = m_out_w1[e - OW1S_O];
        else if (e < APW_O)  v = m_out_w2[e - OW2S_O];
        else if (e < AW1A_O) { int r = e - APW_O; int n = r >> 5, k = r & 31; v = (k < 30) ? a_pre_w[n * 30 + k] : 0.f; }
        else if (e < AW1B_O) { int r = e - AW1A_O; v = a_mlp_w1[(r >> 8) * 512 + (r & 255)]; }
        else if (e < AW2S_O) { int r = e - AW1B_O; v = a_mlp_w1[(r >> 8) * 512 + 256 + (r & 255)]; }
        else if (e < AOW1_O) v = a_mlp_w2[e - AW2S_O];
        else if (e < AOW2_O) v = a_out_w1[e - AOW1_O];
        else                 v = a_out_w2[e - AOW2_O];
        wpnf[e] = (h16)v;
    } else {
        size_t e = (size_t)(bid - PRB_PN) * 256 + tid;
        int L = (int)(e / 786432);
        int r = (int)(e % 786432);
        float v;
        if (r < 196608)      v = wqkv[(size_t)L * 196608 + r];
        else if (r < 262144) v = wo[(size_t)L * 65536 + (r - 196608)];
        else if (r < 524288) v = f1w[(size_t)L * 262144 + (r - 262144)];
        else                 v = f2w[(size_t)L * 262144 + (r - 524288)];
        whf[e] = (h16)v;
    }
}

// ---------------------------------------------------------------- max-pool over P points, 8-wide
template<int P>
__global__ __launch_bounds__(256) void pool_max8(
    const h16* __restrict__ in, h16* __restrict__ out, int cshift)
{
    int e8 = blockIdx.x * 256 + threadIdx.x;
    int C = 1 << cshift;
    int base = e8 * 8;
    int g = base >> cshift, c = base & (C - 1);
    float m0 = -3.4e38f, m1 = m0, m2 = m0, m3 = m0, m4 = m0, m5 = m0, m6 = m0, m7 = m0;
    #pragma unroll
    for (int p = 0; p < P; p++) {
        h8v v = *(const h8v*)&in[((size_t)(g * P + p) << cshift) + c];
        m0 = fmaxf(m0, (float)v[0]); m1 = fmaxf(m1, (float)v[1]);
        m2 = fmaxf(m2, (float)v[2]); m3 = fmaxf(m3, (float)v[3]);
        m4 = fmaxf(m4, (float)v[4]); m5 = fmaxf(m5, (float)v[5]);
        m6 = fmaxf(m6, (float)v[6]); m7 = fmaxf(m7, (float)v[7]);
    }
    h8v o;
    o[0] = (h16)m0; o[1] = (h16)m1; o[2] = (h16)m2; o[3] = (h16)m3;
    o[4] = (h16)m4; o[5] = (h16)m5; o[6] = (h16)m6; o[7] = (h16)m7;
    *(h8v*)&out[((size_t)g << cshift) + c] = o;
}

// ---------------------------------------------------------------- pointnet GEMM (fp16 MFMA)
template<int BN, bool RELU, bool F16OUT, bool ROWMAP>
__global__ __launch_bounds__(256) void gemm_pn(
    const h16* __restrict__ A, const h16* __restrict__ W,
    const float* __restrict__ bias,
    const float* __restrict__ addrow, int ardiv, int arld,
    float* __restrict__ Cf, h16* __restrict__ C16,
    int K, int ldc, int rm_div, int rm_mul, int rm_add)
{
    constexpr int WAVES_M = (BN == 64) ? 4 : 2;
    constexpr int WM = 128 / (16 * WAVES_M);
    __shared__ __align__(16) h16 AS[128][32];
    __shared__ __align__(16) h16 WS[BN][32];
    const int m0 = blockIdx.x * 128;
    const int n0 = blockIdx.y * BN;
    const int tid = threadIdx.x;
    const int wave = tid >> 6, lane = tid & 63;
    const int wr = (BN == 64) ? wave : (wave >> 1);
    const int wc = (BN == 64) ? 0 : (wave & 1);
    const int fr = lane & 15, kb = lane >> 4;
    const int lrow = lane >> 2, lcol = SWZ_LCOL(lane);
    const int rdo = SWZ_RD(kb, fr);

    f4v acc[WM][4];
    #pragma unroll
    for (int i = 0; i < WM; i++)
        #pragma unroll
        for (int j = 0; j < 4; j++) { f4v z = {0.f, 0.f, 0.f, 0.f}; acc[i][j] = z; }

    for (int k0 = 0; k0 < K; k0 += 32) {
        __syncthreads();
        #pragma unroll
        for (int i = 0; i < 2; i++) {
            const int r = wave * 32 + i * 16;
            GLOAD_LDS16(&A[(size_t)(m0 + r + lrow) * K + k0 + lcol], &AS[r][0]);
        }
        if constexpr (BN == 64) {
            const int r = wave * 16;
            GLOAD_LDS16(&W[(size_t)(n0 + r + lrow) * K + k0 + lcol], &WS[r][0]);
        } else {
            #pragma unroll
            for (int i = 0; i < 2; i++) {
                const int r = wave * 32 + i * 16;
                GLOAD_LDS16(&W[(size_t)(n0 + r + lrow) * K + k0 + lcol], &WS[r][0]);
            }
        }
        __syncthreads();
        h8v af[WM];
        #pragma unroll
        for (int mi = 0; mi < WM; mi++)
            af[mi] = *(const h8v*)&AS[wr * (WM * 16) + mi * 16 + fr][rdo];
        #pragma unroll
        for (int nj = 0; nj < 4; nj++) {
            h8v bf = *(const h8v*)&WS[wc * 64 + nj * 16 + fr][rdo];
            #pragma unroll
            for (int mi = 0; mi < WM; mi++)
                acc[mi][nj] = __builtin_amdgcn_mfma_f32_16x16x32_f16(af[mi], bf, acc[mi][nj], 0, 0, 0);
        }
    }
    #pragma unroll
    for (int mi = 0; mi < WM; mi++) {
        #pragma unroll
        for (int nj = 0; nj < 4; nj++) {
            int col = n0 + wc * 64 + nj * 16 + fr;
            float bb = bias ? bias[col] : 0.f;
            #pragma unroll
            for (int r = 0; r < 4; r++) {
                int row = m0 + wr * (WM * 16) + mi * 16 + (lane >> 4) * 4 + r;
                float v = acc[mi][nj][r] + bb;
                if (addrow) v += addrow[(size_t)(row / ardiv) * arld + col];
                if (RELU) v = fmaxf(v, 0.f);
                if (F16OUT) {
                    C16[(size_t)row * ldc + col] = (h16)v;
                } else {
                    int drow = row;
                    if (ROWMAP) drow = row + rm_add + (row / rm_div) * rm_mul;
                    Cf[(size_t)drow * ldc + col] = v;
                }
            }
        }
    }
}

// ---------------------------------------------------------------- initial activation cvt
__global__ __launch_bounds__(256) void split_x0(
    const float* __restrict__ X, const h16* __restrict__ PE16,
    h16* __restrict__ X16, h16* __restrict__ XP16)
{
    size_t base = ((size_t)blockIdx.x * 256 + threadIdx.x) * 4;
    float4 x = *(const float4*)&X[base];
    h4v pe = *(const h4v*)&PE16[base];
    h4v a, b;
    a.x = (h16)x.x; a.y = (h16)x.y; a.z = (h16)x.z; a.w = (h16)x.w;
    b.x = (h16)(x.x + (float)pe.x); b.y = (h16)(x.y + (float)pe.y);
    b.z = (h16)(x.z + (float)pe.z); b.w = (h16)(x.w + (float)pe.w);
    *(h4v*)&X16[base] = a;
    *(h4v*)&XP16[base] = b;
}

// ---------------------------------------------------------------- fused map pre1->pre2->pre3
__global__ __launch_bounds__(256) void fused_map3(
    const h16* __restrict__ A,   // [MAPR][32]
    const h16* __restrict__ W1,  // [64][32]
    const h16* __restrict__ W2, const h16* __restrict__ W3,  // [64][64]
    const float* __restrict__ b1, const float* __restrict__ b2, const float* __restrict__ b3,
    h16* __restrict__ Out)       // [MAPR][64]
{
    __shared__ __align__(16) h16 AS[128][32];
    __shared__ __align__(16) h16 G0[2][128][32];
    __shared__ __align__(16) h16 G1[2][128][32];
    __shared__ __align__(16) h16 W1S[64][32];
    __shared__ __align__(16) h16 W2S[2][64][32];
    __shared__ __align__(16) h16 W3S[2][64][32];
    const int m0 = blockIdx.x * 128;
    const int tid = threadIdx.x;
    const int wave = tid >> 6, lane = tid & 63;
    const int fr = lane & 15, kb = lane >> 4;
    const int lrow = lane >> 2, lcol = SWZ_LCOL(lane);
    const int rdo = SWZ_RD(kb, fr);

    #pragma unroll
    for (int q = 0; q < 2; q++)
        GLOAD_LDS16(&A[(size_t)(m0 + wave * 32 + q * 16 + lrow) * 32 + lcol],
                    &AS[wave * 32 + q * 16][0]);
    GLOAD_LDS16(&W1[(size_t)(wave * 16 + lrow) * 32 + lcol], &W1S[wave * 16][0]);
    #pragma unroll
    for (int t = 0; t < 2; t++) {
        GLOAD_LDS16(&W2[(size_t)(wave * 16 + lrow) * 64 + t * 32 + lcol], &W2S[t][wave * 16][0]);
        GLOAD_LDS16(&W3[(size_t)(wave * 16 + lrow) * 64 + t * 32 + lcol], &W3S[t][wave * 16][0]);
    }
    __syncthreads();
    #pragma unroll
    for (int mi = 0; mi < 2; mi++) {
        h8v af = *(const h8v*)&AS[wave * 32 + mi * 16 + fr][rdo];
        #pragma unroll
        for (int nj = 0; nj < 4; nj++) {
            f4v a = {0.f, 0.f, 0.f, 0.f};
            h8v bf = *(const h8v*)&W1S[nj * 16 + fr][rdo];
            a = __builtin_amdgcn_mfma_f32_16x16x32_f16(af, bf, a, 0, 0, 0);
            int col = nj * 16 + fr, ch = col >> 5, kl = col & 31;
            float bb = b1[col];
            #pragma unroll
            for (int r = 0; r < 4; r++) {
                int row = wave * 32 + mi * 16 + kb * 4 + r;
                G0[ch][row][SWZ_ELEM(row, kl)] = (h16)fmaxf(a[r] + bb, 0.f);
            }
        }
    }
    __syncthreads();
    #pragma unroll
    for (int mi = 0; mi < 2; mi++) {
        #pragma unroll
        for (int nj = 0; nj < 4; nj++) {
            f4v a = {0.f, 0.f, 0.f, 0.f};
            #pragma unroll
            for (int t = 0; t < 2; t++) {
                h8v af = *(const h8v*)&G0[t][wave * 32 + mi * 16 + fr][rdo];
                h8v bf = *(const h8v*)&W2S[t][nj * 16 + fr][rdo];
                a = __builtin_amdgcn_mfma_f32_16x16x32_f16(af, bf, a, 0, 0, 0);
            }
            int col = nj * 16 + fr, ch = col >> 5, kl = col & 31;
            float bb = b2[col];
            #pragma unroll
            for (int r = 0; r < 4; r++) {
                int row = wave * 32 + mi * 16 + kb * 4 + r;
                G1[ch][row][SWZ_ELEM(row, kl)] = (h16)fmaxf(a[r] + bb, 0.f);
            }
        }
    }
    __syncthreads();
    #pragma unroll
    for (int mi = 0; mi < 2; mi++) {
        #pragma unroll
        for (int nj = 0; nj < 4; nj++) {
            f4v a = {0.f, 0.f, 0.f, 0.f};
            #pragma unroll
            for (int t = 0; t < 2; t++) {
                h8v af = *(const h8v*)&G1[t][wave * 32 + mi * 16 + fr][rdo];
                h8v bf = *(const h8v*)&W3S[t][nj * 16 + fr][rdo];
                a = __builtin_amdgcn_mfma_f32_16x16x32_f16(af, bf, a, 0, 0, 0);
            }
            int col = nj * 16 + fr;
            float bb = b3[col];
            #pragma unroll
            for (int r = 0; r < 4; r++) {
                int row = m0 + wave * 32 + mi * 16 + kb * 4 + r;
                Out[(size_t)row * 64 + col] = (h16)fmaxf(a[r] + bb, 0.f);
            }
        }
    }
}

// ---------------------------------------------------------------- fused map mid1->mid2
// mid1 bias b1 is carried entirely by `pooled` (PCf = pooled@W1B + b1).
__global__ __launch_bounds__(256) void fused_map2(
    const h16* __restrict__ A,   // [MAPR][64]
    const h16* __restrict__ W1,  // MW1A [64][64]
    const h16* __restrict__ W2,  // MW2S [64][64]
    const float* __restrict__ b2,
    const float* __restrict__ pooled,  // PCf [12288][64] f32 (includes b1)
    h16* __restrict__ Out)       // [MAPR][64]
{
    __shared__ __align__(16) h16 AS[2][128][32];
    __shared__ __align__(16) h16 G0[2][128][32];
    __shared__ __align__(16) h16 W1S[2][64][32];
    __shared__ __align__(16) h16 W2S[2][64][32];
    const int m0 = blockIdx.x * 128;
    const int tid = threadIdx.x;
    const int wave = tid >> 6, lane = tid & 63;
    const int fr = lane & 15, kb = lane >> 4;
    const int lrow = lane >> 2, lcol = SWZ_LCOL(lane);
    const int rdo = SWZ_RD(kb, fr);

    #pragma unroll
    for (int t = 0; t < 2; t++) {
        #pragma unroll
        for (int q = 0; q < 2; q++)
            GLOAD_LDS16(&A[(size_t)(m0 + wave * 32 + q * 16 + lrow) * 64 + t * 32 + lcol],
                        &AS[t][wave * 32 + q * 16][0]);
        GLOAD_LDS16(&W1[(size_t)(wave * 16 + lrow) * 64 + t * 32 + lcol], &W1S[t][wave * 16][0]);
        GLOAD_LDS16(&W2[(size_t)(wave * 16 + lrow) * 64 + t * 32 + lcol], &W2S[t][wave * 16][0]);
    }
    __syncthreads();
    #pragma unroll
    for (int mi = 0; mi < 2; mi++) {
        #pragma unroll
        for (int nj = 0; nj < 4; nj++) {
            f4v a = {0.f, 0.f, 0.f, 0.f};
            #pragma unroll
            for (int t = 0; t < 2; t++) {
                h8v af = *(const h8v*)&AS[t][wave * 32 + mi * 16 + fr][rdo];
                h8v bf = *(const h8v*)&W1S[t][nj * 16 + fr][rdo];
                a = __builtin_amdgcn_mfma_f32_16x16x32_f16(af, bf, a, 0, 0, 0);
            }
            int col = nj * 16 + fr, ch = col >> 5, kl = col & 31;
            #pragma unroll
            for (int r = 0; r < 4; r++) {
                int row = wave * 32 + mi * 16 + kb * 4 + r;
                int grow = m0 + row;
                float v = a[r] + pooled[(size_t)(grow / PP) * 64 + col];
                G0[ch][row][SWZ_ELEM(row, kl)] = (h16)fmaxf(v, 0.f);
            }
        }
    }
    __syncthreads();
    #pragma unroll
    for (int mi = 0; mi < 2; mi++) {
        #pragma unroll
        for (int nj = 0; nj < 4; nj++) {
            f4v a = {0.f, 0.f, 0.f, 0.f};
            #pragma unroll
            for (int t = 0; t < 2; t++) {
                h8v af = *(const h8v*)&G0[t][wave * 32 + mi * 16 + fr][rdo];
                h8v bf = *(const h8v*)&W2S[t][nj * 16 + fr][rdo];
                a = __builtin_amdgcn_mfma_f32_16x16x32_f16(af, bf, a, 0, 0, 0);
            }
            int col = nj * 16 + fr;
            float bb = b2[col];
            #pragma unroll
            for (int r = 0; r < 4; r++) {
                int row = m0 + wave * 32 + mi * 16 + kb * 4 + r;
                Out[(size_t)row * 64 + col] = (h16)fmaxf(a[r] + bb, 0.f);
            }
        }
    }
}

// ---------------------------------------------------------------- transformer fp16 MFMA GEMM
template<bool RELU, bool F16OUT>
__global__ __launch_bounds__(256) void gemm_mfma(
    const h16* __restrict__ A, const h16* __restrict__ A2, int a2min,
    const h16* __restrict__ W, const float* __restrict__ bias,
    float* __restrict__ Cf, h16* __restrict__ C16,
    int K, int ldc, int coff, float scale, int scale_until)
{
    __shared__ __align__(16) h16 AS[128][32];
    __shared__ __align__(16) h16 WS[128][32];
    const int m0 = blockIdx.x * 128;
    const int n0 = blockIdx.y * 128;
    const h16* pA = (n0 >= a2min) ? A2 : A;
    const int tid = threadIdx.x;
    const int wave = tid >> 6, lane = tid & 63;
    const int wr = wave >> 1, wc = wave & 1;
    const int fr = lane & 15, kb = lane >> 4;
    const int lrow = lane >> 2;
    const int lcol = SWZ_LCOL(lane);
    const int rdo = SWZ_RD(kb, fr);

    f4v acc[4][4];
    #pragma unroll
    for (int i = 0; i < 4; i++)
        #pragma unroll
        for (int j = 0; j < 4; j++) { f4v z = {0.f, 0.f, 0.f, 0.f}; acc[i][j] = z; }

    for (int k0 = 0; k0 < K; k0 += 32) {
        __syncthreads();
        #pragma unroll
        for (int i = 0; i < 2; i++) {
            const int r = wave * 32 + i * 16;
            const size_t grow = (size_t)(r + lrow);
            GLOAD_LDS16(&pA[(m0 + grow) * K + k0 + lcol], &AS[r][0]);
            GLOAD_LDS16(&W [(n0 + grow) * K + k0 + lcol], &WS[r][0]);
        }
        __syncthreads();
        h8v af[4];
        #pragma unroll
        for (int mi = 0; mi < 4; mi++)
            af[mi] = *(const h8v*)&AS[wr * 64 + mi * 16 + fr][rdo];
        #pragma unroll
        for (int nj = 0; nj < 4; nj++) {
            h8v bf = *(const h8v*)&WS[wc * 64 + nj * 16 + fr][rdo];
            #pragma unroll
            for (int mi = 0; mi < 4; mi++)
                acc[mi][nj] = __builtin_amdgcn_mfma_f32_16x16x32_f16(af[mi], bf, acc[mi][nj], 0, 0, 0);
        }
    }
    #pragma unroll
    for (int mi = 0; mi < 4; mi++) {
        #pragma unroll
        for (int nj = 0; nj < 4; nj++) {
            int col = n0 + wc * 64 + nj * 16 + fr;
            float bb = bias[col];
            #pragma unroll
            for (int r = 0; r < 4; r++) {
                int row = m0 + wr * 64 + mi * 16 + (lane >> 4) * 4 + r;
                float v = acc[mi][nj][r] + bb;
                if (RELU) v = fmaxf(v, 0.f);
                int gcol = coff + col;
                if (gcol < scale_until) v *= scale;
                if (F16OUT) {
                    C16[(size_t)row * ldc + gcol] = (h16)v;
                } else {
                    Cf[(size_t)row * ldc + gcol] = v;
                }
            }
        }
    }
}

// ---------------------------------------------------------------- fused O-proj+LN1+FFN1+FFN2+LN2
// 64 rows/block, 8 waves (4 wr x 2 wc). Ping-pong double-buffered weight staging:
// the next phase's chunk is issued into the free buffer right after each barrier,
// so the global_load_lds transfer overlaps the current phase's MFMA (drain is short).
// PEMODE 1: write X16 + XP16(=h16(o+PE)).  PEMODE 2: write fp32 d_out.
template<int PEMODE>
__global__ __launch_bounds__(512) void fused_layer(
    const h16* __restrict__ AO16, const h16* __restrict__ Wo,   // [256][256]
    const float* __restrict__ bo, const h16* __restrict__ X16r,
    const float* __restrict__ g1, const float* __restrict__ bt1,
    const h16* __restrict__ W1,   // [1024][256]
    const h16* __restrict__ W2,   // [256][1024]
    const float* __restrict__ b1, const float* __restrict__ b2,
    const float* __restrict__ g2, const float* __restrict__ bt2,
    float* __restrict__ OutF, h16* __restrict__ O16,
    const h16* __restrict__ PE16p, h16* __restrict__ P16)
{
    __shared__ __align__(16) h16 AOS[8][64][32];   // 32 KB: AO tile (k-tiles)
    __shared__ __align__(16) h16 HS[8][64][32];    // 32 KB: post-LN h (col-chunk tiles)
    __shared__ __align__(16) h16 GS[2][64][32];    // 8 KB: relu'd hidden chunk (64)
    __shared__ __align__(16) h16 U0[16384];        // 32 KB ping
    __shared__ __align__(16) h16 U1[16384];        // 32 KB pong
    __shared__ float red_s[2][8][64];              // 4 KB
    const int m0 = blockIdx.x * 64;
    const int tid = threadIdx.x;
    const int wave = tid >> 6, lane = tid & 63;
    const int wr = wave >> 1, wc = wave & 1;
    const int fr = lane & 15, kb = lane >> 4;
    const int lrow = lane >> 2, lcol = SWZ_LCOL(lane);
    const int rdo = SWZ_RD(kb, fr);

    // stage a 64-row x 256-k panel (k-tile t = wave) into dst
    auto stage_p64 = [&](const h16* src, h16* dst) {
        #pragma unroll
        for (int q = 0; q < 4; q++)
            GLOAD_LDS16(&src[(size_t)(q * 16 + lrow) * 256 + wave * 32 + lcol],
                        &dst[wave * 2048 + (q * 16) * 32]);
    };
    // stage W2 chunk c (256 rows x 64 hidden as 2 k-tiles) into dst
    auto stage_w2 = [&](int c, h16* dst) {
        #pragma unroll
        for (int t2 = 0; t2 < 2; t2++)
            #pragma unroll
            for (int q = 0; q < 2; q++)
                GLOAD_LDS16(&W2[(size_t)(wave * 32 + q * 16 + lrow) * 1024 + c * 64 + t2 * 32 + lcol],
                            &dst[t2 * 8192 + (wave * 32 + q * 16) * 32]);
    };

    // prologue: AO tile + first Wo chunk
    #pragma unroll
    for (int q = 0; q < 4; q++)
        GLOAD_LDS16(&AO16[(size_t)(m0 + q * 16 + lrow) * 256 + wave * 32 + lcol],
                    &AOS[wave][q * 16][0]);
    stage_p64(Wo, U0);
    __syncthreads();   // AOS + U0 ready

    h8v aof[8];
    #pragma unroll
    for (int t = 0; t < 8; t++)
        aof[t] = *(const h8v*)&AOS[t][wr * 16 + fr][rdo];

    // ---- stage 0: O-proj (4 col-chunks of 64) + residual(X16r) + LN1 stats
    float xo[4][2][4];
    float rsum1[4] = {0.f, 0.f, 0.f, 0.f}, rsq1[4] = {0.f, 0.f, 0.f, 0.f};
    #pragma unroll
    for (int oc = 0; oc < 4; oc++) {
        const h16* Ucur = (oc & 1) ? U1 : U0;
        h16* Unxt = (oc & 1) ? U0 : U1;
        // prefetch next chunk into the free buffer (readers of Unxt finished at prev barrier)
        if (oc < 3) stage_p64(Wo + (size_t)(oc + 1) * 64 * 256, Unxt);
        else        stage_p64(W1, Unxt);   // oc=3: Unxt=U0 <- W1 chunk 0
        #pragma unroll
        for (int nj = 0; nj < 2; nj++) {
            f4v o1 = {0.f, 0.f, 0.f, 0.f};
            #pragma unroll
            for (int t = 0; t < 8; t++) {
                h8v bf = *(const h8v*)&Ucur[t * 2048 + (wc * 32 + nj * 16 + fr) * 32 + rdo];
                o1 = __builtin_amdgcn_mfma_f32_16x16x32_f16(aof[t], bf, o1, 0, 0, 0);
            }
            int col = oc * 64 + wc * 32 + nj * 16 + fr;
            float bb = bo[col];
            #pragma unroll
            for (int r = 0; r < 4; r++) {
                int row = wr * 16 + kb * 4 + r;
                float v = o1[r] + bb + (float)X16r[(size_t)(m0 + row) * 256 + col];
                xo[oc][nj][r] = v;
                rsum1[r] += v;
                rsq1[r] += v * v;
            }
        }
        __syncthreads();   // all waves done reading Ucur; Unxt drained
    }
    #pragma unroll
    for (int off = 1; off < 16; off <<= 1)
        #pragma unroll
        for (int r = 0; r < 4; r++) {
            rsum1[r] += __shfl_xor(rsum1[r], off);
            rsq1[r]  += __shfl_xor(rsq1[r], off);
        }
    // each wave owns row-group wr; zero-fill the other 3 groups
    if (fr < 4) {
        int grp = (wr + fr) & 3;
        #pragma unroll
        for (int r = 0; r < 4; r++) {
            red_s[0][wave][grp * 16 + kb * 4 + r] = (fr == 0) ? rsum1[r] : 0.f;
            red_s[1][wave][grp * 16 + kb * 4 + r] = (fr == 0) ? rsq1[r] : 0.f;
        }
    }
    __syncthreads();
    float mean1[4], inv1[4];
    #pragma unroll
    for (int r = 0; r < 4; r++) {
        int rid = wr * 16 + kb * 4 + r;
        float s = 0.f, sq = 0.f;
        #pragma unroll
        for (int w = 0; w < 8; w++) { s += red_s[0][w][rid]; sq += red_s[1][w][rid]; }
        mean1[r] = s * (1.f / 256.f);
        float var = sq * (1.f / 256.f) - mean1[r] * mean1[r];
        inv1[r] = rsqrtf(var + 1e-5f);
    }
    // write h = LN1(xo) into HS (col-chunk tile layout)
    #pragma unroll
    for (int oc = 0; oc < 4; oc++)
        #pragma unroll
        for (int nj = 0; nj < 2; nj++) {
            int col = oc * 64 + wc * 32 + nj * 16 + fr;
            int ch = col >> 5, kl = col & 31;
            float gg = g1[col], bb = bt1[col];
            #pragma unroll
            for (int r = 0; r < 4; r++) {
                int row = wr * 16 + kb * 4 + r;
                float h = (xo[oc][nj][r] - mean1[r]) * inv1[r] * gg + bb;
                HS[ch][row][SWZ_ELEM(row, kl)] = (h16)h;
            }
        }
    __syncthreads();   // HS ready

    // hoist h A-fragments (HS is chunk-invariant)
    h8v haf[8];
    #pragma unroll
    for (int t = 0; t < 8; t++)
        haf[t] = *(const h8v*)&HS[t][wr * 16 + fr][rdo];

    // ---- stage 1+2: FFN (hidden chunked by 64); W1[c] lives in U0, W2[c] in U1
    f4v acc2[8];
    #pragma unroll
    for (int j = 0; j < 8; j++) { f4v z = {0.f, 0.f, 0.f, 0.f}; acc2[j] = z; }

    for (int c = 0; c < 16; c++) {
        // W1 phase (U0): prefetch W2[c] -> U1 (U1 readers done at last barrier)
        stage_w2(c, U1);
        #pragma unroll
        for (int nj = 0; nj < 2; nj++) {
            f4v a1 = {0.f, 0.f, 0.f, 0.f};
            #pragma unroll
            for (int t = 0; t < 8; t++) {
                h8v bf = *(const h8v*)&U0[t * 2048 + (wc * 32 + nj * 16 + fr) * 32 + rdo];
                a1 = __builtin_amdgcn_mfma_f32_16x16x32_f16(haf[t], bf, a1, 0, 0, 0);
            }
            int n = wc * 32 + nj * 16 + fr;    // hidden index within chunk (0..63)
            int ch = n >> 5, kl = n & 31;
            float bb = b1[c * 64 + n];
            #pragma unroll
            for (int r = 0; r < 4; r++) {
                int row = wr * 16 + kb * 4 + r;
                GS[ch][row][SWZ_ELEM(row, kl)] = (h16)fmaxf(a1[r] + bb, 0.f);
            }
        }
        __syncthreads();   // GS visible; U0 reads done; U1 drained
        // W2 phase (U1): prefetch W1[c+1] -> U0 (U0 readers done at barrier above)
        if (c < 15) stage_p64(W1 + (size_t)(c + 1) * 64 * 256, U0);
        #pragma unroll
        for (int t2 = 0; t2 < 2; t2++) {
            h8v gaf = *(const h8v*)&GS[t2][wr * 16 + fr][rdo];
            #pragma unroll
            for (int nj = 0; nj < 8; nj++) {
                h8v bf = *(const h8v*)&U1[t2 * 8192 + (wc * 128 + nj * 16 + fr) * 32 + rdo];
                acc2[nj] = __builtin_amdgcn_mfma_f32_16x16x32_f16(gaf, bf, acc2[nj], 0, 0, 0);
            }
        }
        __syncthreads();   // U1 reads done; GS free; U0 drained
    }
    // ---- epilogue: x = h-residual(HS) + acc2 + b2; LN2; write
    float x[8][4];
    float rsum[4] = {0.f, 0.f, 0.f, 0.f}, rsq[4] = {0.f, 0.f, 0.f, 0.f};
    #pragma unroll
    for (int nj = 0; nj < 8; nj++) {
        int col = wc * 128 + nj * 16 + fr;
        int ch = col >> 5, kl = col & 31;
        float bb = b2[col];
        #pragma unroll
        for (int r = 0; r < 4; r++) {
            int row = wr * 16 + kb * 4 + r;
            float res = (float)HS[ch][row][SWZ_ELEM(row, kl)];
            float v = acc2[nj][r] + bb + res;
            x[nj][r] = v;
            rsum[r] += v;
            rsq[r] += v * v;
        }
    }
    #pragma unroll
    for (int off = 1; off < 16; off <<= 1)
        #pragma unroll
        for (int r = 0; r < 4; r++) {
            rsum[r] += __shfl_xor(rsum[r], off);
            rsq[r]  += __shfl_xor(rsq[r], off);
        }
    __syncthreads();   // red_s free from LN1
    if (fr < 4) {
        int grp = (wr + fr) & 3;
        #pragma unroll
        for (int r = 0; r < 4; r++) {
            red_s[0][wave][grp * 16 + kb * 4 + r] = (fr == 0) ? rsum[r] : 0.f;
            red_s[1][wave][grp * 16 + kb * 4 + r] = (fr == 0) ? rsq[r] : 0.f;
        }
    }
    __syncthreads();
    #pragma unroll
    for (int r = 0; r < 4; r++) {
        int rid = wr * 16 + kb * 4 + r;
        float s = 0.f, sq = 0.f;
        #pragma unroll
        for (int w = 0; w < 8; w++) { s += red_s[0][w][rid]; sq += red_s[1][w][rid]; }
        float mean = s * (1.f / 256.f);
        float var = sq * (1.f / 256.f) - mean * mean;
        float inv = rsqrtf(var + 1e-5f);
        #pragma unroll
        for (int nj = 0; nj < 8; nj++) {
            int col = wc * 128 + nj * 16 + fr;
            float o = (x[nj][r] - mean) * inv * g2[col] + bt2[col];
            size_t idx = (size_t)(m0 + rid) * 256 + col;
            if (PEMODE == 2) {
                OutF[idx] = o;
            } else {
                O16[idx] = (h16)o;
                P16[idx] = (h16)(o + (float)PE16p[idx]);
            }
        }
    }
}

// ---------------------------------------------------------------- local KNN attention (fp16 QKV)
__global__ __launch_bounds__(256) void attn_kernel(
    const h16* __restrict__ QKV16, const int* __restrict__ IDX,
    h16* __restrict__ AO16)
{
    __shared__ __align__(16) h16 Ks[32][256];
    __shared__ float p_s[2][HH][16];
    __shared__ int gid_s[2][16];
    const int sub = threadIdx.x >> 7;
    const int t = threadIdx.x & 127;
    const int wave = threadIdx.x >> 6, lane = threadIdx.x & 63;
    const int xcd = blockIdx.x & 7;
    const int j = blockIdx.x >> 3;            // 0..831
    const int b = (j / 416) * 8 + xcd;        // batch
    const int row = b * NN + (j % 416) * 2 + sub;
    const int h = t >> 4, k = t & 15;
    int nb = IDX[(size_t)row * 16 + k];
    int g = b * NN + nb;
    if (h == 0) gid_s[sub][k] = g;
    __syncthreads();
    #pragma unroll
    for (int i = 0; i < 4; i++) {
        int s0 = wave * 8 + i * 2;
        int s = s0 + (lane >> 5);
        int gs = gid_s[s >> 4][s & 15];
        int clog = (lane & 31) ^ (s & 7);
        GLOAD_LDS16(&QKV16[(size_t)gs * 768 + 256 + clog * 8], &Ks[s0][0]);
    }
    __syncthreads();
    const h16* q = &QKV16[(size_t)row * 768 + h * HDX];
    const int sidx = sub * 16 + k;
    float s = 0.f;
    #pragma unroll
    for (int c = 0; c < 4; c++) {
        h8v q8 = *(const h8v*)&q[c * 8];
        h8v k8 = *(const h8v*)&Ks[sidx][(((h * 4 + c) ^ (sidx & 7)) * 8)];
        #pragma unroll
        for (int e = 0; e < 8; e++) s += (float)q8[e] * (float)k8[e];
    }
    float m = s;
    #pragma unroll
    for (int off = 8; off; off >>= 1) m = fmaxf(m, __shfl_xor(m, off, 16));
    float e = expf(s - m);
    float sum = e;
    #pragma unroll
    for (int off = 8; off; off >>= 1) sum += __shfl_xor(sum, off, 16);
    p_s[sub][h][k] = e / sum;
    __syncthreads();
    const int d0 = t * 2;
    const int hh = d0 >> 5, dd = d0 & 31;
    float o0 = 0.f, o1 = 0.f;
    #pragma unroll
    for (int kk = 0; kk < 16; kk++) {
        int gg = gid_s[sub][kk];
        const h16* vr = &QKV16[(size_t)gg * 768 + 512 + hh * HDX + dd];
        float p = p_s[sub][hh][kk];
        o0 += p * (float)vr[0];
        o1 += p * (float)vr[1];
    }
    size_t base = (size_t)row * DD + d0;
    AO16[base] = (h16)o0;
    AO16[base + 1] = (h16)o1;
}

// ----------------------------------------------------------------
extern "C" void kernel_launch(void* const* d_in, const int* in_sizes, int n_in,
                              void* d_out, int out_size, void* d_ws, size_t ws_size,
                              hipStream_t stream)
{
    const float* obj      = (const float*)d_in[0];
    const float* mp       = (const float*)d_in[1];
    const float* opos     = (const float*)d_in[2];
    const float* mpos     = (const float*)d_in[3];
    const float* a_pre_w  = (const float*)d_in[4];
    const float* a_pre_b  = (const float*)d_in[5];
    const float* a_mlp_w1 = (const float*)d_in[6];
    const float* a_mlp_b1 = (const float*)d_in[7];
    const float* a_mlp_w2 = (const float*)d_in[8];
    const float* a_mlp_b2 = (const float*)d_in[9];
    const float* a_out_w1 = (const float*)d_in[10];
    const float* a_out_b1 = (const float*)d_in[11];
    const float* a_out_w2 = (const float*)d_in[12];
    const float* a_out_b2 = (const float*)d_in[13];
    const float* m_pre_w1 = (const float*)d_in[14];
    const float* m_pre_b1 = (const float*)d_in[15];
    const float* m_pre_w2 = (const float*)d_in[16];
    const float* m_pre_b2 = (const float*)d_in[17];
    const float* m_pre_w3 = (const float*)d_in[18];
    const float* m_pre_b3 = (const float*)d_in[19];
    const float* m_mlp_w1 = (const float*)d_in[20];
    const float* m_mlp_b1 = (const float*)d_in[21];
    const float* m_mlp_w2 = (const float*)d_in[22];
    const float* m_mlp_b2 = (const float*)d_in[23];
    const float* m_out_w1 = (const float*)d_in[24];
    const float* m_out_b1 = (const float*)d_in[25];
    const float* m_out_w2 = (const float*)d_in[26];
    const float* m_out_b2 = (const float*)d_in[27];
    const float* attn_wqkv = (const float*)d_in[28];
    const float* attn_bqkv = (const float*)d_in[29];
    const float* attn_wo   = (const float*)d_in[30];
    const float* attn_bo   = (const float*)d_in[31];
    const float* ffn_w1    = (const float*)d_in[32];
    const float* ffn_b1    = (const float*)d_in[33];
    const float* ffn_w2    = (const float*)d_in[34];
    const float* ffn_b2    = (const float*)d_in[35];
    const float* ln1_g     = (const float*)d_in[36];
    const float* ln1_b     = (const float*)d_in[37];
    const float* ln2_g     = (const float*)d_in[38];
    const float* ln2_b     = (const float*)d_in[39];

    const size_t M = MTOT;  // 13312
    float* ws   = (float*)d_ws;
    float* X    = ws;                 // M*256 f32 (pointnet out staging)
    float* PEr  = X   + M * 256;      // PE16 region
    float* QKVr = PEr + M * 256;      // aliased region
    float* Hpad = QKVr + M * 768;     // padding region
    h16* AO16   = (h16*)(Hpad + M * 256);
    h16* X16    = AO16 + M * 256;
    h16* XP16   = X16  + M * 256;
    h16* H16    = XP16 + M * 256;     // unused now (layout stability)
    h16* whf    = H16  + M * 256;     // 4,718,592 fp16
    h16* wpnf   = whf  + 4718592;
    int* IDX    = (int*)(wpnf + WPN_TOT);

    h16* PE16 = (h16*)PEr;
    h16* QKV16 = (h16*)QKVr;          // M*768 fp16 (live QKV-gemm..attn)

    // pointnet-phase aliases (QKVr..AO16 dead window during pre-phase;
    // X16/XP16 written ONLY by split_x0 after all pointnet buffers are dead)
    h16* PN0f = (h16*)QKVr;
    h16* PN1f = PN0f + 15728640;
    h16* SB   = PN0f + 31457280;
    h16* PLf  = SB;
    h16* GMf  = SB + 786432;
    h16* HVf  = SB + 1572864;
    h16* APLf = SB + 2359296;
    h16* AGMf = SB + 2621440;
    h16* AHVf = SB + 2883584;
    float* PCf = (float*)(SB + 3145728);
    float* APC = PCf + 786432;

    // ---------------- pre-phase (knn merged into prep_all for overlap) ----------------
    prep_all<<<PRB_TOT, 256, 0, stream>>>(
        mp, obj, opos, mpos,
        attn_wqkv, attn_wo, ffn_w1, ffn_w2,
        m_pre_w1, m_pre_w2, m_pre_w3, m_mlp_w1, m_mlp_w2, m_out_w1, m_out_w2,
        a_pre_w, a_mlp_w1, a_mlp_w2, a_out_w1, a_out_w2,
        PN0f /*pmap*/, PN1f /*pagent*/, PE16, wpnf, whf, IDX);

    // ---- agent pointnet as GEMM chain (pagent staged in PN1f)
    {
        h16* PA32 = PN1f;
        h16* PB   = PN0f + 7864320;
        h16* PA2  = PN1f;
        gemm_pn<128, true, true, false><<<dim3(168, 2), 256, 0, stream>>>(
            PA32, wpnf + APW_O, a_pre_b, nullptr, 1, 0,
            nullptr, PB, 32, 256, 1, 0, 0);
        pool_max8<21><<<128, 256, 0, stream>>>(PB, APLf, 8);
        gemm_pn<128, false, false, false><<<dim3(8, 2), 256, 0, stream>>>(
            APLf, wpnf + AW1B_O, a_mlp_b1, nullptr, 1, 0,
            APC, nullptr, 256, 256, 1, 0, 0);
        gemm_pn<128, true, true, false><<<dim3(168, 2), 256, 0, stream>>>(
            PB, wpnf + AW1A_O, nullptr, APC, 21, 256,
            nullptr, PA2, 256, 256, 1, 0, 0);
        gemm_pn<128, true, true, false><<<dim3(168, 2), 256, 0, stream>>>(
            PA2, wpnf + AW2S_O, a_mlp_b2, nullptr, 1, 0,
            nullptr, PB, 256, 256, 1, 0, 0);
        pool_max8<21><<<128, 256, 0, stream>>>(PB, AGMf, 8);
        gemm_pn<128, true, true, false><<<dim3(8, 2), 256, 0, stream>>>(
            AGMf, wpnf + AOW1_O, a_out_b1, nullptr, 1, 0,
            nullptr, AHVf, 256, 256, 1, 0, 0);
        gemm_pn<128, false, false, true><<<dim3(8, 2), 256, 0, stream>>>(
            AHVf, wpnf + AOW2_O, a_out_b2, nullptr, 1, 0,
            X, nullptr, 256, 256, 64, 768, 0);
    }

    // ---- map pointnet: fused chains (pmap in PN0f)
    {
        fused_map3<<<MAPR / 128, 256, 0, stream>>>(
            PN0f, wpnf + W1P_O, wpnf + W2S_O, wpnf + W3S_O,
            m_pre_b1, m_pre_b2, m_pre_b3, PN1f);
        pool_max8<20><<<384, 256, 0, stream>>>(PN1f, PLf, 6);
        gemm_pn<64, false, false, false><<<dim3(96, 1), 256, 0, stream>>>(
            PLf, wpnf + MW1B_O, m_mlp_b1, nullptr, 1, 0,
            PCf, nullptr, 64, 64, 1, 0, 0);
        fused_map2<<<MAPR / 128, 256, 0, stream>>>(
            PN1f, wpnf + MW1A_O, wpnf + MW2S_O,
            m_mlp_b2, PCf, PN0f);
        pool_max8<20><<<384, 256, 0, stream>>>(PN0f, GMf, 6);
        gemm_pn<64, true, true, false><<<dim3(96, 1), 256, 0, stream>>>(
            GMf, wpnf + OW1S_O, m_out_b1, nullptr, 1, 0,
            nullptr, HVf, 64, 64, 1, 0, 0);
        gemm_pn<128, false, false, true><<<dim3(96, 2), 256, 0, stream>>>(
            HVf, wpnf + OW2S_O, m_out_b2, nullptr, 1, 0,
            X, nullptr, 64, 256, 768, 64, 64);
    }

    split_x0<<<(int)(M * 256 / 1024), 256, 0, stream>>>(X, PE16, X16, XP16);

    // ---------------- transformer layers (3 dispatches/layer) ----------------
    const float scal = 0.17677669529663687f;  // 32^-0.5
    const int MB = MTOT / 128;  // 104
    for (int l = 0; l < LL; l++) {
        const size_t wb = (size_t)l * 786432;
        const h16* wqkv_f = whf + wb;
        const h16* wo_f   = whf + wb + 196608;
        const h16* f1_f   = whf + wb + 262144;
        const h16* f2_f   = whf + wb + 524288;
        const float* bqkv = attn_bqkv + (size_t)l * 768;
        gemm_mfma<false, true><<<dim3(MB, 6), 256, 0, stream>>>(
            XP16, X16, 512, wqkv_f, bqkv,
            nullptr, QKV16, 256, 768, 0, scal, 256);
        attn_kernel<<<MTOT / 2, 256, 0, stream>>>(QKV16, IDX, AO16);
        if (l == LL - 1) {
            fused_layer<2><<<MTOT / 64, 512, 0, stream>>>(
                AO16, wo_f, attn_bo + (size_t)l * 256, X16,
                ln1_g + l * 256, ln1_b + l * 256,
                f1_f, f2_f, ffn_b1 + (size_t)l * 1024, ffn_b2 + (size_t)l * 256,
                ln2_g + l * 256, ln2_b + l * 256,
                (float*)d_out, nullptr, nullptr, nullptr);
        } else {
            fused_layer<1><<<MTOT / 64, 512, 0, stream>>>(
                AO16, wo_f, attn_bo + (size_t)l * 256, X16,
                ln1_g + l * 256, ln1_b + l * 256,
                f1_f, f2_f, ffn_b1 + (size_t)l * 1024, ffn_b2 + (size_t)l * 256,
                ln2_g + l * 256, ln2_b + l * 256,
                nullptr, X16, PE16, XP16);
        }
    }
}

// Round 25
// 634.554 us; speedup vs baseline: 2.8323x; 1.0191x over previous
//
#include <hip/hip_runtime.h>
#include <hip/hip_bf16.h>

typedef unsigned short u16;
typedef _Float16 h16;

#define BB 16
#define NO 64
#define TT 21
#define NM 768
#define PP 20
#define CAx 29
#define CMx 9
#define DD 256
#define HH 8
#define LL 6
#define KK 16
#define NN (NO + NM)        // 832
#define HDX (DD / HH)       // 32
#define MTOT (BB * NN)      // 13312
#define MAPR (BB * NM * PP) // 245760 map point-rows

typedef __attribute__((ext_vector_type(8))) h16 h8v;
typedef __attribute__((ext_vector_type(4))) h16 h4v;
typedef __attribute__((ext_vector_type(4))) float f4v;

#define GLOAD_LDS16(gptr, lptr)                                                             \
    __builtin_amdgcn_global_load_lds(                                                       \
        (const __attribute__((address_space(1))) void*)(gptr),                              \
        (__attribute__((address_space(3))) void*)(lptr), 16, 0, 0)

// Bank-conflict swizzle for [rows][32]-fp16 linear tiles (gload_lds-compatible):
#define SWZ_LCOL(lane)   ((((lane) & 3) ^ (((lane) >> 3) & 3)) * 8)
#define SWZ_RD(kb, fr)   ((((kb) ^ (((fr) >> 1) & 3))) * 8)
#define SWZ_ELEM(row, kl) (((((kl) >> 3) ^ (((row) >> 1) & 3)) << 3) | ((kl) & 7))

// ---------------------------------------------------------------- merged prep + KNN (8-wide cvt)
// block ranges: knn | map | agent | pe | cvt_pn | cvt_weights
#define PRB_KNN   3328
#define PRB_MAP   (PRB_KNN + 3840)
#define PRB_AG    (PRB_MAP + 336)
#define PRB_PE    (PRB_AG + 1664)
#define PRB_PN    (PRB_PE + 185)
#define PRB_TOT   (PRB_PN + 2304)
#define W1P_O   0
#define W2S_O   2048
#define W3S_O   6144
#define MW1A_O  10240
#define MW1B_O  14336
#define MW2S_O  18432
#define OW1S_O  22528
#define OW2S_O  26624
#define APW_O   43008
#define AW1A_O  51200
#define AW1B_O  116736
#define AW2S_O  182272
#define AOW1_O  247808
#define AOW2_O  313344
#define WPN_TOT 378880
__global__ __launch_bounds__(256) void prep_all(
    const float* __restrict__ mp, const float* __restrict__ obj,
    const float* __restrict__ opos, const float* __restrict__ mpos,
    const float* __restrict__ wqkv, const float* __restrict__ wo,
    const float* __restrict__ f1w, const float* __restrict__ f2w,
    const float* __restrict__ m_pre_w1, const float* __restrict__ m_pre_w2,
    const float* __restrict__ m_pre_w3, const float* __restrict__ m_mlp_w1,
    const float* __restrict__ m_mlp_w2, const float* __restrict__ m_out_w1,
    const float* __restrict__ m_out_w2,
    const float* __restrict__ a_pre_w,  const float* __restrict__ a_mlp_w1,
    const float* __restrict__ a_mlp_w2, const float* __restrict__ a_out_w1,
    const float* __restrict__ a_out_w2,
    h16* __restrict__ pmap, h16* __restrict__ pagent,
    h16* __restrict__ PE16, h16* __restrict__ wpnf, h16* __restrict__ whf,
    int* __restrict__ IDX)
{
    const int bid = blockIdx.x;
    const int tid = threadIdx.x;
    if (bid < PRB_KNN) {
        // ---- KNN (top-16 smallest d2); VALU-bound, overlaps the mem-bound ranges below
        const int b = bid / 208;
        const int blk = bid % 208;
        __shared__ float px[NN], py[NN], pz[NN];
        for (int i = tid; i < NN; i += 256) {
            const float* src = (i < NO) ? &opos[(size_t)(b * NO + i) * 3]
                                        : &mpos[(size_t)(b * NM + (i - NO)) * 3];
            px[i] = src[0]; py[i] = src[1]; pz[i] = src[2];
        }
        __syncthreads();
        const int wave = tid >> 6, lane = tid & 63;
        const int n = blk * 4 + wave;
        const float qx = px[n], qy = py[n], qz = pz[n];
        float d[13];
        #pragma unroll
        for (int s = 0; s < 13; s++) {
            int j = s * 64 + lane;
            float dx = qx - px[j], dy = qy - py[j], dz = qz - pz[j];
            d[s] = dx * dx + dy * dy + dz * dz;
        }
        int keep = 0;
        #pragma unroll
        for (int it = 0; it < 16; it++) {
            float bv = d[0]; int bs = 0;
            #pragma unroll
            for (int s = 1; s < 13; s++) { if (d[s] < bv) { bv = d[s]; bs = s; } }
            float v = bv; int jj = bs * 64 + lane;
            #pragma unroll
            for (int off = 32; off; off >>= 1) {
                float ov = __shfl_xor(v, off);
                int oj = __shfl_xor(jj, off);
                if (ov < v || (ov == v && oj < jj)) { v = ov; jj = oj; }
            }
            if (lane == (jj & 63)) {
                int sl = jj >> 6;
                #pragma unroll
                for (int s = 0; s < 13; s++) if (s == sl) d[s] = 3.4e38f;
            }
            if (lane == it) keep = jj;
        }
        if (lane < 16) IDX[((size_t)(b * NN + n)) * 16 + lane] = keep;
    } else if (bid < PRB_MAP) {
        int idx = (bid - PRB_KNN) * 256 + tid;       // 8-elem group
        int r = idx >> 2, c0 = (idx & 3) * 8;
        h8v o;
        #pragma unroll
        for (int j = 0; j < 8; j++) {
            int c = c0 + j;
            o[j] = (h16)((c < CMx) ? mp[(size_t)r * CMx + c] : 0.f);
        }
        *(h8v*)&pmap[(size_t)r * 32 + c0] = o;
    } else if (bid < PRB_AG) {
        int idx = (bid - PRB_MAP) * 256 + tid;
        int r = idx >> 2, c0 = (idx & 3) * 8;
        h8v o;
        #pragma unroll
        for (int j = 0; j < 8; j++) {
            int c = c0 + j;
            float v = (c < CAx) ? obj[(size_t)r * CAx + c] : ((c == CAx) ? 1.0f : 0.f);
            o[j] = (h16)v;
        }
        *(h8v*)&pagent[(size_t)r * 32 + c0] = o;
    } else if (bid < PRB_PE) {
        int idx = (bid - PRB_AG) * 256 + tid;        // 32 groups per row
        int row = idx >> 5;
        int c0 = (idx & 31) * 8;
        int b = row / NN, n = row % NN;
        const float* p = (n < NO) ? &opos[(size_t)(b * NO + n) * 3]
                                  : &mpos[(size_t)(b * NM + (n - NO)) * 3];
        float x = p[0], y = p[1];
        float v = (c0 < 128) ? y : x;                // 8-group never crosses the 128 split
        h8v o;
        #pragma unroll
        for (int j = 0; j < 8; j++) {
            int jj = (c0 + j) & 127;
            float inv_dt = exp2f(-(float)(jj & ~1) * 0.10381025296523f);
            float e = v * 6.283185307179586f * inv_dt;
            o[j] = (h16)((jj & 1) ? cosf(e) : sinf(e));
        }
        *(h8v*)&PE16[(size_t)row * DD + c0] = o;
    } else if (bid < PRB_PN) {
        int e0 = ((bid - PRB_PE) * 256 + tid) * 8;   // all sub-range offsets %8==0
        h8v o;
        #pragma unroll
        for (int j = 0; j < 8; j++) {
            int e = e0 + j;
            float v;
            if (e < W2S_O)       { int n = e >> 5, k = e & 31; v = (k < 9) ? m_pre_w1[n * 9 + k] : 0.f; }
            else if (e < W3S_O)  v = m_pre_w2[e - W2S_O];
            else if (e < MW1A_O) v = m_pre_w3[e - W3S_O];
            else if (e < MW1B_O) { int r = e - MW1A_O; v = m_mlp_w1[(r >> 6) * 128 + (r & 63)]; }
            else if (e < MW2S_O) { int r = e - MW1B_O; v = m_mlp_w1[(r >> 6) * 128 + 64 + (r & 63)]; }
            else if (e < OW1S_O) v = m_mlp_w2[e - MW2S_O];
            else if (e < OW2S_O) v = m_out_w1[e - OW1S_O];
            else if (e < APW_O)  v = m_out_w2[e - OW2S_O];
            else if (e < AW1A_O) { int r = e - APW_O; int n = r >> 5, k = r & 31; v = (k < 30) ? a_pre_w[n * 30 + k] : 0.f; }
            else if (e < AW1B_O) { int r = e - AW1A_O; v = a_mlp_w1[(r >> 8) * 512 + (r & 255)]; }
            else if (e < AW2S_O) { int r = e - AW1B_O; v = a_mlp_w1[(r >> 8) * 512 + 256 + (r & 255)]; }
            else if (e < AOW1_O) v = a_mlp_w2[e - AW2S_O];
            else if (e < AOW2_O) v = a_out_w1[e - AOW1_O];
            else                 v = a_out_w2[e - AOW2_O];
            o[j] = (h16)v;
        }
        *(h8v*)&wpnf[e0] = o;
    } else {
        size_t e0 = ((size_t)(bid - PRB_PN) * 256 + tid) * 8;
        int L = (int)(e0 / 786432);
        int r0 = (int)(e0 % 786432);
        h8v o;
        #pragma unroll
        for (int j = 0; j < 8; j++) {
            int r = r0 + j;
            float v;
            if (r < 196608)      v = wqkv[(size_t)L * 196608 + r];
            else if (r < 262144) v = wo[(size_t)L * 65536 + (r - 196608)];
            else if (r < 524288) v = f1w[(size_t)L * 262144 + (r - 262144)];
            else                 v = f2w[(size_t)L * 262144 + (r - 524288)];
            o[j] = (h16)v;
        }
        *(h8v*)&whf[e0] = o;
    }
}

// ---------------------------------------------------------------- max-pool over P points, 8-wide
template<int P>
__global__ __launch_bounds__(256) void pool_max8(
    const h16* __restrict__ in, h16* __restrict__ out, int cshift)
{
    int e8 = blockIdx.x * 256 + threadIdx.x;
    int C = 1 << cshift;
    int base = e8 * 8;
    int g = base >> cshift, c = base & (C - 1);
    float m0 = -3.4e38f, m1 = m0, m2 = m0, m3 = m0, m4 = m0, m5 = m0, m6 = m0, m7 = m0;
    #pragma unroll
    for (int p = 0; p < P; p++) {
        h8v v = *(const h8v*)&in[((size_t)(g * P + p) << cshift) + c];
        m0 = fmaxf(m0, (float)v[0]); m1 = fmaxf(m1, (float)v[1]);
        m2 = fmaxf(m2, (float)v[2]); m3 = fmaxf(m3, (float)v[3]);
        m4 = fmaxf(m4, (float)v[4]); m5 = fmaxf(m5, (float)v[5]);
        m6 = fmaxf(m6, (float)v[6]); m7 = fmaxf(m7, (float)v[7]);
    }
    h8v o;
    o[0] = (h16)m0; o[1] = (h16)m1; o[2] = (h16)m2; o[3] = (h16)m3;
    o[4] = (h16)m4; o[5] = (h16)m5; o[6] = (h16)m6; o[7] = (h16)m7;
    *(h8v*)&out[((size_t)g << cshift) + c] = o;
}

// ---------------------------------------------------------------- pointnet GEMM (fp16 MFMA)
// ping-pong double-buffered staging: one barrier per K-step, transfer overlaps MFMA.
template<int BN, bool RELU, bool F16OUT, bool ROWMAP>
__global__ __launch_bounds__(256) void gemm_pn(
    const h16* __restrict__ A, const h16* __restrict__ W,
    const float* __restrict__ bias,
    const float* __restrict__ addrow, int ardiv, int arld,
    float* __restrict__ Cf, h16* __restrict__ C16,
    int K, int ldc, int rm_div, int rm_mul, int rm_add)
{
    constexpr int WAVES_M = (BN == 64) ? 4 : 2;
    constexpr int WM = 128 / (16 * WAVES_M);
    __shared__ __align__(16) h16 AS[2][128][32];
    __shared__ __align__(16) h16 WS[2][BN][32];
    const int m0 = blockIdx.x * 128;
    const int n0 = blockIdx.y * BN;
    const int tid = threadIdx.x;
    const int wave = tid >> 6, lane = tid & 63;
    const int wr = (BN == 64) ? wave : (wave >> 1);
    const int wc = (BN == 64) ? 0 : (wave & 1);
    const int fr = lane & 15, kb = lane >> 4;
    const int lrow = lane >> 2, lcol = SWZ_LCOL(lane);
    const int rdo = SWZ_RD(kb, fr);

    auto stage = [&](int buf, int k0) {
        #pragma unroll
        for (int i = 0; i < 2; i++) {
            const int r = wave * 32 + i * 16;
            GLOAD_LDS16(&A[(size_t)(m0 + r + lrow) * K + k0 + lcol], &AS[buf][r][0]);
        }
        if constexpr (BN == 64) {
            const int r = wave * 16;
            GLOAD_LDS16(&W[(size_t)(n0 + r + lrow) * K + k0 + lcol], &WS[buf][r][0]);
        } else {
            #pragma unroll
            for (int i = 0; i < 2; i++) {
                const int r = wave * 32 + i * 16;
                GLOAD_LDS16(&W[(size_t)(n0 + r + lrow) * K + k0 + lcol], &WS[buf][r][0]);
            }
        }
    };

    f4v acc[WM][4];
    #pragma unroll
    for (int i = 0; i < WM; i++)
        #pragma unroll
        for (int j = 0; j < 4; j++) { f4v z = {0.f, 0.f, 0.f, 0.f}; acc[i][j] = z; }

    stage(0, 0);
    __syncthreads();
    const int nk = K >> 5;
    for (int i = 0; i < nk; i++) {
        const int cur = i & 1;
        if (i + 1 < nk) stage(cur ^ 1, (i + 1) << 5);
        h8v af[WM];
        #pragma unroll
        for (int mi = 0; mi < WM; mi++)
            af[mi] = *(const h8v*)&AS[cur][wr * (WM * 16) + mi * 16 + fr][rdo];
        #pragma unroll
        for (int nj = 0; nj < 4; nj++) {
            h8v bf = *(const h8v*)&WS[cur][wc * 64 + nj * 16 + fr][rdo];
            #pragma unroll
            for (int mi = 0; mi < WM; mi++)
                acc[mi][nj] = __builtin_amdgcn_mfma_f32_16x16x32_f16(af[mi], bf, acc[mi][nj], 0, 0, 0);
        }
        __syncthreads();   // cur reads done (safe to re-stage next iter); prefetch drained
    }
    #pragma unroll
    for (int mi = 0; mi < WM; mi++) {
        #pragma unroll
        for (int nj = 0; nj < 4; nj++) {
            int col = n0 + wc * 64 + nj * 16 + fr;
            float bb = bias ? bias[col] : 0.f;
            #pragma unroll
            for (int r = 0; r < 4; r++) {
                int row = m0 + wr * (WM * 16) + mi * 16 + (lane >> 4) * 4 + r;
                float v = acc[mi][nj][r] + bb;
                if (addrow) v += addrow[(size_t)(row / ardiv) * arld + col];
                if (RELU) v = fmaxf(v, 0.f);
                if (F16OUT) {
                    C16[(size_t)row * ldc + col] = (h16)v;
                } else {
                    int drow = row;
                    if (ROWMAP) drow = row + rm_add + (row / rm_div) * rm_mul;
                    Cf[(size_t)drow * ldc + col] = v;
                }
            }
        }
    }
}

// ---------------------------------------------------------------- initial activation cvt
__global__ __launch_bounds__(256) void split_x0(
    const float* __restrict__ X, const h16* __restrict__ PE16,
    h16* __restrict__ X16, h16* __restrict__ XP16)
{
    size_t base = ((size_t)blockIdx.x * 256 + threadIdx.x) * 4;
    float4 x = *(const float4*)&X[base];
    h4v pe = *(const h4v*)&PE16[base];
    h4v a, b;
    a.x = (h16)x.x; a.y = (h16)x.y; a.z = (h16)x.z; a.w = (h16)x.w;
    b.x = (h16)(x.x + (float)pe.x); b.y = (h16)(x.y + (float)pe.y);
    b.z = (h16)(x.z + (float)pe.z); b.w = (h16)(x.w + (float)pe.w);
    *(h4v*)&X16[base] = a;
    *(h4v*)&XP16[base] = b;
}

// ---------------------------------------------------------------- fused map pre1->pre2->pre3
__global__ __launch_bounds__(256) void fused_map3(
    const h16* __restrict__ A,   // [MAPR][32]
    const h16* __restrict__ W1,  // [64][32]
    const h16* __restrict__ W2, const h16* __restrict__ W3,  // [64][64]
    const float* __restrict__ b1, const float* __restrict__ b2, const float* __restrict__ b3,
    h16* __restrict__ Out)       // [MAPR][64]
{
    __shared__ __align__(16) h16 AS[128][32];
    __shared__ __align__(16) h16 G0[2][128][32];
    __shared__ __align__(16) h16 G1[2][128][32];
    __shared__ __align__(16) h16 W1S[64][32];
    __shared__ __align__(16) h16 W2S[2][64][32];
    __shared__ __align__(16) h16 W3S[2][64][32];
    const int m0 = blockIdx.x * 128;
    const int tid = threadIdx.x;
    const int wave = tid >> 6, lane = tid & 63;
    const int fr = lane & 15, kb = lane >> 4;
    const int lrow = lane >> 2, lcol = SWZ_LCOL(lane);
    const int rdo = SWZ_RD(kb, fr);

    #pragma unroll
    for (int q = 0; q < 2; q++)
        GLOAD_LDS16(&A[(size_t)(m0 + wave * 32 + q * 16 + lrow) * 32 + lcol],
                    &AS[wave * 32 + q * 16][0]);
    GLOAD_LDS16(&W1[(size_t)(wave * 16 + lrow) * 32 + lcol], &W1S[wave * 16][0]);
    #pragma unroll
    for (int t = 0; t < 2; t++) {
        GLOAD_LDS16(&W2[(size_t)(wave * 16 + lrow) * 64 + t * 32 + lcol], &W2S[t][wave * 16][0]);
        GLOAD_LDS16(&W3[(size_t)(wave * 16 + lrow) * 64 + t * 32 + lcol], &W3S[t][wave * 16][0]);
    }
    __syncthreads();
    #pragma unroll
    for (int mi = 0; mi < 2; mi++) {
        h8v af = *(const h8v*)&AS[wave * 32 + mi * 16 + fr][rdo];
        #pragma unroll
        for (int nj = 0; nj < 4; nj++) {
            f4v a = {0.f, 0.f, 0.f, 0.f};
            h8v bf = *(const h8v*)&W1S[nj * 16 + fr][rdo];
            a = __builtin_amdgcn_mfma_f32_16x16x32_f16(af, bf, a, 0, 0, 0);
            int col = nj * 16 + fr, ch = col >> 5, kl = col & 31;
            float bb = b1[col];
            #pragma unroll
            for (int r = 0; r < 4; r++) {
                int row = wave * 32 + mi * 16 + kb * 4 + r;
                G0[ch][row][SWZ_ELEM(row, kl)] = (h16)fmaxf(a[r] + bb, 0.f);
            }
        }
    }
    __syncthreads();
    #pragma unroll
    for (int mi = 0; mi < 2; mi++) {
        #pragma unroll
        for (int nj = 0; nj < 4; nj++) {
            f4v a = {0.f, 0.f, 0.f, 0.f};
            #pragma unroll
            for (int t = 0; t < 2; t++) {
                h8v af = *(const h8v*)&G0[t][wave * 32 + mi * 16 + fr][rdo];
                h8v bf = *(const h8v*)&W2S[t][nj * 16 + fr][rdo];
                a = __builtin_amdgcn_mfma_f32_16x16x32_f16(af, bf, a, 0, 0, 0);
            }
            int col = nj * 16 + fr, ch = col >> 5, kl = col & 31;
            float bb = b2[col];
            #pragma unroll
            for (int r = 0; r < 4; r++) {
                int row = wave * 32 + mi * 16 + kb * 4 + r;
                G1[ch][row][SWZ_ELEM(row, kl)] = (h16)fmaxf(a[r] + bb, 0.f);
            }
        }
    }
    __syncthreads();
    #pragma unroll
    for (int mi = 0; mi < 2; mi++) {
        #pragma unroll
        for (int nj = 0; nj < 4; nj++) {
            f4v a = {0.f, 0.f, 0.f, 0.f};
            #pragma unroll
            for (int t = 0; t < 2; t++) {
                h8v af = *(const h8v*)&G1[t][wave * 32 + mi * 16 + fr][rdo];
                h8v bf = *(const h8v*)&W3S[t][nj * 16 + fr][rdo];
                a = __builtin_amdgcn_mfma_f32_16x16x32_f16(af, bf, a, 0, 0, 0);
            }
            int col = nj * 16 + fr;
            float bb = b3[col];
            #pragma unroll
            for (int r = 0; r < 4; r++) {
                int row = m0 + wave * 32 + mi * 16 + kb * 4 + r;
                Out[(size_t)row * 64 + col] = (h16)fmaxf(a[r] + bb, 0.f);
            }
        }
    }
}

// ---------------------------------------------------------------- fused map mid1->mid2
// mid1 bias b1 is carried entirely by `pooled` (PCf = pooled@W1B + b1).
__global__ __launch_bounds__(256) void fused_map2(
    const h16* __restrict__ A,   // [MAPR][64]
    const h16* __restrict__ W1,  // MW1A [64][64]
    const h16* __restrict__ W2,  // MW2S [64][64]
    const float* __restrict__ b2,
    const float* __restrict__ pooled,  // PCf [12288][64] f32 (includes b1)
    h16* __restrict__ Out)       // [MAPR][64]
{
    __shared__ __align__(16) h16 AS[2][128][32];
    __shared__ __align__(16) h16 G0[2][128][32];
    __shared__ __align__(16) h16 W1S[2][64][32];
    __shared__ __align__(16) h16 W2S[2][64][32];
    const int m0 = blockIdx.x * 128;
    const int tid = threadIdx.x;
    const int wave = tid >> 6, lane = tid & 63;
    const int fr = lane & 15, kb = lane >> 4;
    const int lrow = lane >> 2, lcol = SWZ_LCOL(lane);
    const int rdo = SWZ_RD(kb, fr);

    #pragma unroll
    for (int t = 0; t < 2; t++) {
        #pragma unroll
        for (int q = 0; q < 2; q++)
            GLOAD_LDS16(&A[(size_t)(m0 + wave * 32 + q * 16 + lrow) * 64 + t * 32 + lcol],
                        &AS[t][wave * 32 + q * 16][0]);
        GLOAD_LDS16(&W1[(size_t)(wave * 16 + lrow) * 64 + t * 32 + lcol], &W1S[t][wave * 16][0]);
        GLOAD_LDS16(&W2[(size_t)(wave * 16 + lrow) * 64 + t * 32 + lcol], &W2S[t][wave * 16][0]);
    }
    __syncthreads();
    #pragma unroll
    for (int mi = 0; mi < 2; mi++) {
        #pragma unroll
        for (int nj = 0; nj < 4; nj++) {
            f4v a = {0.f, 0.f, 0.f, 0.f};
            #pragma unroll
            for (int t = 0; t < 2; t++) {
                h8v af = *(const h8v*)&AS[t][wave * 32 + mi * 16 + fr][rdo];
                h8v bf = *(const h8v*)&W1S[t][nj * 16 + fr][rdo];
                a = __builtin_amdgcn_mfma_f32_16x16x32_f16(af, bf, a, 0, 0, 0);
            }
            int col = nj * 16 + fr, ch = col >> 5, kl = col & 31;
            #pragma unroll
            for (int r = 0; r < 4; r++) {
                int row = wave * 32 + mi * 16 + kb * 4 + r;
                int grow = m0 + row;
                float v = a[r] + pooled[(size_t)(grow / PP) * 64 + col];
                G0[ch][row][SWZ_ELEM(row, kl)] = (h16)fmaxf(v, 0.f);
            }
        }
    }
    __syncthreads();
    #pragma unroll
    for (int mi = 0; mi < 2; mi++) {
        #pragma unroll
        for (int nj = 0; nj < 4; nj++) {
            f4v a = {0.f, 0.f, 0.f, 0.f};
            #pragma unroll
            for (int t = 0; t < 2; t++) {
                h8v af = *(const h8v*)&G0[t][wave * 32 + mi * 16 + fr][rdo];
                h8v bf = *(const h8v*)&W2S[t][nj * 16 + fr][rdo];
                a = __builtin_amdgcn_mfma_f32_16x16x32_f16(af, bf, a, 0, 0, 0);
            }
            int col = nj * 16 + fr;
            float bb = b2[col];
            #pragma unroll
            for (int r = 0; r < 4; r++) {
                int row = m0 + wave * 32 + mi * 16 + kb * 4 + r;
                Out[(size_t)row * 64 + col] = (h16)fmaxf(a[r] + bb, 0.f);
            }
        }
    }
}

// ---------------------------------------------------------------- transformer fp16 MFMA GEMM
// ping-pong double-buffered: one barrier per K-step.
template<bool RELU, bool F16OUT>
__global__ __launch_bounds__(256) void gemm_mfma(
    const h16* __restrict__ A, const h16* __restrict__ A2, int a2min,
    const h16* __restrict__ W, const float* __restrict__ bias,
    float* __restrict__ Cf, h16* __restrict__ C16,
    int K, int ldc, int coff, float scale, int scale_until)
{
    __shared__ __align__(16) h16 AS[2][128][32];
    __shared__ __align__(16) h16 WS[2][128][32];
    const int m0 = blockIdx.x * 128;
    const int n0 = blockIdx.y * 128;
    const h16* pA = (n0 >= a2min) ? A2 : A;
    const int tid = threadIdx.x;
    const int wave = tid >> 6, lane = tid & 63;
    const int wr = wave >> 1, wc = wave & 1;
    const int fr = lane & 15, kb = lane >> 4;
    const int lrow = lane >> 2;
    const int lcol = SWZ_LCOL(lane);
    const int rdo = SWZ_RD(kb, fr);

    auto stage = [&](int buf, int k0) {
        #pragma unroll
        for (int i = 0; i < 2; i++) {
            const int r = wave * 32 + i * 16;
            const size_t grow = (size_t)(r + lrow);
            GLOAD_LDS16(&pA[(m0 + grow) * K + k0 + lcol], &AS[buf][r][0]);
            GLOAD_LDS16(&W [(n0 + grow) * K + k0 + lcol], &WS[buf][r][0]);
        }
    };

    f4v acc[4][4];
    #pragma unroll
    for (int i = 0; i < 4; i++)
        #pragma unroll
        for (int j = 0; j < 4; j++) { f4v z = {0.f, 0.f, 0.f, 0.f}; acc[i][j] = z; }

    stage(0, 0);
    __syncthreads();
    const int nk = K >> 5;
    for (int i = 0; i < nk; i++) {
        const int cur = i & 1;
        if (i + 1 < nk) stage(cur ^ 1, (i + 1) << 5);
        h8v af[4];
        #pragma unroll
        for (int mi = 0; mi < 4; mi++)
            af[mi] = *(const h8v*)&AS[cur][wr * 64 + mi * 16 + fr][rdo];
        #pragma unroll
        for (int nj = 0; nj < 4; nj++) {
            h8v bf = *(const h8v*)&WS[cur][wc * 64 + nj * 16 + fr][rdo];
            #pragma unroll
            for (int mi = 0; mi < 4; mi++)
                acc[mi][nj] = __builtin_amdgcn_mfma_f32_16x16x32_f16(af[mi], bf, acc[mi][nj], 0, 0, 0);
        }
        __syncthreads();
    }
    #pragma unroll
    for (int mi = 0; mi < 4; mi++) {
        #pragma unroll
        for (int nj = 0; nj < 4; nj++) {
            int col = n0 + wc * 64 + nj * 16 + fr;
            float bb = bias[col];
            #pragma unroll
            for (int r = 0; r < 4; r++) {
                int row = m0 + wr * 64 + mi * 16 + (lane >> 4) * 4 + r;
                float v = acc[mi][nj][r] + bb;
                if (RELU) v = fmaxf(v, 0.f);
                int gcol = coff + col;
                if (gcol < scale_until) v *= scale;
                if (F16OUT) {
                    C16[(size_t)row * ldc + gcol] = (h16)v;
                } else {
                    Cf[(size_t)row * ldc + gcol] = v;
                }
            }
        }
    }
}

// ---------------------------------------------------------------- fused O-proj+LN1+FFN1+FFN2+LN2
// 64 rows/block, 8 waves (4 wr x 2 wc). Ping-pong double-buffered weight staging.
// PEMODE 1: write X16 + XP16(=h16(o+PE)).  PEMODE 2: write fp32 d_out.
template<int PEMODE>
__global__ __launch_bounds__(512) void fused_layer(
    const h16* __restrict__ AO16, const h16* __restrict__ Wo,   // [256][256]
    const float* __restrict__ bo, const h16* __restrict__ X16r,
    const float* __restrict__ g1, const float* __restrict__ bt1,
    const h16* __restrict__ W1,   // [1024][256]
    const h16* __restrict__ W2,   // [256][1024]
    const float* __restrict__ b1, const float* __restrict__ b2,
    const float* __restrict__ g2, const float* __restrict__ bt2,
    float* __restrict__ OutF, h16* __restrict__ O16,
    const h16* __restrict__ PE16p, h16* __restrict__ P16)
{
    __shared__ __align__(16) h16 AOS[8][64][32];   // 32 KB: AO tile (k-tiles)
    __shared__ __align__(16) h16 HS[8][64][32];    // 32 KB: post-LN h (col-chunk tiles)
    __shared__ __align__(16) h16 GS[2][64][32];    // 8 KB: relu'd hidden chunk (64)
    __shared__ __align__(16) h16 U0[16384];        // 32 KB ping
    __shared__ __align__(16) h16 U1[16384];        // 32 KB pong
    __shared__ float red_s[2][8][64];              // 4 KB
    const int m0 = blockIdx.x * 64;
    const int tid = threadIdx.x;
    const int wave = tid >> 6, lane = tid & 63;
    const int wr = wave >> 1, wc = wave & 1;
    const int fr = lane & 15, kb = lane >> 4;
    const int lrow = lane >> 2, lcol = SWZ_LCOL(lane);
    const int rdo = SWZ_RD(kb, fr);

    // stage a 64-row x 256-k panel (k-tile t = wave) into dst
    auto stage_p64 = [&](const h16* src, h16* dst) {
        #pragma unroll
        for (int q = 0; q < 4; q++)
            GLOAD_LDS16(&src[(size_t)(q * 16 + lrow) * 256 + wave * 32 + lcol],
                        &dst[wave * 2048 + (q * 16) * 32]);
    };
    // stage W2 chunk c (256 rows x 64 hidden as 2 k-tiles) into dst
    auto stage_w2 = [&](int c, h16* dst) {
        #pragma unroll
        for (int t2 = 0; t2 < 2; t2++)
            #pragma unroll
            for (int q = 0; q < 2; q++)
                GLOAD_LDS16(&W2[(size_t)(wave * 32 + q * 16 + lrow) * 1024 + c * 64 + t2 * 32 + lcol],
                            &dst[t2 * 8192 + (wave * 32 + q * 16) * 32]);
    };

    // prologue: AO tile + first Wo chunk
    #pragma unroll
    for (int q = 0; q < 4; q++)
        GLOAD_LDS16(&AO16[(size_t)(m0 + q * 16 + lrow) * 256 + wave * 32 + lcol],
                    &AOS[wave][q * 16][0]);
    stage_p64(Wo, U0);
    __syncthreads();   // AOS + U0 ready

    h8v aof[8];
    #pragma unroll
    for (int t = 0; t < 8; t++)
        aof[t] = *(const h8v*)&AOS[t][wr * 16 + fr][rdo];

    // ---- stage 0: O-proj (4 col-chunks of 64) + residual(X16r) + LN1 stats
    float xo[4][2][4];
    float rsum1[4] = {0.f, 0.f, 0.f, 0.f}, rsq1[4] = {0.f, 0.f, 0.f, 0.f};
    #pragma unroll
    for (int oc = 0; oc < 4; oc++) {
        const h16* Ucur = (oc & 1) ? U1 : U0;
        h16* Unxt = (oc & 1) ? U0 : U1;
        // prefetch next chunk into the free buffer (readers of Unxt finished at prev barrier)
        if (oc < 3) stage_p64(Wo + (size_t)(oc + 1) * 64 * 256, Unxt);
        else        stage_p64(W1, Unxt);   // oc=3: Unxt=U0 <- W1 chunk 0
        #pragma unroll
        for (int nj = 0; nj < 2; nj++) {
            f4v o1 = {0.f, 0.f, 0.f, 0.f};
            #pragma unroll
            for (int t = 0; t < 8; t++) {
                h8v bf = *(const h8v*)&Ucur[t * 2048 + (wc * 32 + nj * 16 + fr) * 32 + rdo];
                o1 = __builtin_amdgcn_mfma_f32_16x16x32_f16(aof[t], bf, o1, 0, 0, 0);
            }
            int col = oc * 64 + wc * 32 + nj * 16 + fr;
            float bb = bo[col];
            #pragma unroll
            for (int r = 0; r < 4; r++) {
                int row = wr * 16 + kb * 4 + r;
                float v = o1[r] + bb + (float)X16r[(size_t)(m0 + row) * 256 + col];
                xo[oc][nj][r] = v;
                rsum1[r] += v;
                rsq1[r] += v * v;
            }
        }
        __syncthreads();   // all waves done reading Ucur; Unxt drained
    }
    #pragma unroll
    for (int off = 1; off < 16; off <<= 1)
        #pragma unroll
        for (int r = 0; r < 4; r++) {
            rsum1[r] += __shfl_xor(rsum1[r], off);
            rsq1[r]  += __shfl_xor(rsq1[r], off);
        }
    // each wave owns row-group wr; zero-fill the other 3 groups
    if (fr < 4) {
        int grp = (wr + fr) & 3;
        #pragma unroll
        for (int r = 0; r < 4; r++) {
            red_s[0][wave][grp * 16 + kb * 4 + r] = (fr == 0) ? rsum1[r] : 0.f;
            red_s[1][wave][grp * 16 + kb * 4 + r] = (fr == 0) ? rsq1[r] : 0.f;
        }
    }
    __syncthreads();
    float mean1[4], inv1[4];
    #pragma unroll
    for (int r = 0; r < 4; r++) {
        int rid = wr * 16 + kb * 4 + r;
        float s = 0.f, sq = 0.f;
        #pragma unroll
        for (int w = 0; w < 8; w++) { s += red_s[0][w][rid]; sq += red_s[1][w][rid]; }
        mean1[r] = s * (1.f / 256.f);
        float var = sq * (1.f / 256.f) - mean1[r] * mean1[r];
        inv1[r] = rsqrtf(var + 1e-5f);
    }
    // write h = LN1(xo) into HS (col-chunk tile layout)
    #pragma unroll
    for (int oc = 0; oc < 4; oc++)
        #pragma unroll
        for (int nj = 0; nj < 2; nj++) {
            int col = oc * 64 + wc * 32 + nj * 16 + fr;
            int ch = col >> 5, kl = col & 31;
            float gg = g1[col], bb = bt1[col];
            #pragma unroll
            for (int r = 0; r < 4; r++) {
                int row = wr * 16 + kb * 4 + r;
                float h = (xo[oc][nj][r] - mean1[r]) * inv1[r] * gg + bb;
                HS[ch][row][SWZ_ELEM(row, kl)] = (h16)h;
            }
        }
    __syncthreads();   // HS ready

    // hoist h A-fragments (HS is chunk-invariant)
    h8v haf[8];
    #pragma unroll
    for (int t = 0; t < 8; t++)
        haf[t] = *(const h8v*)&HS[t][wr * 16 + fr][rdo];

    // ---- stage 1+2: FFN (hidden chunked by 64); W1[c] lives in U0, W2[c] in U1
    f4v acc2[8];
    #pragma unroll
    for (int j = 0; j < 8; j++) { f4v z = {0.f, 0.f, 0.f, 0.f}; acc2[j] = z; }

    for (int c = 0; c < 16; c++) {
        // W1 phase (U0): prefetch W2[c] -> U1 (U1 readers done at last barrier)
        stage_w2(c, U1);
        #pragma unroll
        for (int nj = 0; nj < 2; nj++) {
            f4v a1 = {0.f, 0.f, 0.f, 0.f};
            #pragma unroll
            for (int t = 0; t < 8; t++) {
                h8v bf = *(const h8v*)&U0[t * 2048 + (wc * 32 + nj * 16 + fr) * 32 + rdo];
                a1 = __builtin_amdgcn_mfma_f32_16x16x32_f16(haf[t], bf, a1, 0, 0, 0);
            }
            int n = wc * 32 + nj * 16 + fr;    // hidden index within chunk (0..63)
            int ch = n >> 5, kl = n & 31;
            float bb = b1[c * 64 + n];
            #pragma unroll
            for (int r = 0; r < 4; r++) {
                int row = wr * 16 + kb * 4 + r;
                GS[ch][row][SWZ_ELEM(row, kl)] = (h16)fmaxf(a1[r] + bb, 0.f);
            }
        }
        __syncthreads();   // GS visible; U0 reads done; U1 drained
        // W2 phase (U1): prefetch W1[c+1] -> U0 (U0 readers done at barrier above)
        if (c < 15) stage_p64(W1 + (size_t)(c + 1) * 64 * 256, U0);
        #pragma unroll
        for (int t2 = 0; t2 < 2; t2++) {
            h8v gaf = *(const h8v*)&GS[t2][wr * 16 + fr][rdo];
            #pragma unroll
            for (int nj = 0; nj < 8; nj++) {
                h8v bf = *(const h8v*)&U1[t2 * 8192 + (wc * 128 + nj * 16 + fr) * 32 + rdo];
                acc2[nj] = __builtin_amdgcn_mfma_f32_16x16x32_f16(gaf, bf, acc2[nj], 0, 0, 0);
            }
        }
        __syncthreads();   // U1 reads done; GS free; U0 drained
    }
    // ---- epilogue: x = h-residual(HS) + acc2 + b2; LN2; write
    float x[8][4];
    float rsum[4] = {0.f, 0.f, 0.f, 0.f}, rsq[4] = {0.f, 0.f, 0.f, 0.f};
    #pragma unroll
    for (int nj = 0; nj < 8; nj++) {
        int col = wc * 128 + nj * 16 + fr;
        int ch = col >> 5, kl = col & 31;
        float bb = b2[col];
        #pragma unroll
        for (int r = 0; r < 4; r++) {
            int row = wr * 16 + kb * 4 + r;
            float res = (float)HS[ch][row][SWZ_ELEM(row, kl)];
            float v = acc2[nj][r] + bb + res;
            x[nj][r] = v;
            rsum[r] += v;
            rsq[r] += v * v;
        }
    }
    #pragma unroll
    for (int off = 1; off < 16; off <<= 1)
        #pragma unroll
        for (int r = 0; r < 4; r++) {
            rsum[r] += __shfl_xor(rsum[r], off);
            rsq[r]  += __shfl_xor(rsq[r], off);
        }
    __syncthreads();   // red_s free from LN1
    if (fr < 4) {
        int grp = (wr + fr) & 3;
        #pragma unroll
        for (int r = 0; r < 4; r++) {
            red_s[0][wave][grp * 16 + kb * 4 + r] = (fr == 0) ? rsum[r] : 0.f;
            red_s[1][wave][grp * 16 + kb * 4 + r] = (fr == 0) ? rsq[r] : 0.f;
        }
    }
    __syncthreads();
    #pragma unroll
    for (int r = 0; r < 4; r++) {
        int rid = wr * 16 + kb * 4 + r;
        float s = 0.f, sq = 0.f;
        #pragma unroll
        for (int w = 0; w < 8; w++) { s += red_s[0][w][rid]; sq += red_s[1][w][rid]; }
        float mean = s * (1.f / 256.f);
        float var = sq * (1.f / 256.f) - mean * mean;
        float inv = rsqrtf(var + 1e-5f);
        #pragma unroll
        for (int nj = 0; nj < 8; nj++) {
            int col = wc * 128 + nj * 16 + fr;
            float o = (x[nj][r] - mean) * inv * g2[col] + bt2[col];
            size_t idx = (size_t)(m0 + rid) * 256 + col;
            if (PEMODE == 2) {
                OutF[idx] = o;
            } else {
                O16[idx] = (h16)o;
                P16[idx] = (h16)(o + (float)PE16p[idx]);
            }
        }
    }
}

// ---------------------------------------------------------------- local KNN attention (fp16 QKV)
__global__ __launch_bounds__(256) void attn_kernel(
    const h16* __restrict__ QKV16, const int* __restrict__ IDX,
    h16* __restrict__ AO16)
{
    __shared__ __align__(16) h16 Ks[32][256];
    __shared__ float p_s[2][HH][16];
    __shared__ int gid_s[2][16];
    const int sub = threadIdx.x >> 7;
    const int t = threadIdx.x & 127;
    const int wave = threadIdx.x >> 6, lane = threadIdx.x & 63;
    const int xcd = blockIdx.x & 7;
    const int j = blockIdx.x >> 3;            // 0..831
    const int b = (j / 416) * 8 + xcd;        // batch
    const int row = b * NN + (j % 416) * 2 + sub;
    const int h = t >> 4, k = t & 15;
    int nb = IDX[(size_t)row * 16 + k];
    int g = b * NN + nb;
    if (h == 0) gid_s[sub][k] = g;
    __syncthreads();
    #pragma unroll
    for (int i = 0; i < 4; i++) {
        int s0 = wave * 8 + i * 2;
        int s = s0 + (lane >> 5);
        int gs = gid_s[s >> 4][s & 15];
        int clog = (lane & 31) ^ (s & 7);
        GLOAD_LDS16(&QKV16[(size_t)gs * 768 + 256 + clog * 8], &Ks[s0][0]);
    }
    __syncthreads();
    const h16* q = &QKV16[(size_t)row * 768 + h * HDX];
    const int sidx = sub * 16 + k;
    float s = 0.f;
    #pragma unroll
    for (int c = 0; c < 4; c++) {
        h8v q8 = *(const h8v*)&q[c * 8];
        h8v k8 = *(const h8v*)&Ks[sidx][(((h * 4 + c) ^ (sidx & 7)) * 8)];
        #pragma unroll
        for (int e = 0; e < 8; e++) s += (float)q8[e] * (float)k8[e];
    }
    float m = s;
    #pragma unroll
    for (int off = 8; off; off >>= 1) m = fmaxf(m, __shfl_xor(m, off, 16));
    float e = expf(s - m);
    float sum = e;
    #pragma unroll
    for (int off = 8; off; off >>= 1) sum += __shfl_xor(sum, off, 16);
    p_s[sub][h][k] = e / sum;
    __syncthreads();
    const int d0 = t * 2;
    const int hh = d0 >> 5, dd = d0 & 31;
    float o0 = 0.f, o1 = 0.f;
    #pragma unroll
    for (int kk = 0; kk < 16; kk++) {
        int gg = gid_s[sub][kk];
        const h16* vr = &QKV16[(size_t)gg * 768 + 512 + hh * HDX + dd];
        float p = p_s[sub][hh][kk];
        o0 += p * (float)vr[0];
        o1 += p * (float)vr[1];
    }
    size_t base = (size_t)row * DD + d0;
    AO16[base] = (h16)o0;
    AO16[base + 1] = (h16)o1;
}

// ----------------------------------------------------------------
extern "C" void kernel_launch(void* const* d_in, const int* in_sizes, int n_in,
                              void* d_out, int out_size, void* d_ws, size_t ws_size,
                              hipStream_t stream)
{
    const float* obj      = (const float*)d_in[0];
    const float* mp       = (const float*)d_in[1];
    const float* opos     = (const float*)d_in[2];
    const float* mpos     = (const float*)d_in[3];
    const float* a_pre_w  = (const float*)d_in[4];
    const float* a_pre_b  = (const float*)d_in[5];
    const float* a_mlp_w1 = (const float*)d_in[6];
    const float* a_mlp_b1 = (const float*)d_in[7];
    const float* a_mlp_w2 = (const float*)d_in[8];
    const float* a_mlp_b2 = (const float*)d_in[9];
    const float* a_out_w1 = (const float*)d_in[10];
    const float* a_out_b1 = (const float*)d_in[11];
    const float* a_out_w2 = (const float*)d_in[12];
    const float* a_out_b2 = (const float*)d_in[13];
    const float* m_pre_w1 = (const float*)d_in[14];
    const float* m_pre_b1 = (const float*)d_in[15];
    const float* m_pre_w2 = (const float*)d_in[16];
    const float* m_pre_b2 = (const float*)d_in[17];
    const float* m_pre_w3 = (const float*)d_in[18];
    const float* m_pre_b3 = (const float*)d_in[19];
    const float* m_mlp_w1 = (const float*)d_in[20];
    const float* m_mlp_b1 = (const float*)d_in[21];
    const float* m_mlp_w2 = (const float*)d_in[22];
    const float* m_mlp_b2 = (const float*)d_in[23];
    const float* m_out_w1 = (const float*)d_in[24];
    const float* m_out_b1 = (const float*)d_in[25];
    const float* m_out_w2 = (const float*)d_in[26];
    const float* m_out_b2 = (const float*)d_in[27];
    const float* attn_wqkv = (const float*)d_in[28];
    const float* attn_bqkv = (const float*)d_in[29];
    const float* attn_wo   = (const float*)d_in[30];
    const float* attn_bo   = (const float*)d_in[31];
    const float* ffn_w1    = (const float*)d_in[32];
    const float* ffn_b1    = (const float*)d_in[33];
    const float* ffn_w2    = (const float*)d_in[34];
    const float* ffn_b2    = (const float*)d_in[35];
    const float* ln1_g     = (const float*)d_in[36];
    const float* ln1_b     = (const float*)d_in[37];
    const float* ln2_g     = (const float*)d_in[38];
    const float* ln2_b     = (const float*)d_in[39];

    const size_t M = MTOT;  // 13312
    float* ws   = (float*)d_ws;
    float* X    = ws;                 // M*256 f32 (pointnet out staging)
    float* PEr  = X   + M * 256;      // PE16 region
    float* QKVr = PEr + M * 256;      // aliased region
    float* Hpad = QKVr + M * 768;     // padding region
    h16* AO16   = (h16*)(Hpad + M * 256);
    h16* X16    = AO16 + M * 256;
    h16* XP16   = X16  + M * 256;
    h16* H16    = XP16 + M * 256;     // unused now (layout stability)
    h16* whf    = H16  + M * 256;     // 4,718,592 fp16
    h16* wpnf   = whf  + 4718592;
    int* IDX    = (int*)(wpnf + WPN_TOT);

    h16* PE16 = (h16*)PEr;
    h16* QKV16 = (h16*)QKVr;          // M*768 fp16 (live QKV-gemm..attn)

    // pointnet-phase aliases (QKVr..AO16 dead window during pre-phase;
    // X16/XP16 written ONLY by split_x0 after all pointnet buffers are dead)
    h16* PN0f = (h16*)QKVr;
    h16* PN1f = PN0f + 15728640;
    h16* SB   = PN0f + 31457280;
    h16* PLf  = SB;
    h16* GMf  = SB + 786432;
    h16* HVf  = SB + 1572864;
    h16* APLf = SB + 2359296;
    h16* AGMf = SB + 2621440;
    h16* AHVf = SB + 2883584;
    float* PCf = (float*)(SB + 3145728);
    float* APC = PCf + 786432;

    // ---------------- pre-phase (knn merged into prep_all; cvt 8-wide) ----------------
    prep_all<<<PRB_TOT, 256, 0, stream>>>(
        mp, obj, opos, mpos,
        attn_wqkv, attn_wo, ffn_w1, ffn_w2,
        m_pre_w1, m_pre_w2, m_pre_w3, m_mlp_w1, m_mlp_w2, m_out_w1, m_out_w2,
        a_pre_w, a_mlp_w1, a_mlp_w2, a_out_w1, a_out_w2,
        PN0f /*pmap*/, PN1f /*pagent*/, PE16, wpnf, whf, IDX);

    // ---- agent pointnet as GEMM chain (pagent staged in PN1f)
    {
        h16* PA32 = PN1f;
        h16* PB   = PN0f + 7864320;
        h16* PA2  = PN1f;
        gemm_pn<128, true, true, false><<<dim3(168, 2), 256, 0, stream>>>(
            PA32, wpnf + APW_O, a_pre_b, nullptr, 1, 0,
            nullptr, PB, 32, 256, 1, 0, 0);
        pool_max8<21><<<128, 256, 0, stream>>>(PB, APLf, 8);
        gemm_pn<128, false, false, false><<<dim3(8, 2), 256, 0, stream>>>(
            APLf, wpnf + AW1B_O, a_mlp_b1, nullptr, 1, 0,
            APC, nullptr, 256, 256, 1, 0, 0);
        gemm_pn<128, true, true, false><<<dim3(168, 2), 256, 0, stream>>>(
            PB, wpnf + AW1A_O, nullptr, APC, 21, 256,
            nullptr, PA2, 256, 256, 1, 0, 0);
        gemm_pn<128, true, true, false><<<dim3(168, 2), 256, 0, stream>>>(
            PA2, wpnf + AW2S_O, a_mlp_b2, nullptr, 1, 0,
            nullptr, PB, 256, 256, 1, 0, 0);
        pool_max8<21><<<128, 256, 0, stream>>>(PB, AGMf, 8);
        gemm_pn<128, true, true, false><<<dim3(8, 2), 256, 0, stream>>>(
            AGMf, wpnf + AOW1_O, a_out_b1, nullptr, 1, 0,
            nullptr, AHVf, 256, 256, 1, 0, 0);
        gemm_pn<128, false, false, true><<<dim3(8, 2), 256, 0, stream>>>(
            AHVf, wpnf + AOW2_O, a_out_b2, nullptr, 1, 0,
            X, nullptr, 256, 256, 64, 768, 0);
    }

    // ---- map pointnet: fused chains (pmap in PN0f)
    {
        fused_map3<<<MAPR / 128, 256, 0, stream>>>(
            PN0f, wpnf + W1P_O, wpnf + W2S_O, wpnf + W3S_O,
            m_pre_b1, m_pre_b2, m_pre_b3, PN1f);
        pool_max8<20><<<384, 256, 0, stream>>>(PN1f, PLf, 6);
        gemm_pn<64, false, false, false><<<dim3(96, 1), 256, 0, stream>>>(
            PLf, wpnf + MW1B_O, m_mlp_b1, nullptr, 1, 0,
            PCf, nullptr, 64, 64, 1, 0, 0);
        fused_map2<<<MAPR / 128, 256, 0, stream>>>(
            PN1f, wpnf + MW1A_O, wpnf + MW2S_O,
            m_mlp_b2, PCf, PN0f);
        pool_max8<20><<<384, 256, 0, stream>>>(PN0f, GMf, 6);
        gemm_pn<64, true, true, false><<<dim3(96, 1), 256, 0, stream>>>(
            GMf, wpnf + OW1S_O, m_out_b1, nullptr, 1, 0,
            nullptr, HVf, 64, 64, 1, 0, 0);
        gemm_pn<128, false, false, true><<<dim3(96, 2), 256, 0, stream>>>(
            HVf, wpnf + OW2S_O, m_out_b2, nullptr, 1, 0,
            X, nullptr, 64, 256, 768, 64, 64);
    }

    split_x0<<<(int)(M * 256 / 1024), 256, 0, stream>>>(X, PE16, X16, XP16);

    // ---------------- transformer layers (3 dispatches/layer) ----------------
    const float scal = 0.17677669529663687f;  // 32^-0.5
    const int MB = MTOT / 128;  // 104
    for (int l = 0; l < LL; l++) {
        const size_t wb = (size_t)l * 786432;
        const h16* wqkv_f = whf + wb;
        const h16* wo_f   = whf + wb + 196608;
        const h16* f1_f   = whf + wb + 262144;
        const h16* f2_f   = whf + wb + 524288;
        const float* bqkv = attn_bqkv + (size_t)l * 768;
        gemm_mfma<false, true><<<dim3(MB, 6), 256, 0, stream>>>(
            XP16, X16, 512, wqkv_f, bqkv,
            nullptr, QKV16, 256, 768, 0, scal, 256);
        attn_kernel<<<MTOT / 2, 256, 0, stream>>>(QKV16, IDX, AO16);
        if (l == LL - 1) {
            fused_layer<2><<<MTOT / 64, 512, 0, stream>>>(
                AO16, wo_f, attn_bo + (size_t)l * 256, X16,
                ln1_g + l * 256, ln1_b + l * 256,
                f1_f, f2_f, ffn_b1 + (size_t)l * 1024, ffn_b2 + (size_t)l * 256,
                ln2_g + l * 256, ln2_b + l * 256,
                (float*)d_out, nullptr, nullptr, nullptr);
        } else {
            fused_layer<1><<<MTOT / 64, 512, 0, stream>>>(
                AO16, wo_f, attn_bo + (size_t)l * 256, X16,
                ln1_g + l * 256, ln1_b + l * 256,
                f1_f, f2_f, ffn_b1 + (size_t)l * 1024, ffn_b2 + (size_t)l * 256,
                ln2_g + l * 256, ln2_b + l * 256,
                nullptr, X16, PE16, XP16);
        }
    }
}